// Round 1
// baseline (822.113 us; speedup 1.0000x reference)
//
#include <hip/hip_runtime.h>
#include <hip/hip_bf16.h>

// Problem constants
#define BB 64
#define NJ 30
#define NM 20
#define NN 600
#define HH 128
#define NROWS (BB*NN)   // 38400
#define CAP 64          // max neighbors kept per row (E[nbrs]~7, P(>63)~0)

// Workspace byte offsets (total needed: ~47.1 MB)
#define STATS_B   0            // 4 stages x (sum[128], sumsq[128]) = 4096 B
#define HPOOL_B   4096         // B*H floats = 32768 B
#define FLAGS_B   36864        // 2 ints (mask layout detection)
#define ZERO_B    37120        // bytes to memset at start
#define NBRCNT_B  37120        // NROWS ints
#define NBRIDX_B  190720       // NROWS*CAP ints
#define TA_B      10021120     // NROWS*H floats (t0, then t2)
#define TB_B      29681920     // NROWS*H floats (t1, then t3)
#define CONCAT_B  10021120     // aliases TA (t2 dead after stage-3 GEMM)
#define A1_B      (10021120 + 2949120)
#define SCORES_B  (10021120 + 2949120 + 983040)

// Output float offsets
#define OUT_ENT   0
#define OUT_V     64
#define OUT_LOGA  128
#define OUT_ANODE 192
#define OUT_AFEAT 1472
#define OUT_MMCH  9664
#define OUT_HPOOL 10944

__device__ __forceinline__ bool mask_at(const void* p, int layout, long i) {
    if (layout == 2) return ((const float*)p)[i] != 0.f;
    if (layout == 1) return ((const unsigned char*)p)[i] != 0;
    return ((const int*)p)[i] != 0;
}

__device__ __forceinline__ float f4c(const float4& v, int i) {
    return i == 0 ? v.x : (i == 1 ? v.y : (i == 2 ? v.z : v.w));
}

// --- detect byte layout of the two bool inputs ---
// bit0: saw 0x3f at pos%4==3  -> float32 (1.0f = 00 00 80 3f)
// bit1: saw 0x01 at pos%4!=0  -> uint8
// neither -> int32
__global__ void k_detect(const void* mask_p, const void* maskmch_p, int* flags) {
    const unsigned char* p = (const unsigned char*)(blockIdx.x == 0 ? mask_p : maskmch_p);
    int nbytes = (blockIdx.x == 0) ? (BB * NJ) : 76800;  // both safe under u8 layout
    int f = 0;
    for (int i = threadIdx.x; i < nbytes; i += blockDim.x) {
        unsigned char v = p[i];
        int m4 = i & 3;
        if (m4 == 3 && v == 0x3f) f |= 1;
        if (m4 != 0 && v == 1)    f |= 2;
    }
    if (f) atomicOr(&flags[blockIdx.x], f);
}

// --- scan adj once, build neighbor lists (adj entries are exactly 0/1) ---
__global__ __launch_bounds__(256) void k_sparse(const float* __restrict__ adj,
                                                int* __restrict__ nbr_cnt,
                                                int* __restrict__ nbr_idx) {
    int wave = (int)((blockIdx.x * (size_t)blockDim.x + threadIdx.x) >> 6);
    int lane = threadIdx.x & 63;
    if (wave >= NROWS) return;
    const float* arow = adj + (size_t)wave * NN;
    int* irow = nbr_idx + (size_t)wave * CAP;
    int cnt = 0;
    for (int m0 = 0; m0 < NN; m0 += 64) {
        int m = m0 + lane;
        float v = (m < NN) ? arow[m] : 0.f;
        unsigned long long bal = __ballot(v != 0.f);
        if (v != 0.f) {
            int pos = cnt + __popcll(bal & ((1ull << lane) - 1ull));
            if (pos < CAP) irow[pos] = m;
        }
        cnt += __popcll(bal);
    }
    if (lane == 0) nbr_cnt[wave] = (cnt < CAP) ? cnt : CAP;
}

// --- layer0 mm1: pooled0 = sum_nbr x  (IN_DIM=2), t0 = pooled0 @ W1_0 + b1_0, BN0 stats ---
__global__ __launch_bounds__(256) void k_l0mm1(const float* __restrict__ x,
                                               const int* __restrict__ nbr_cnt,
                                               const int* __restrict__ nbr_idx,
                                               const float* __restrict__ W1,
                                               const float* __restrict__ b1,
                                               float* __restrict__ tA,
                                               float* __restrict__ stats) {
    int c = threadIdx.x & 127, rr = threadIdx.x >> 7;
    int base = blockIdx.x * 64;
    float w0 = W1[c], w1 = W1[HH + c], bb = b1[c];
    float s = 0.f, sq = 0.f;
    for (int r = rr; r < 64; r += 2) {
        int row = base + r;
        int b = row / NN;
        int cnt = nbr_cnt[row];
        const int* ir = nbr_idx + (size_t)row * CAP;
        float p0 = 0.f, p1 = 0.f;
        for (int i = 0; i < cnt; ++i) {
            int m = ir[i];
            const float* xp = x + ((size_t)b * NN + m) * 2;
            p0 += xp[0]; p1 += xp[1];
        }
        float t = p0 * w0 + p1 * w1 + bb;
        tA[(size_t)row * HH + c] = t;
        s += t; sq += t * t;
    }
    __shared__ float red[256], red2[256];
    red[threadIdx.x] = s; red2[threadIdx.x] = sq;
    __syncthreads();
    if (threadIdx.x < 128) {
        atomicAdd(&stats[c], red[c] + red[c + 128]);
        atomicAdd(&stats[128 + c], red2[c] + red2[c + 128]);
    }
}

// --- generic stage: h = relu(BN_{s_in}(t_in)) [optionally pooled over nbrs],
//     t_out = h @ W + bias, accumulate BN_{s_out} stats.
//     32 rows/block, thread tile 4 rows x 4 cols, LDS-tiled over K. ---
__global__ __launch_bounds__(256) void k_dense(const float* __restrict__ t_in,
                                               const float* __restrict__ W,
                                               const float* __restrict__ bias,
                                               float* __restrict__ t_out,
                                               float* __restrict__ stats,
                                               int s_in, int s_out, int gather,
                                               const int* __restrict__ nbr_cnt,
                                               const int* __restrict__ nbr_idx) {
    __shared__ __align__(16) float sm_mean[HH], sm_inv[HH];
    __shared__ __align__(16) float sh_h[32 * 132];
    __shared__ __align__(16) float sh_w[32 * 128];
    __shared__ __align__(16) float redS[8 * 128], redQ[8 * 128];

    if (threadIdx.x < HH) {
        float s = stats[s_in * 256 + threadIdx.x];
        float q = stats[s_in * 256 + 128 + threadIdx.x];
        float m = s * (1.f / (float)NROWS);
        float var = q * (1.f / (float)NROWS) - m * m;
        sm_mean[threadIdx.x] = m;
        sm_inv[threadIdx.x] = 1.f / sqrtf(var + 1e-5f);
    }
    __syncthreads();

    int base = blockIdx.x * 32;

    if (!gather) {
        for (int idx = threadIdx.x; idx < 32 * HH; idx += 256) {
            int r = idx >> 7, k = idx & 127;
            float v = t_in[(size_t)(base + r) * HH + k];
            sh_h[r * 132 + k] = fmaxf((v - sm_mean[k]) * sm_inv[k], 0.f);
        }
    } else {
        int wv = threadIdx.x >> 6, lane = threadIdx.x & 63;
        int k2 = lane * 2;
        float m0 = sm_mean[k2], m1 = sm_mean[k2 + 1];
        float i0 = sm_inv[k2], i1 = sm_inv[k2 + 1];
        for (int r = wv; r < 32; r += 4) {
            int row = base + r;
            int b = row / NN;
            int cnt = nbr_cnt[row];
            const int* ir = nbr_idx + (size_t)row * CAP;
            float a0 = 0.f, a1v = 0.f;
            for (int i = 0; i < cnt; ++i) {
                int m = ir[i];
                const float2 v = *(const float2*)&t_in[((size_t)b * NN + m) * HH + k2];
                a0  += fmaxf((v.x - m0) * i0, 0.f);
                a1v += fmaxf((v.y - m1) * i1, 0.f);
            }
            sh_h[r * 132 + k2]     = a0;
            sh_h[r * 132 + k2 + 1] = a1v;
        }
    }

    int cg = threadIdx.x & 31, rg = threadIdx.x >> 5;
    int c0 = cg * 4, r0 = rg * 4;
    float acc[4][4] = {};
    for (int kt = 0; kt < 4; ++kt) {
        __syncthreads();
        for (int idx = threadIdx.x; idx < 32 * 128; idx += 256) {
            int kk = idx >> 7, c = idx & 127;
            sh_w[kk * 128 + c] = W[(size_t)(kt * 32 + kk) * HH + c];
        }
        __syncthreads();
        for (int kq = 0; kq < 8; ++kq) {
            int kb = kq * 4;
            float4 hv[4], wv[4];
#pragma unroll
            for (int i = 0; i < 4; ++i)
                hv[i] = *(const float4*)&sh_h[(r0 + i) * 132 + kt * 32 + kb];
#pragma unroll
            for (int i = 0; i < 4; ++i)
                wv[i] = *(const float4*)&sh_w[(kb + i) * 128 + c0];
#pragma unroll
            for (int ri = 0; ri < 4; ++ri) {
                float4 h4 = hv[ri];
#pragma unroll
                for (int ci = 0; ci < 4; ++ci) {
                    acc[ri][ci] += h4.x * f4c(wv[0], ci) + h4.y * f4c(wv[1], ci)
                                 + h4.z * f4c(wv[2], ci) + h4.w * f4c(wv[3], ci);
                }
            }
        }
    }

    float colS[4] = {0, 0, 0, 0}, colQ[4] = {0, 0, 0, 0};
#pragma unroll
    for (int ri = 0; ri < 4; ++ri) {
        float4 o;
        o.x = acc[ri][0] + bias[c0 + 0];
        o.y = acc[ri][1] + bias[c0 + 1];
        o.z = acc[ri][2] + bias[c0 + 2];
        o.w = acc[ri][3] + bias[c0 + 3];
        *(float4*)&t_out[(size_t)(base + r0 + ri) * HH + c0] = o;
        colS[0] += o.x; colQ[0] += o.x * o.x;
        colS[1] += o.y; colQ[1] += o.y * o.y;
        colS[2] += o.z; colQ[2] += o.z * o.z;
        colS[3] += o.w; colQ[3] += o.w * o.w;
    }
#pragma unroll
    for (int ci = 0; ci < 4; ++ci) {
        redS[rg * 128 + c0 + ci] = colS[ci];
        redQ[rg * 128 + c0 + ci] = colQ[ci];
    }
    __syncthreads();
    if (threadIdx.x < 128) {
        int c = threadIdx.x;
        float s = 0.f, q = 0.f;
#pragma unroll
        for (int g = 0; g < 8; ++g) { s += redS[g * 128 + c]; q += redQ[g * 128 + c]; }
        atomicAdd(&stats[s_out * 256 + c], s);
        atomicAdd(&stats[s_out * 256 + 128 + c], q);
    }
}

// --- h_pooled = sum_n graph_pool * relu(BN3(t3)) ---
__global__ __launch_bounds__(256) void k_hpool(const float* __restrict__ t3,
                                               const float* __restrict__ gp,
                                               const float* __restrict__ stats,
                                               float* __restrict__ hpool) {
    __shared__ float sm_mean[HH], sm_inv[HH];
    if (threadIdx.x < HH) {
        float s = stats[3 * 256 + threadIdx.x];
        float q = stats[3 * 256 + 128 + threadIdx.x];
        float m = s * (1.f / (float)NROWS);
        float var = q * (1.f / (float)NROWS) - m * m;
        sm_mean[threadIdx.x] = m;
        sm_inv[threadIdx.x] = 1.f / sqrtf(var + 1e-5f);
    }
    __syncthreads();
    int b = blockIdx.x / 5, chunk = blockIdx.x % 5;
    int c = threadIdx.x & 127, rr = threadIdx.x >> 7;
    float acc = 0.f;
    for (int n = chunk * 120 + rr; n < chunk * 120 + 120; n += 2) {
        float w = gp[b * NN + n];
        float v = t3[((size_t)b * NN + n) * HH + c];
        acc += w * fmaxf((v - sm_mean[c]) * sm_inv[c], 0.f);
    }
    __shared__ float red[256];
    red[threadIdx.x] = acc;
    __syncthreads();
    if (threadIdx.x < 128) atomicAdd(&hpool[b * HH + c], red[c] + red[c + 128]);
}

// --- build concat rows: [h_nodes[cand], h_pooled, mch_pool] ---
__global__ __launch_bounds__(128) void k_concat(const float* __restrict__ t3,
                                                const int* __restrict__ cand,
                                                const float* __restrict__ hpool,
                                                const float* __restrict__ mch,
                                                const float* __restrict__ stats,
                                                float* __restrict__ concat) {
    __shared__ float sm_mean[HH], sm_inv[HH];
    int t = threadIdx.x;
    {
        float s = stats[3 * 256 + t], q = stats[3 * 256 + 128 + t];
        float m = s * (1.f / (float)NROWS);
        float var = q * (1.f / (float)NROWS) - m * m;
        sm_mean[t] = m;
        sm_inv[t] = 1.f / sqrtf(var + 1e-5f);
    }
    __syncthreads();
    int row = blockIdx.x;
    int b = row / NJ;
    int cd = cand[row];
    float v = t3[((size_t)b * NN + cd) * HH + t];
    concat[(size_t)row * 384 + t]       = fmaxf((v - sm_mean[t]) * sm_inv[t], 0.f);
    concat[(size_t)row * 384 + 128 + t] = hpool[b * HH + t];
    concat[(size_t)row * 384 + 256 + t] = mch[b * HH + t];
}

// --- a1 = tanh(concat @ Wa1 + ba1): 1920 x 384 @ 384 x 128 ---
__global__ __launch_bounds__(256) void k_a1(const float* __restrict__ concat,
                                            const float* __restrict__ Wa1,
                                            const float* __restrict__ ba1,
                                            float* __restrict__ a1out) {
    __shared__ __align__(16) float sh_c[16 * 388];
    __shared__ __align__(16) float sh_w[32 * 128];
    int base = blockIdx.x * 16;
    for (int r = 0; r < 16; ++r)
        for (int k = threadIdx.x; k < 384; k += 256)
            sh_c[r * 388 + k] = concat[(size_t)(base + r) * 384 + k];
    int cg = threadIdx.x & 31, rg = threadIdx.x >> 5;
    int c0 = cg * 4, r0 = rg * 2;
    float acc[2][4] = {};
    for (int kt = 0; kt < 12; ++kt) {
        __syncthreads();
        for (int idx = threadIdx.x; idx < 32 * 128; idx += 256) {
            int kk = idx >> 7, c = idx & 127;
            sh_w[kk * 128 + c] = Wa1[(size_t)(kt * 32 + kk) * 128 + c];
        }
        __syncthreads();
        for (int kq = 0; kq < 8; ++kq) {
            int kb = kt * 32 + kq * 4;
            float4 hv[2], wv[4];
            hv[0] = *(const float4*)&sh_c[r0 * 388 + kb];
            hv[1] = *(const float4*)&sh_c[(r0 + 1) * 388 + kb];
#pragma unroll
            for (int i = 0; i < 4; ++i)
                wv[i] = *(const float4*)&sh_w[(kq * 4 + i) * 128 + c0];
#pragma unroll
            for (int ri = 0; ri < 2; ++ri) {
                float4 h4 = hv[ri];
#pragma unroll
                for (int ci = 0; ci < 4; ++ci) {
                    acc[ri][ci] += h4.x * f4c(wv[0], ci) + h4.y * f4c(wv[1], ci)
                                 + h4.z * f4c(wv[2], ci) + h4.w * f4c(wv[3], ci);
                }
            }
        }
    }
#pragma unroll
    for (int ri = 0; ri < 2; ++ri) {
        float4 o;
        o.x = tanhf(acc[ri][0] + ba1[c0 + 0]);
        o.y = tanhf(acc[ri][1] + ba1[c0 + 1]);
        o.z = tanhf(acc[ri][2] + ba1[c0 + 2]);
        o.w = tanhf(acc[ri][3] + ba1[c0 + 3]);
        *(float4*)&a1out[(size_t)(base + r0 + ri) * 128 + c0] = o;
    }
}

// --- a2 = tanh(a1 @ Wa2 + ba2); scores = 10*(a2 @ Wa3 + ba3) ---
__global__ __launch_bounds__(256) void k_a2s(const float* __restrict__ a1,
                                             const float* __restrict__ Wa2,
                                             const float* __restrict__ ba2,
                                             const float* __restrict__ Wa3,
                                             const float* __restrict__ ba3,
                                             float* __restrict__ scores) {
    __shared__ __align__(16) float sh_h[32 * 132];
    __shared__ __align__(16) float sh_w[32 * 128];
    __shared__ __align__(16) float sh_a2[32 * 132];
    __shared__ float sred[256];
    int base = blockIdx.x * 32;
    for (int idx = threadIdx.x; idx < 32 * 128; idx += 256) {
        int r = idx >> 7, k = idx & 127;
        sh_h[r * 132 + k] = a1[(size_t)(base + r) * 128 + k];
    }
    int cg = threadIdx.x & 31, rg = threadIdx.x >> 5;
    int c0 = cg * 4, r0 = rg * 4;
    float acc[4][4] = {};
    for (int kt = 0; kt < 4; ++kt) {
        __syncthreads();
        for (int idx = threadIdx.x; idx < 32 * 128; idx += 256) {
            int kk = idx >> 7, c = idx & 127;
            sh_w[kk * 128 + c] = Wa2[(size_t)(kt * 32 + kk) * 128 + c];
        }
        __syncthreads();
        for (int kq = 0; kq < 8; ++kq) {
            int kb = kq * 4;
            float4 hv[4], wv[4];
#pragma unroll
            for (int i = 0; i < 4; ++i)
                hv[i] = *(const float4*)&sh_h[(r0 + i) * 132 + kt * 32 + kb];
#pragma unroll
            for (int i = 0; i < 4; ++i)
                wv[i] = *(const float4*)&sh_w[(kb + i) * 128 + c0];
#pragma unroll
            for (int ri = 0; ri < 4; ++ri) {
                float4 h4 = hv[ri];
#pragma unroll
                for (int ci = 0; ci < 4; ++ci) {
                    acc[ri][ci] += h4.x * f4c(wv[0], ci) + h4.y * f4c(wv[1], ci)
                                 + h4.z * f4c(wv[2], ci) + h4.w * f4c(wv[3], ci);
                }
            }
        }
    }
#pragma unroll
    for (int ri = 0; ri < 4; ++ri)
#pragma unroll
        for (int ci = 0; ci < 4; ++ci)
            sh_a2[(r0 + ri) * 132 + c0 + ci] = tanhf(acc[ri][ci] + ba2[c0 + ci]);
    __syncthreads();
    int r = threadIdx.x >> 3, p = threadIdx.x & 7;
    float part = 0.f;
    for (int i = 0; i < 16; ++i) {
        int c = p * 16 + i;
        part += sh_a2[r * 132 + c] * Wa3[c];
    }
    sred[threadIdx.x] = part;
    __syncthreads();
    if (p == 0) {
        float s = 0.f;
        for (int i = 0; i < 8; ++i) s += sred[r * 8 + i];
        scores[base + r] = 10.f * (s + ba3[0]);
    }
}

// --- per-b: critic, masked log_softmax/entropy/log_a, gathers ---
__global__ __launch_bounds__(128) void k_final(const float* __restrict__ t3,
                                               const float* __restrict__ stats,
                                               const float* __restrict__ hpool,
                                               const float* __restrict__ scores,
                                               const void* __restrict__ mask_p,
                                               const void* __restrict__ maskmch_p,
                                               const int* __restrict__ flags,
                                               const float* __restrict__ dur,
                                               const int* __restrict__ a_index,
                                               const int* __restrict__ old_action,
                                               const float* __restrict__ Wc1,
                                               const float* __restrict__ bc1,
                                               const float* __restrict__ Wc2,
                                               const float* __restrict__ bc2,
                                               float* __restrict__ out) {
    __shared__ float sm_mean[HH], sm_inv[HH], sh_hp[HH], sh_red[HH];
    __shared__ float sh_s[32], sh_lp[32];
    __shared__ int sh_m[32];
    int b = blockIdx.x, t = threadIdx.x;
    {
        float s = stats[3 * 256 + t], q = stats[3 * 256 + 128 + t];
        float m = s * (1.f / (float)NROWS);
        float var = q * (1.f / (float)NROWS) - m * m;
        sm_mean[t] = m;
        sm_inv[t] = 1.f / sqrtf(var + 1e-5f);
    }
    sh_hp[t] = hpool[b * HH + t];
    __syncthreads();

    // critic
    float acc = bc1[t];
    for (int k = 0; k < HH; ++k) acc += sh_hp[k] * Wc1[k * HH + t];
    sh_red[t] = tanhf(acc) * Wc2[t];
    __syncthreads();
    for (int st = 64; st > 0; st >>= 1) {
        if (t < st) sh_red[t] += sh_red[t + st];
        __syncthreads();
    }
    if (t == 0) out[OUT_V + b] = sh_red[0] + bc2[0];

    // softmax over candidates
    int fA = flags[0], fB = flags[1];
    int layA = (fA & 1) ? 2 : ((fA & 2) ? 1 : 0);
    int layB = (fB & 1) ? 2 : ((fB & 2) ? 1 : 0);
    if (t < NJ) {
        sh_s[t] = scores[b * NJ + t];
        sh_m[t] = mask_at(mask_p, layA, (long)b * NJ + t) ? 1 : 0;
    }
    __syncthreads();
    if (t == 0) {
        float mx = -1e30f;
        for (int j = 0; j < NJ; ++j)
            if (!sh_m[j] && sh_s[j] > mx) mx = sh_s[j];
        float sum = 0.f;
        for (int j = 0; j < NJ; ++j)
            if (!sh_m[j]) sum += expf(sh_s[j] - mx);
        float lse = mx + logf(sum);
        float ent = 0.f;
        for (int j = 0; j < NJ; ++j) {
            if (!sh_m[j]) {
                float lp = sh_s[j] - lse;
                sh_lp[j] = lp;
                float pi = expf(lp);
                if (pi > 0.f) ent -= pi * lp;
            }
        }
        out[OUT_ENT + b] = ent;
        out[OUT_LOGA + b] = sh_lp[a_index[b]];
    }

    // gathers
    int old = old_action[b];
    if (t < NM) {
        out[OUT_ANODE + b * NM + t] = dur[((size_t)b * NN + old) * NM + t];
        out[OUT_MMCH + b * NM + t] =
            mask_at(maskmch_p, layB, ((size_t)b * NN + old) * NM + t) ? 1.f : 0.f;
    }
    {
        float v = t3[((size_t)b * NN + old) * HH + t];
        out[OUT_AFEAT + b * HH + t] = fmaxf((v - sm_mean[t]) * sm_inv[t], 0.f);
        out[OUT_HPOOL + b * HH + t] = sh_hp[t];
    }
}

extern "C" void kernel_launch(void* const* d_in, const int* in_sizes, int n_in,
                              void* d_out, int out_size, void* d_ws, size_t ws_size,
                              hipStream_t stream) {
    (void)in_sizes; (void)n_in; (void)out_size; (void)ws_size;
    const float* x         = (const float*)d_in[0];
    const float* gp        = (const float*)d_in[1];
    const float* adj       = (const float*)d_in[3];
    const int*   cand      = (const int*)d_in[4];
    const void*  mask_p    = d_in[5];
    const void*  maskmch_p = d_in[6];
    const float* dur       = (const float*)d_in[7];
    const int*   a_index   = (const int*)d_in[8];
    const int*   old_act   = (const int*)d_in[9];
    const float* mch_pool  = (const float*)d_in[10];
    const float* W1_0 = (const float*)d_in[11];
    const float* b1_0 = (const float*)d_in[12];
    const float* W2_0 = (const float*)d_in[13];
    const float* b2_0 = (const float*)d_in[14];
    const float* W1_1 = (const float*)d_in[15];
    const float* b1_1 = (const float*)d_in[16];
    const float* W2_1 = (const float*)d_in[17];
    const float* b2_1 = (const float*)d_in[18];
    const float* Wa1  = (const float*)d_in[19];
    const float* ba1  = (const float*)d_in[20];
    const float* Wa2  = (const float*)d_in[21];
    const float* ba2  = (const float*)d_in[22];
    const float* Wa3  = (const float*)d_in[23];
    const float* ba3  = (const float*)d_in[24];
    const float* Wc1  = (const float*)d_in[25];
    const float* bc1  = (const float*)d_in[26];
    const float* Wc2  = (const float*)d_in[27];
    const float* bc2  = (const float*)d_in[28];

    char* ws = (char*)d_ws;
    float* stats   = (float*)(ws + STATS_B);
    float* hpool   = (float*)(ws + HPOOL_B);
    int*   flags   = (int*)(ws + FLAGS_B);
    int*   nbr_cnt = (int*)(ws + NBRCNT_B);
    int*   nbr_idx = (int*)(ws + NBRIDX_B);
    float* tA      = (float*)(ws + TA_B);
    float* tB      = (float*)(ws + TB_B);
    float* concat  = (float*)(ws + CONCAT_B);
    float* a1      = (float*)(ws + A1_B);
    float* scores  = (float*)(ws + SCORES_B);
    float* out     = (float*)d_out;

    hipMemsetAsync(ws, 0, ZERO_B, stream);
    k_detect<<<2, 256, 0, stream>>>(mask_p, maskmch_p, flags);
    k_sparse<<<(NROWS * 64) / 256, 256, 0, stream>>>(adj, nbr_cnt, nbr_idx);
    k_l0mm1<<<NROWS / 64, 256, 0, stream>>>(x, nbr_cnt, nbr_idx, W1_0, b1_0, tA, stats);
    // t1 = relu(BN0(t0)) @ W2_0 + b2_0
    k_dense<<<NROWS / 32, 256, 0, stream>>>(tA, W2_0, b2_0, tB, stats, 0, 1, 0, nbr_cnt, nbr_idx);
    // t2 = (sum_nbr relu(BN1(t1))) @ W1_1 + b1_1
    k_dense<<<NROWS / 32, 256, 0, stream>>>(tB, W1_1, b1_1, tA, stats, 1, 2, 1, nbr_cnt, nbr_idx);
    // t3 = relu(BN2(t2)) @ W2_1 + b2_1
    k_dense<<<NROWS / 32, 256, 0, stream>>>(tA, W2_1, b2_1, tB, stats, 2, 3, 0, nbr_cnt, nbr_idx);
    k_hpool<<<BB * 5, 256, 0, stream>>>(tB, gp, stats, hpool);
    k_concat<<<BB * NJ, 128, 0, stream>>>(tB, cand, hpool, mch_pool, stats, concat);
    k_a1<<<120, 256, 0, stream>>>(concat, Wa1, ba1, a1);
    k_a2s<<<60, 256, 0, stream>>>(a1, Wa2, ba2, Wa3, ba3, scores);
    k_final<<<BB, 128, 0, stream>>>(tB, stats, hpool, scores, mask_p, maskmch_p, flags,
                                    dur, a_index, old_act, Wc1, bc1, Wc2, bc2, out);
}

// Round 2
// 523.684 us; speedup vs baseline: 1.5699x; 1.5699x over previous
//
#include <hip/hip_runtime.h>
#include <hip/hip_bf16.h>

#define BB 64
#define NJ 30
#define NM 20
#define NN 600
#define HH 128
#define NROWS (BB*NN)   // 38400
#define CAP 48          // max neighbors kept (E~7, P(>47) ~ 0)

typedef __attribute__((ext_vector_type(8))) short short8;
typedef __attribute__((ext_vector_type(4))) float f32x4;

// ---- workspace byte offsets (peak 47.30 MB < round-1-proven 49.34 MB) ----
#define STATS_B   0           // slot0: 5 scalars (S0,S1,Q0,Q1,P01); slots1-3: sum[128],sq[128]
#define HPOOL_B   4096
#define FLAGS_B   36864
#define ZERO_B    36880       // memset range
#define WTB_B     37120       // 3 x 128x128 bf16 transposed weights (98304 B)
#define SCORES_B  135424
#define NBRCNT_B  143104
#define NBRIDX_B  296704      // NROWS*CAP ints (7372800 B)
#define CONCAT_B  296704      // alias: nbr data dead after k_pool1
#define A1_B      3245824     // alias inside NBRIDX region
#define POOLED0_B 7669504     // NROWS * 2 floats
#define T1_B      7976704     // NROWS*H fp32 (t1, then t2)
#define P1_B      27637504    // NROWS*H fp32 (pooled1, then t3)

// ---- output float offsets ----
#define OUT_ENT   0
#define OUT_V     64
#define OUT_LOGA  128
#define OUT_ANODE 192
#define OUT_AFEAT 1472
#define OUT_MMCH  9664
#define OUT_HPOOL 10944

__device__ __forceinline__ bool mask_at(const void* p, int layout, long i) {
    if (layout == 2) return ((const float*)p)[i] != 0.f;
    if (layout == 1) return ((const unsigned char*)p)[i] != 0;
    return ((const int*)p)[i] != 0;
}

__device__ __forceinline__ short bf16rne(float f) {
    unsigned u = __float_as_uint(f);
    return (short)((u + 0x7fffu + ((u >> 16) & 1u)) >> 16);
}

// --- detect byte layout of bool inputs (f32 / u8 / i32) ---
__global__ void k_detect(const void* mask_p, const void* maskmch_p, int* flags) {
    const unsigned char* p = (const unsigned char*)(blockIdx.x == 0 ? mask_p : maskmch_p);
    int nbytes = (blockIdx.x == 0) ? (BB * NJ) : 76800;
    int f = 0;
    for (int i = threadIdx.x; i < nbytes; i += blockDim.x) {
        unsigned char v = p[i];
        int m4 = i & 3;
        if (m4 == 3 && v == 0x3f) f |= 1;
        if (m4 != 0 && v == 1)    f |= 2;
    }
    if (f) atomicOr(&flags[blockIdx.x], f);
}

// --- pre-transpose + cvt trunk GEMM weights to bf16: wT[c][k] = W[k][c] ---
__global__ void k_wconv(const float* __restrict__ Wa, const float* __restrict__ Wb,
                        const float* __restrict__ Wc, unsigned short* __restrict__ wT) {
    int mat = blockIdx.x >> 6;
    int idx = ((blockIdx.x & 63) << 8) + threadIdx.x;   // 0..16383
    const float* W = mat == 0 ? Wa : (mat == 1 ? Wb : Wc);
    int k = idx >> 7, c = idx & 127;
    wT[mat * 16384 + c * HH + k] = (unsigned short)bf16rne(W[idx]);
}

// --- scan adj once (float4): neighbor lists + pooled0 = sum_nbr x (IN_DIM=2) ---
__global__ __launch_bounds__(256) void k_sparse(const float* __restrict__ adj,
                                                const float* __restrict__ x,
                                                int* __restrict__ nbr_cnt,
                                                int* __restrict__ nbr_idx,
                                                float* __restrict__ pooled0) {
    int wrow = blockIdx.x * 4 + (threadIdx.x >> 6);
    int lane = threadIdx.x & 63;
    int b = wrow / NN;
    const float4* arow = (const float4*)(adj + (size_t)wrow * NN);
    int* irow = nbr_idx + (size_t)wrow * CAP;
    const float* xb = x + (size_t)b * NN * 2;
    int cnt = 0;
    float p0 = 0.f, p1 = 0.f;
    for (int it = 0; it < 3; ++it) {
        int fi = it * 64 + lane;
        float4 v = {0.f, 0.f, 0.f, 0.f};
        if (fi < 150) v = arow[fi];
#pragma unroll
        for (int s = 0; s < 4; ++s) {
            float c = s == 0 ? v.x : (s == 1 ? v.y : (s == 2 ? v.z : v.w));
            bool pred = (c != 0.f);
            unsigned long long bal = __ballot(pred);
            if (pred) {
                int pos = cnt + __popcll(bal & ((1ull << lane) - 1ull));
                int m = fi * 4 + s;
                if (pos < CAP) irow[pos] = m;
                p0 += xb[m * 2];
                p1 += xb[m * 2 + 1];
            }
            cnt += __popcll(bal);
        }
    }
#pragma unroll
    for (int off = 1; off < 64; off <<= 1) {
        p0 += __shfl_xor(p0, off);
        p1 += __shfl_xor(p1, off);
    }
    if (lane == 0) {
        nbr_cnt[wrow] = cnt < CAP ? cnt : CAP;
        pooled0[(size_t)wrow * 2]     = p0;
        pooled0[(size_t)wrow * 2 + 1] = p1;
    }
}

// --- 5-scalar stats over pooled0 (BN0 stats are rank-2 in (p0,p1)) ---
__global__ __launch_bounds__(256) void k_p0stats(const float* __restrict__ pooled0,
                                                 float* __restrict__ out5) {
    __shared__ float red[4][5];
    int i = blockIdx.x * 256 + threadIdx.x;
    float p0 = pooled0[(size_t)i * 2], p1 = pooled0[(size_t)i * 2 + 1];
    float v[5] = {p0, p1, p0 * p0, p1 * p1, p0 * p1};
#pragma unroll
    for (int j = 0; j < 5; ++j)
#pragma unroll
        for (int off = 1; off < 64; off <<= 1) v[j] += __shfl_xor(v[j], off);
    int lane = threadIdx.x & 63, w = threadIdx.x >> 6;
    if (lane == 0)
#pragma unroll
        for (int j = 0; j < 5; ++j) red[w][j] = v[j];
    __syncthreads();
    if (threadIdx.x == 0)
#pragma unroll
        for (int j = 0; j < 5; ++j)
            atomicAdd(&out5[j], red[0][j] + red[1][j] + red[2][j] + red[3][j]);
}

// --- MFMA GEMM stage: t_out[38400x128] = A @ W(bf16,transposed), + BN stats for t_out.
//     MODE 0: A = relu(BN0(pooled0 @ W1))  synthesized in-register from (p0,p1)
//     MODE 1: A = relu(BN(t_in))           (stats_in = sum/sq slot)
//     MODE 2: A = t_in raw                 (pooled activations, already relu'd)
//     Wave computes 16 rows x 128 cols via 8 col-tiles of 16x16x32 MFMA. No inner barriers.
template<int MODE>
__global__ __launch_bounds__(256) void k_stage(const float* __restrict__ t_in,
                                               const float* __restrict__ pooled0,
                                               const float* __restrict__ W1,
                                               const unsigned short* __restrict__ wT,
                                               const float* __restrict__ stats_in,
                                               float* __restrict__ t_out,
                                               float* __restrict__ stats_out) {
    __shared__ float sm_mean[HH], sm_inv[HH];
    __shared__ float smS[4][HH], smQ[4][HH];
    int tid = threadIdx.x;
    if (MODE == 0 && tid < HH) {
        float S0 = stats_in[0], S1 = stats_in[1], Q0 = stats_in[2], Q1 = stats_in[3], P01 = stats_in[4];
        float w0 = W1[tid], w1 = W1[HH + tid];
        float m = (S0 * w0 + S1 * w1) * (1.f / NROWS);
        float eq = (Q0 * w0 * w0 + Q1 * w1 * w1 + 2.f * P01 * w0 * w1) * (1.f / NROWS);
        sm_mean[tid] = m;
        sm_inv[tid] = 1.f / sqrtf(eq - m * m + 1e-5f);
    }
    if (MODE == 1 && tid < HH) {
        float s = stats_in[tid], q = stats_in[HH + tid];
        float m = s * (1.f / NROWS);
        sm_mean[tid] = m;
        sm_inv[tid] = 1.f / sqrtf(q * (1.f / NROWS) - m * m + 1e-5f);
    }
    if (MODE != 2) __syncthreads();

    int lane = tid & 63, wave = tid >> 6;
    int r16 = lane & 15, kg = lane >> 4;
    int rowbase = blockIdx.x * 64 + wave * 16;

    f32x4 acc[8];
#pragma unroll
    for (int t = 0; t < 8; ++t)
#pragma unroll
        for (int i = 0; i < 4; ++i) acc[t][i] = 0.f;

    float p0 = 0.f, p1 = 0.f;
    if (MODE == 0) {
        p0 = pooled0[(size_t)(rowbase + r16) * 2];
        p1 = pooled0[(size_t)(rowbase + r16) * 2 + 1];
    }

#pragma unroll
    for (int ks = 0; ks < 4; ++ks) {
        int kb = ks * 32 + kg * 8;
        float av[8];
        if (MODE == 0) {
            float4 wa0 = *(const float4*)&W1[kb];
            float4 wa1 = *(const float4*)&W1[kb + 4];
            float4 wb0 = *(const float4*)&W1[HH + kb];
            float4 wb1 = *(const float4*)&W1[HH + kb + 4];
            av[0] = p0 * wa0.x + p1 * wb0.x; av[1] = p0 * wa0.y + p1 * wb0.y;
            av[2] = p0 * wa0.z + p1 * wb0.z; av[3] = p0 * wa0.w + p1 * wb0.w;
            av[4] = p0 * wa1.x + p1 * wb1.x; av[5] = p0 * wa1.y + p1 * wb1.y;
            av[6] = p0 * wa1.z + p1 * wb1.z; av[7] = p0 * wa1.w + p1 * wb1.w;
        } else {
            const float* rp = t_in + (size_t)(rowbase + r16) * HH + kb;
            float4 v0 = *(const float4*)rp;
            float4 v1 = *(const float4*)(rp + 4);
            av[0] = v0.x; av[1] = v0.y; av[2] = v0.z; av[3] = v0.w;
            av[4] = v1.x; av[5] = v1.y; av[6] = v1.z; av[7] = v1.w;
        }
        if (MODE != 2) {
            float4 m0 = *(const float4*)&sm_mean[kb];
            float4 m1 = *(const float4*)&sm_mean[kb + 4];
            float4 i0 = *(const float4*)&sm_inv[kb];
            float4 i1 = *(const float4*)&sm_inv[kb + 4];
            av[0] = fmaxf((av[0] - m0.x) * i0.x, 0.f);
            av[1] = fmaxf((av[1] - m0.y) * i0.y, 0.f);
            av[2] = fmaxf((av[2] - m0.z) * i0.z, 0.f);
            av[3] = fmaxf((av[3] - m0.w) * i0.w, 0.f);
            av[4] = fmaxf((av[4] - m1.x) * i1.x, 0.f);
            av[5] = fmaxf((av[5] - m1.y) * i1.y, 0.f);
            av[6] = fmaxf((av[6] - m1.z) * i1.z, 0.f);
            av[7] = fmaxf((av[7] - m1.w) * i1.w, 0.f);
        }
        short8 afr;
#pragma unroll
        for (int j = 0; j < 8; ++j) afr[j] = bf16rne(av[j]);
#pragma unroll
        for (int t = 0; t < 8; ++t) {
            short8 bfr = *(const short8*)&wT[(size_t)(t * 16 + r16) * HH + kb];
            acc[t] = __builtin_amdgcn_mfma_f32_16x16x32_bf16(afr, bfr, acc[t], 0, 0, 0);
        }
    }

    // epilogue: write C (no bias — BN makes trunk biases no-ops) + column stats
    float* orow = t_out + (size_t)(rowbase + kg * 4) * HH;
#pragma unroll
    for (int t = 0; t < 8; ++t) {
        int col = t * 16 + r16;
        float s = 0.f, q = 0.f;
#pragma unroll
        for (int i = 0; i < 4; ++i) {
            float v = acc[t][i];
            orow[(size_t)i * HH + col] = v;
            s += v; q += v * v;
        }
        s += __shfl_xor(s, 16); q += __shfl_xor(q, 16);
        s += __shfl_xor(s, 32); q += __shfl_xor(q, 32);
        if (kg == 0) { smS[wave][col] = s; smQ[wave][col] = q; }
    }
    __syncthreads();
    if (tid < HH) {
        atomicAdd(&stats_out[tid],      smS[0][tid] + smS[1][tid] + smS[2][tid] + smS[3][tid]);
        atomicAdd(&stats_out[HH + tid], smQ[0][tid] + smQ[1][tid] + smQ[2][tid] + smQ[3][tid]);
    }
}

// --- pooled1 = sum_nbr relu(BN1(t1)) ---
__global__ __launch_bounds__(256) void k_pool1(const float* __restrict__ t1,
                                               const int* __restrict__ nbr_cnt,
                                               const int* __restrict__ nbr_idx,
                                               const float* __restrict__ stats1,
                                               float* __restrict__ pooled1) {
    __shared__ float sm_mean[HH], sm_inv[HH];
    int tid = threadIdx.x;
    if (tid < HH) {
        float s = stats1[tid], q = stats1[HH + tid];
        float m = s * (1.f / NROWS);
        sm_mean[tid] = m;
        sm_inv[tid] = 1.f / sqrtf(q * (1.f / NROWS) - m * m + 1e-5f);
    }
    __syncthreads();
    int c4 = tid & 31, rl = tid >> 5;
    int row = blockIdx.x * 8 + rl;
    int b = row / NN;
    float4 mm = *(const float4*)&sm_mean[c4 * 4];
    float4 iv = *(const float4*)&sm_inv[c4 * 4];
    int cnt = nbr_cnt[row];
    const int* ir = nbr_idx + (size_t)row * CAP;
    const float* tb = t1 + (size_t)b * NN * HH;
    float4 acc = {0.f, 0.f, 0.f, 0.f};
    for (int i = 0; i < cnt; ++i) {
        int m_ = ir[i];
        float4 v = *(const float4*)&tb[(size_t)m_ * HH + c4 * 4];
        acc.x += fmaxf((v.x - mm.x) * iv.x, 0.f);
        acc.y += fmaxf((v.y - mm.y) * iv.y, 0.f);
        acc.z += fmaxf((v.z - mm.z) * iv.z, 0.f);
        acc.w += fmaxf((v.w - mm.w) * iv.w, 0.f);
    }
    *(float4*)&pooled1[(size_t)row * HH + c4 * 4] = acc;
}

// --- h_pooled = sum_n gp * relu(BN3(t3)) ---
__global__ __launch_bounds__(256) void k_hpool(const float* __restrict__ t3,
                                               const float* __restrict__ gp,
                                               const float* __restrict__ stats3,
                                               float* __restrict__ hpool) {
    __shared__ float sm_mean[HH], sm_inv[HH];
    __shared__ float red[256];
    int tid = threadIdx.x;
    if (tid < HH) {
        float s = stats3[tid], q = stats3[HH + tid];
        float m = s * (1.f / NROWS);
        sm_mean[tid] = m;
        sm_inv[tid] = 1.f / sqrtf(q * (1.f / NROWS) - m * m + 1e-5f);
    }
    __syncthreads();
    int b = blockIdx.x >> 3, chunk = blockIdx.x & 7;
    int c = tid & 127, rr = tid >> 7;
    float m = sm_mean[c], iv = sm_inv[c];
    float acc = 0.f;
    for (int n = chunk * 75 + rr; n < chunk * 75 + 75; n += 2) {
        float w = gp[b * NN + n];
        float v = t3[((size_t)b * NN + n) * HH + c];
        acc += w * fmaxf((v - m) * iv, 0.f);
    }
    red[tid] = acc;
    __syncthreads();
    if (tid < HH) atomicAdd(&hpool[b * HH + c], red[c] + red[c + 128]);
}

// --- concat rows: [relu(BN3(t3[cand])), h_pooled, mch_pool] ---
__global__ __launch_bounds__(128) void k_concat(const float* __restrict__ t3,
                                                const int* __restrict__ cand,
                                                const float* __restrict__ hpool,
                                                const float* __restrict__ mch,
                                                const float* __restrict__ stats3,
                                                float* __restrict__ concat) {
    __shared__ float sm_mean[HH], sm_inv[HH];
    int t = threadIdx.x;
    {
        float s = stats3[t], q = stats3[HH + t];
        float m = s * (1.f / NROWS);
        sm_mean[t] = m;
        sm_inv[t] = 1.f / sqrtf(q * (1.f / NROWS) - m * m + 1e-5f);
    }
    __syncthreads();
    int row = blockIdx.x;
    int b = row / NJ;
    int cd = cand[row];
    float v = t3[((size_t)b * NN + cd) * HH + t];
    concat[(size_t)row * 384 + t]       = fmaxf((v - sm_mean[t]) * sm_inv[t], 0.f);
    concat[(size_t)row * 384 + 128 + t] = hpool[b * HH + t];
    concat[(size_t)row * 384 + 256 + t] = mch[b * HH + t];
}

// --- a1 = tanh(concat @ Wa1 + ba1), 8 rows/block, LDS-broadcast rows ---
__global__ __launch_bounds__(256) void k_a1(const float* __restrict__ concat,
                                            const float* __restrict__ Wa1,
                                            const float* __restrict__ ba1,
                                            float* __restrict__ a1out) {
    __shared__ float sh[8 * 384];
    int tid = threadIdx.x;
    int rbase = blockIdx.x * 8;
    const float4* src = (const float4*)(concat + (size_t)rbase * 384);
    float4* dst = (float4*)sh;
    for (int i = tid; i < 768; i += 256) dst[i] = src[i];
    __syncthreads();
    int c = tid & 127, slot = tid >> 7;
    float acc[4] = {0.f, 0.f, 0.f, 0.f};
    for (int k = 0; k < 384; ++k) {
        float w = Wa1[(size_t)k * HH + c];
#pragma unroll
        for (int rr = 0; rr < 4; ++rr)
            acc[rr] += sh[(slot * 4 + rr) * 384 + k] * w;
    }
    float bb = ba1[c];
#pragma unroll
    for (int rr = 0; rr < 4; ++rr)
        a1out[(size_t)(rbase + slot * 4 + rr) * HH + c] = tanhf(acc[rr] + bb);
}

// --- a2 = tanh(a1 @ Wa2 + ba2); scores = 10*(a2 . Wa3 + ba3) ---
__global__ __launch_bounds__(256) void k_a2s(const float* __restrict__ a1,
                                             const float* __restrict__ Wa2,
                                             const float* __restrict__ ba2,
                                             const float* __restrict__ Wa3,
                                             const float* __restrict__ ba3,
                                             float* __restrict__ scores) {
    __shared__ float sh[8 * HH];
    __shared__ float sred[8][HH];
    int tid = threadIdx.x;
    int rbase = blockIdx.x * 8;
    const float4* src = (const float4*)(a1 + (size_t)rbase * HH);
    float4* dst = (float4*)sh;
    dst[tid] = src[tid];   // 256 float4 = 8x128 floats
    __syncthreads();
    int c = tid & 127, slot = tid >> 7;
    float acc[4] = {0.f, 0.f, 0.f, 0.f};
    for (int k = 0; k < HH; ++k) {
        float w = Wa2[(size_t)k * HH + c];
#pragma unroll
        for (int rr = 0; rr < 4; ++rr)
            acc[rr] += sh[(slot * 4 + rr) * HH + k] * w;
    }
    float w3 = Wa3[c], bb = ba2[c];
#pragma unroll
    for (int rr = 0; rr < 4; ++rr)
        sred[slot * 4 + rr][c] = tanhf(acc[rr] + bb) * w3;
    __syncthreads();
    int r = tid >> 5, l32 = tid & 31;
    float v = sred[r][l32] + sred[r][l32 + 32] + sred[r][l32 + 64] + sred[r][l32 + 96];
    v += __shfl_xor(v, 1); v += __shfl_xor(v, 2); v += __shfl_xor(v, 4);
    v += __shfl_xor(v, 8); v += __shfl_xor(v, 16);
    if (l32 == 0) scores[rbase + r] = 10.f * (v + ba3[0]);
}

// --- per-b: critic, masked log_softmax/entropy/log_a, gathers ---
__global__ __launch_bounds__(128) void k_final(const float* __restrict__ t3,
                                               const float* __restrict__ stats3,
                                               const float* __restrict__ hpool,
                                               const float* __restrict__ scores,
                                               const void* __restrict__ mask_p,
                                               const void* __restrict__ maskmch_p,
                                               const int* __restrict__ flags,
                                               const float* __restrict__ dur,
                                               const int* __restrict__ a_index,
                                               const int* __restrict__ old_action,
                                               const float* __restrict__ Wc1,
                                               const float* __restrict__ bc1,
                                               const float* __restrict__ Wc2,
                                               const float* __restrict__ bc2,
                                               float* __restrict__ out) {
    __shared__ float sm_mean[HH], sm_inv[HH], sh_hp[HH], sh_red[HH];
    __shared__ float sh_s[32], sh_lp[32];
    __shared__ int sh_m[32];
    int b = blockIdx.x, t = threadIdx.x;
    {
        float s = stats3[t], q = stats3[HH + t];
        float m = s * (1.f / NROWS);
        sm_mean[t] = m;
        sm_inv[t] = 1.f / sqrtf(q * (1.f / NROWS) - m * m + 1e-5f);
    }
    sh_hp[t] = hpool[b * HH + t];
    __syncthreads();

    float acc = bc1[t];
    for (int k = 0; k < HH; ++k) acc += sh_hp[k] * Wc1[k * HH + t];
    sh_red[t] = tanhf(acc) * Wc2[t];
    __syncthreads();
    for (int st = 64; st > 0; st >>= 1) {
        if (t < st) sh_red[t] += sh_red[t + st];
        __syncthreads();
    }
    if (t == 0) out[OUT_V + b] = sh_red[0] + bc2[0];

    int fA = flags[0], fB = flags[1];
    int layA = (fA & 1) ? 2 : ((fA & 2) ? 1 : 0);
    int layB = (fB & 1) ? 2 : ((fB & 2) ? 1 : 0);
    if (t < NJ) {
        sh_s[t] = scores[b * NJ + t];
        sh_m[t] = mask_at(mask_p, layA, (long)b * NJ + t) ? 1 : 0;
    }
    __syncthreads();
    if (t == 0) {
        float mx = -1e30f;
        for (int j = 0; j < NJ; ++j)
            if (!sh_m[j] && sh_s[j] > mx) mx = sh_s[j];
        float sum = 0.f;
        for (int j = 0; j < NJ; ++j)
            if (!sh_m[j]) sum += expf(sh_s[j] - mx);
        float lse = mx + logf(sum);
        float ent = 0.f;
        for (int j = 0; j < NJ; ++j) {
            if (!sh_m[j]) {
                float lp = sh_s[j] - lse;
                sh_lp[j] = lp;
                float pi = expf(lp);
                if (pi > 0.f) ent -= pi * lp;
            }
        }
        out[OUT_ENT + b] = ent;
        out[OUT_LOGA + b] = sh_lp[a_index[b]];
    }

    int old = old_action[b];
    if (t < NM) {
        out[OUT_ANODE + b * NM + t] = dur[((size_t)b * NN + old) * NM + t];
        out[OUT_MMCH + b * NM + t] =
            mask_at(maskmch_p, layB, ((size_t)b * NN + old) * NM + t) ? 1.f : 0.f;
    }
    {
        float v = t3[((size_t)b * NN + old) * HH + t];
        out[OUT_AFEAT + b * HH + t] = fmaxf((v - sm_mean[t]) * sm_inv[t], 0.f);
        out[OUT_HPOOL + b * HH + t] = sh_hp[t];
    }
}

extern "C" void kernel_launch(void* const* d_in, const int* in_sizes, int n_in,
                              void* d_out, int out_size, void* d_ws, size_t ws_size,
                              hipStream_t stream) {
    (void)in_sizes; (void)n_in; (void)out_size; (void)ws_size;
    const float* x         = (const float*)d_in[0];
    const float* gp        = (const float*)d_in[1];
    const float* adj       = (const float*)d_in[3];
    const int*   cand      = (const int*)d_in[4];
    const void*  mask_p    = d_in[5];
    const void*  maskmch_p = d_in[6];
    const float* dur       = (const float*)d_in[7];
    const int*   a_index   = (const int*)d_in[8];
    const int*   old_act   = (const int*)d_in[9];
    const float* mch_pool  = (const float*)d_in[10];
    const float* W1_0 = (const float*)d_in[11];
    const float* W2_0 = (const float*)d_in[13];
    const float* W1_1 = (const float*)d_in[15];
    const float* W2_1 = (const float*)d_in[17];
    const float* Wa1  = (const float*)d_in[19];
    const float* ba1  = (const float*)d_in[20];
    const float* Wa2  = (const float*)d_in[21];
    const float* ba2  = (const float*)d_in[22];
    const float* Wa3  = (const float*)d_in[23];
    const float* ba3  = (const float*)d_in[24];
    const float* Wc1  = (const float*)d_in[25];
    const float* bc1  = (const float*)d_in[26];
    const float* Wc2  = (const float*)d_in[27];
    const float* bc2  = (const float*)d_in[28];

    char* ws = (char*)d_ws;
    float* stats   = (float*)(ws + STATS_B);     // slot s at stats + s*256
    float* hpool   = (float*)(ws + HPOOL_B);
    int*   flags   = (int*)(ws + FLAGS_B);
    unsigned short* wtb = (unsigned short*)(ws + WTB_B);
    float* scores  = (float*)(ws + SCORES_B);
    int*   nbr_cnt = (int*)(ws + NBRCNT_B);
    int*   nbr_idx = (int*)(ws + NBRIDX_B);
    float* concat  = (float*)(ws + CONCAT_B);
    float* a1      = (float*)(ws + A1_B);
    float* pooled0 = (float*)(ws + POOLED0_B);
    float* t1      = (float*)(ws + T1_B);        // then t2
    float* p1b     = (float*)(ws + P1_B);        // pooled1, then t3
    float* out     = (float*)d_out;

    hipMemsetAsync(ws, 0, ZERO_B, stream);
    k_detect<<<2, 256, 0, stream>>>(mask_p, maskmch_p, flags);
    k_wconv<<<192, 256, 0, stream>>>(W2_0, W1_1, W2_1, wtb);
    k_sparse<<<NROWS / 4, 256, 0, stream>>>(adj, x, nbr_cnt, nbr_idx, pooled0);
    k_p0stats<<<NROWS / 256, 256, 0, stream>>>(pooled0, stats);
    // t1 = relu(BN0(pooled0 @ W1_0)) @ W2_0   [+ stats1]
    k_stage<0><<<600, 256, 0, stream>>>(nullptr, pooled0, W1_0, wtb, stats, t1, stats + 256);
    // pooled1 = sum_nbr relu(BN1(t1))
    k_pool1<<<NROWS / 8, 256, 0, stream>>>(t1, nbr_cnt, nbr_idx, stats + 256, p1b);
    // t2 = pooled1 @ W1_1   [+ stats2]  (t2 aliases t1 buffer)
    k_stage<2><<<600, 256, 0, stream>>>(p1b, nullptr, nullptr, wtb + 16384, stats, t1, stats + 512);
    // t3 = relu(BN2(t2)) @ W2_1   [+ stats3]  (t3 aliases pooled1 buffer)
    k_stage<1><<<600, 256, 0, stream>>>(t1, nullptr, nullptr, wtb + 32768, stats + 512, p1b, stats + 768);
    k_hpool<<<BB * 8, 256, 0, stream>>>(p1b, gp, stats + 768, hpool);
    k_concat<<<BB * NJ, 128, 0, stream>>>(p1b, cand, hpool, mch_pool, stats + 768, concat);
    k_a1<<<240, 256, 0, stream>>>(concat, Wa1, ba1, a1);
    k_a2s<<<240, 256, 0, stream>>>(a1, Wa2, ba2, Wa3, ba3, scores);
    k_final<<<BB, 128, 0, stream>>>(p1b, stats + 768, hpool, scores, mask_p, maskmch_p, flags,
                                    dur, a_index, old_act, Wc1, bc1, Wc2, bc2, out);
}

// Round 3
// 403.328 us; speedup vs baseline: 2.0383x; 1.2984x over previous
//
#include <hip/hip_runtime.h>
#include <hip/hip_bf16.h>

#define BB 64
#define NJ 30
#define NM 20
#define NN 600
#define HH 128
#define NROWS (BB*NN)   // 38400
#define CAP 48          // max neighbors kept (E~7, P(>47) ~ 0)

typedef __attribute__((ext_vector_type(8))) short short8;
typedef __attribute__((ext_vector_type(4))) float f32x4;

// ---- workspace byte offsets (peak 47.30 MB < round-1-proven 49.34 MB) ----
#define STATS_B   0           // slot0: 5 scalars (S0,S1,Q0,Q1,P01); slots1-3: sum[128],sq[128]
#define HPOOL_B   4096
#define FLAGS_B   36864
#define ZERO_B    36880       // memset range
#define WTB_B     37120       // 3 x 128x128 bf16 transposed weights (98304 B)
#define SCORES_B  135424
#define NBRCNT_B  143104
#define NBRIDX_B  296704      // NROWS*CAP ints (7372800 B)
#define CONCAT_B  296704      // alias: nbr data dead after k_pool1
#define A1_B      3245824     // alias inside NBRIDX region
#define POOLED0_B 7669504     // NROWS * 2 floats
#define T1_B      7976704     // NROWS*H fp32 (t1, then t2)
#define P1_B      27637504    // NROWS*H fp32 (pooled1, then t3)

// ---- output float offsets ----
#define OUT_ENT   0
#define OUT_V     64
#define OUT_LOGA  128
#define OUT_ANODE 192
#define OUT_AFEAT 1472
#define OUT_MMCH  9664
#define OUT_HPOOL 10944

__device__ __forceinline__ bool mask_at(const void* p, int layout, long i) {
    if (layout == 2) return ((const float*)p)[i] != 0.f;
    if (layout == 1) return ((const unsigned char*)p)[i] != 0;
    return ((const int*)p)[i] != 0;
}

__device__ __forceinline__ short bf16rne(float f) {
    unsigned u = __float_as_uint(f);
    return (short)((u + 0x7fffu + ((u >> 16) & 1u)) >> 16);
}

// --- detect byte layout of bool inputs (f32 / u8 / i32) ---
// Parallel + u32-vectorized: 25 blocks, <=4 independent loads/thread, OR-combine.
// OR-combining is sound: encodings' byte values {0,1} (u8), {0,0x80,0x3f} (f32),
// {0} (i32 bytes 1-3) cannot alias each other's signatures under OR.
// bit0: byte at pos%4==3 ORs to 0x3f -> float32. bit1: byte at pos%4!=0 ORs to
// 0x01 -> uint8. neither -> int32 (f32 misclassified as i32 is still correct:
// both are 4-byte "!=0" tests).
__global__ __launch_bounds__(256) void k_detect(const void* mask_p, const void* maskmch_p,
                                                int* flags) {
    unsigned agg = 0;
    int which;
    int tid = threadIdx.x;
    if (blockIdx.x == 0) {
        which = 0;
        const unsigned* p = (const unsigned*)mask_p;     // scan 480 words = 1920 B
        unsigned w0 = (tid < 480) ? p[tid] : 0u;
        unsigned w1 = (tid + 256 < 480) ? p[tid + 256] : 0u;
        agg = w0 | w1;
    } else {
        which = 1;
        const unsigned* p = (const unsigned*)maskmch_p + (size_t)(blockIdx.x - 1) * 800;
        unsigned w0 = p[tid];                            // 24 blocks x 800 words = 76800 B
        unsigned w1 = (tid + 256 < 800) ? p[tid + 256] : 0u;
        unsigned w2 = (tid + 512 < 800) ? p[tid + 512] : 0u;
        unsigned w3 = (tid + 768 < 800) ? p[tid + 768] : 0u;
        agg = w0 | w1 | w2 | w3;
    }
    int f = 0;
    if (((agg >> 24) & 0xffu) == 0x3fu) f |= 1;
    if ((((agg >> 8) & 0xffu) == 1u) || (((agg >> 16) & 0xffu) == 1u) ||
        (((agg >> 24) & 0xffu) == 1u)) f |= 2;
#pragma unroll
    for (int off = 1; off < 64; off <<= 1) f |= __shfl_xor(f, off);
    if ((tid & 63) == 0 && f) atomicOr(&flags[which], f);
}

// --- pre-transpose + cvt trunk GEMM weights to bf16: wT[c][k] = W[k][c] ---
__global__ void k_wconv(const float* __restrict__ Wa, const float* __restrict__ Wb,
                        const float* __restrict__ Wc, unsigned short* __restrict__ wT) {
    int mat = blockIdx.x >> 6;
    int idx = ((blockIdx.x & 63) << 8) + threadIdx.x;   // 0..16383
    const float* W = mat == 0 ? Wa : (mat == 1 ? Wb : Wc);
    int k = idx >> 7, c = idx & 127;
    wT[mat * 16384 + c * HH + k] = (unsigned short)bf16rne(W[idx]);
}

// --- scan adj once (float4): neighbor lists + pooled0 = sum_nbr x (IN_DIM=2) ---
__global__ __launch_bounds__(256) void k_sparse(const float* __restrict__ adj,
                                                const float* __restrict__ x,
                                                int* __restrict__ nbr_cnt,
                                                int* __restrict__ nbr_idx,
                                                float* __restrict__ pooled0) {
    int wrow = blockIdx.x * 4 + (threadIdx.x >> 6);
    int lane = threadIdx.x & 63;
    int b = wrow / NN;
    const float4* arow = (const float4*)(adj + (size_t)wrow * NN);
    int* irow = nbr_idx + (size_t)wrow * CAP;
    const float* xb = x + (size_t)b * NN * 2;
    int cnt = 0;
    float p0 = 0.f, p1 = 0.f;
    for (int it = 0; it < 3; ++it) {
        int fi = it * 64 + lane;
        float4 v = {0.f, 0.f, 0.f, 0.f};
        if (fi < 150) v = arow[fi];
#pragma unroll
        for (int s = 0; s < 4; ++s) {
            float c = s == 0 ? v.x : (s == 1 ? v.y : (s == 2 ? v.z : v.w));
            bool pred = (c != 0.f);
            unsigned long long bal = __ballot(pred);
            if (pred) {
                int pos = cnt + __popcll(bal & ((1ull << lane) - 1ull));
                int m = fi * 4 + s;
                if (pos < CAP) irow[pos] = m;
                p0 += xb[m * 2];
                p1 += xb[m * 2 + 1];
            }
            cnt += __popcll(bal);
        }
    }
#pragma unroll
    for (int off = 1; off < 64; off <<= 1) {
        p0 += __shfl_xor(p0, off);
        p1 += __shfl_xor(p1, off);
    }
    if (lane == 0) {
        nbr_cnt[wrow] = cnt < CAP ? cnt : CAP;
        pooled0[(size_t)wrow * 2]     = p0;
        pooled0[(size_t)wrow * 2 + 1] = p1;
    }
}

// --- 5-scalar stats over pooled0 (BN0 stats are rank-2 in (p0,p1)) ---
__global__ __launch_bounds__(256) void k_p0stats(const float* __restrict__ pooled0,
                                                 float* __restrict__ out5) {
    __shared__ float red[4][5];
    int i = blockIdx.x * 256 + threadIdx.x;
    float p0 = pooled0[(size_t)i * 2], p1 = pooled0[(size_t)i * 2 + 1];
    float v[5] = {p0, p1, p0 * p0, p1 * p1, p0 * p1};
#pragma unroll
    for (int j = 0; j < 5; ++j)
#pragma unroll
        for (int off = 1; off < 64; off <<= 1) v[j] += __shfl_xor(v[j], off);
    int lane = threadIdx.x & 63, w = threadIdx.x >> 6;
    if (lane == 0)
#pragma unroll
        for (int j = 0; j < 5; ++j) red[w][j] = v[j];
    __syncthreads();
    if (threadIdx.x == 0)
#pragma unroll
        for (int j = 0; j < 5; ++j)
            atomicAdd(&out5[j], red[0][j] + red[1][j] + red[2][j] + red[3][j]);
}

// --- MFMA GEMM stage: t_out[38400x128] = A @ W(bf16,transposed), + BN stats for t_out.
//     MODE 0: A = relu(BN0(pooled0 @ W1))  synthesized in-register from (p0,p1)
//     MODE 1: A = relu(BN(t_in))           (stats_in = sum/sq slot)
//     MODE 2: A = t_in raw                 (pooled activations, already relu'd)
//     Wave computes 16 rows x 128 cols via 8 col-tiles of 16x16x32 MFMA. No inner barriers.
template<int MODE>
__global__ __launch_bounds__(256) void k_stage(const float* __restrict__ t_in,
                                               const float* __restrict__ pooled0,
                                               const float* __restrict__ W1,
                                               const unsigned short* __restrict__ wT,
                                               const float* __restrict__ stats_in,
                                               float* __restrict__ t_out,
                                               float* __restrict__ stats_out) {
    __shared__ float sm_mean[HH], sm_inv[HH];
    __shared__ float smS[4][HH], smQ[4][HH];
    int tid = threadIdx.x;
    if (MODE == 0 && tid < HH) {
        float S0 = stats_in[0], S1 = stats_in[1], Q0 = stats_in[2], Q1 = stats_in[3], P01 = stats_in[4];
        float w0 = W1[tid], w1 = W1[HH + tid];
        float m = (S0 * w0 + S1 * w1) * (1.f / NROWS);
        float eq = (Q0 * w0 * w0 + Q1 * w1 * w1 + 2.f * P01 * w0 * w1) * (1.f / NROWS);
        sm_mean[tid] = m;
        sm_inv[tid] = 1.f / sqrtf(eq - m * m + 1e-5f);
    }
    if (MODE == 1 && tid < HH) {
        float s = stats_in[tid], q = stats_in[HH + tid];
        float m = s * (1.f / NROWS);
        sm_mean[tid] = m;
        sm_inv[tid] = 1.f / sqrtf(q * (1.f / NROWS) - m * m + 1e-5f);
    }
    if (MODE != 2) __syncthreads();

    int lane = tid & 63, wave = tid >> 6;
    int r16 = lane & 15, kg = lane >> 4;
    int rowbase = blockIdx.x * 64 + wave * 16;

    f32x4 acc[8];
#pragma unroll
    for (int t = 0; t < 8; ++t)
#pragma unroll
        for (int i = 0; i < 4; ++i) acc[t][i] = 0.f;

    float p0 = 0.f, p1 = 0.f;
    if (MODE == 0) {
        p0 = pooled0[(size_t)(rowbase + r16) * 2];
        p1 = pooled0[(size_t)(rowbase + r16) * 2 + 1];
    }

#pragma unroll
    for (int ks = 0; ks < 4; ++ks) {
        int kb = ks * 32 + kg * 8;
        float av[8];
        if (MODE == 0) {
            float4 wa0 = *(const float4*)&W1[kb];
            float4 wa1 = *(const float4*)&W1[kb + 4];
            float4 wb0 = *(const float4*)&W1[HH + kb];
            float4 wb1 = *(const float4*)&W1[HH + kb + 4];
            av[0] = p0 * wa0.x + p1 * wb0.x; av[1] = p0 * wa0.y + p1 * wb0.y;
            av[2] = p0 * wa0.z + p1 * wb0.z; av[3] = p0 * wa0.w + p1 * wb0.w;
            av[4] = p0 * wa1.x + p1 * wb1.x; av[5] = p0 * wa1.y + p1 * wb1.y;
            av[6] = p0 * wa1.z + p1 * wb1.z; av[7] = p0 * wa1.w + p1 * wb1.w;
        } else {
            const float* rp = t_in + (size_t)(rowbase + r16) * HH + kb;
            float4 v0 = *(const float4*)rp;
            float4 v1 = *(const float4*)(rp + 4);
            av[0] = v0.x; av[1] = v0.y; av[2] = v0.z; av[3] = v0.w;
            av[4] = v1.x; av[5] = v1.y; av[6] = v1.z; av[7] = v1.w;
        }
        if (MODE != 2) {
            float4 m0 = *(const float4*)&sm_mean[kb];
            float4 m1 = *(const float4*)&sm_mean[kb + 4];
            float4 i0 = *(const float4*)&sm_inv[kb];
            float4 i1 = *(const float4*)&sm_inv[kb + 4];
            av[0] = fmaxf((av[0] - m0.x) * i0.x, 0.f);
            av[1] = fmaxf((av[1] - m0.y) * i0.y, 0.f);
            av[2] = fmaxf((av[2] - m0.z) * i0.z, 0.f);
            av[3] = fmaxf((av[3] - m0.w) * i0.w, 0.f);
            av[4] = fmaxf((av[4] - m1.x) * i1.x, 0.f);
            av[5] = fmaxf((av[5] - m1.y) * i1.y, 0.f);
            av[6] = fmaxf((av[6] - m1.z) * i1.z, 0.f);
            av[7] = fmaxf((av[7] - m1.w) * i1.w, 0.f);
        }
        short8 afr;
#pragma unroll
        for (int j = 0; j < 8; ++j) afr[j] = bf16rne(av[j]);
#pragma unroll
        for (int t = 0; t < 8; ++t) {
            short8 bfr = *(const short8*)&wT[(size_t)(t * 16 + r16) * HH + kb];
            acc[t] = __builtin_amdgcn_mfma_f32_16x16x32_bf16(afr, bfr, acc[t], 0, 0, 0);
        }
    }

    // epilogue: write C (no bias — BN makes trunk biases no-ops) + column stats
    float* orow = t_out + (size_t)(rowbase + kg * 4) * HH;
#pragma unroll
    for (int t = 0; t < 8; ++t) {
        int col = t * 16 + r16;
        float s = 0.f, q = 0.f;
#pragma unroll
        for (int i = 0; i < 4; ++i) {
            float v = acc[t][i];
            orow[(size_t)i * HH + col] = v;
            s += v; q += v * v;
        }
        s += __shfl_xor(s, 16); q += __shfl_xor(q, 16);
        s += __shfl_xor(s, 32); q += __shfl_xor(q, 32);
        if (kg == 0) { smS[wave][col] = s; smQ[wave][col] = q; }
    }
    __syncthreads();
    if (tid < HH) {
        atomicAdd(&stats_out[tid],      smS[0][tid] + smS[1][tid] + smS[2][tid] + smS[3][tid]);
        atomicAdd(&stats_out[HH + tid], smQ[0][tid] + smQ[1][tid] + smQ[2][tid] + smQ[3][tid]);
    }
}

// --- pooled1 = sum_nbr relu(BN1(t1)) ---
__global__ __launch_bounds__(256) void k_pool1(const float* __restrict__ t1,
                                               const int* __restrict__ nbr_cnt,
                                               const int* __restrict__ nbr_idx,
                                               const float* __restrict__ stats1,
                                               float* __restrict__ pooled1) {
    __shared__ float sm_mean[HH], sm_inv[HH];
    int tid = threadIdx.x;
    if (tid < HH) {
        float s = stats1[tid], q = stats1[HH + tid];
        float m = s * (1.f / NROWS);
        sm_mean[tid] = m;
        sm_inv[tid] = 1.f / sqrtf(q * (1.f / NROWS) - m * m + 1e-5f);
    }
    __syncthreads();
    int c4 = tid & 31, rl = tid >> 5;
    int row = blockIdx.x * 8 + rl;
    int b = row / NN;
    float4 mm = *(const float4*)&sm_mean[c4 * 4];
    float4 iv = *(const float4*)&sm_inv[c4 * 4];
    int cnt = nbr_cnt[row];
    const int* ir = nbr_idx + (size_t)row * CAP;
    const float* tb = t1 + (size_t)b * NN * HH;
    float4 acc = {0.f, 0.f, 0.f, 0.f};
    for (int i = 0; i < cnt; ++i) {
        int m_ = ir[i];
        float4 v = *(const float4*)&tb[(size_t)m_ * HH + c4 * 4];
        acc.x += fmaxf((v.x - mm.x) * iv.x, 0.f);
        acc.y += fmaxf((v.y - mm.y) * iv.y, 0.f);
        acc.z += fmaxf((v.z - mm.z) * iv.z, 0.f);
        acc.w += fmaxf((v.w - mm.w) * iv.w, 0.f);
    }
    *(float4*)&pooled1[(size_t)row * HH + c4 * 4] = acc;
}

// --- h_pooled = sum_n gp * relu(BN3(t3)) ---
__global__ __launch_bounds__(256) void k_hpool(const float* __restrict__ t3,
                                               const float* __restrict__ gp,
                                               const float* __restrict__ stats3,
                                               float* __restrict__ hpool) {
    __shared__ float sm_mean[HH], sm_inv[HH];
    __shared__ float red[256];
    int tid = threadIdx.x;
    if (tid < HH) {
        float s = stats3[tid], q = stats3[HH + tid];
        float m = s * (1.f / NROWS);
        sm_mean[tid] = m;
        sm_inv[tid] = 1.f / sqrtf(q * (1.f / NROWS) - m * m + 1e-5f);
    }
    __syncthreads();
    int b = blockIdx.x >> 3, chunk = blockIdx.x & 7;
    int c = tid & 127, rr = tid >> 7;
    float m = sm_mean[c], iv = sm_inv[c];
    float acc = 0.f;
    for (int n = chunk * 75 + rr; n < chunk * 75 + 75; n += 2) {
        float w = gp[b * NN + n];
        float v = t3[((size_t)b * NN + n) * HH + c];
        acc += w * fmaxf((v - m) * iv, 0.f);
    }
    red[tid] = acc;
    __syncthreads();
    if (tid < HH) atomicAdd(&hpool[b * HH + c], red[c] + red[c + 128]);
}

// --- concat rows: [relu(BN3(t3[cand])), h_pooled, mch_pool] ---
__global__ __launch_bounds__(128) void k_concat(const float* __restrict__ t3,
                                                const int* __restrict__ cand,
                                                const float* __restrict__ hpool,
                                                const float* __restrict__ mch,
                                                const float* __restrict__ stats3,
                                                float* __restrict__ concat) {
    __shared__ float sm_mean[HH], sm_inv[HH];
    int t = threadIdx.x;
    {
        float s = stats3[t], q = stats3[HH + t];
        float m = s * (1.f / NROWS);
        sm_mean[t] = m;
        sm_inv[t] = 1.f / sqrtf(q * (1.f / NROWS) - m * m + 1e-5f);
    }
    __syncthreads();
    int row = blockIdx.x;
    int b = row / NJ;
    int cd = cand[row];
    float v = t3[((size_t)b * NN + cd) * HH + t];
    concat[(size_t)row * 384 + t]       = fmaxf((v - sm_mean[t]) * sm_inv[t], 0.f);
    concat[(size_t)row * 384 + 128 + t] = hpool[b * HH + t];
    concat[(size_t)row * 384 + 256 + t] = mch[b * HH + t];
}

// --- a1 = tanh(concat @ Wa1 + ba1), 8 rows/block, LDS-broadcast rows ---
__global__ __launch_bounds__(256) void k_a1(const float* __restrict__ concat,
                                            const float* __restrict__ Wa1,
                                            const float* __restrict__ ba1,
                                            float* __restrict__ a1out) {
    __shared__ float sh[8 * 384];
    int tid = threadIdx.x;
    int rbase = blockIdx.x * 8;
    const float4* src = (const float4*)(concat + (size_t)rbase * 384);
    float4* dst = (float4*)sh;
    for (int i = tid; i < 768; i += 256) dst[i] = src[i];
    __syncthreads();
    int c = tid & 127, slot = tid >> 7;
    float acc[4] = {0.f, 0.f, 0.f, 0.f};
    for (int k = 0; k < 384; ++k) {
        float w = Wa1[(size_t)k * HH + c];
#pragma unroll
        for (int rr = 0; rr < 4; ++rr)
            acc[rr] += sh[(slot * 4 + rr) * 384 + k] * w;
    }
    float bb = ba1[c];
#pragma unroll
    for (int rr = 0; rr < 4; ++rr)
        a1out[(size_t)(rbase + slot * 4 + rr) * HH + c] = tanhf(acc[rr] + bb);
}

// --- a2 = tanh(a1 @ Wa2 + ba2); scores = 10*(a2 . Wa3 + ba3) ---
__global__ __launch_bounds__(256) void k_a2s(const float* __restrict__ a1,
                                             const float* __restrict__ Wa2,
                                             const float* __restrict__ ba2,
                                             const float* __restrict__ Wa3,
                                             const float* __restrict__ ba3,
                                             float* __restrict__ scores) {
    __shared__ float sh[8 * HH];
    __shared__ float sred[8][HH];
    int tid = threadIdx.x;
    int rbase = blockIdx.x * 8;
    const float4* src = (const float4*)(a1 + (size_t)rbase * HH);
    float4* dst = (float4*)sh;
    dst[tid] = src[tid];   // 256 float4 = 8x128 floats
    __syncthreads();
    int c = tid & 127, slot = tid >> 7;
    float acc[4] = {0.f, 0.f, 0.f, 0.f};
    for (int k = 0; k < HH; ++k) {
        float w = Wa2[(size_t)k * HH + c];
#pragma unroll
        for (int rr = 0; rr < 4; ++rr)
            acc[rr] += sh[(slot * 4 + rr) * HH + k] * w;
    }
    float w3 = Wa3[c], bb = ba2[c];
#pragma unroll
    for (int rr = 0; rr < 4; ++rr)
        sred[slot * 4 + rr][c] = tanhf(acc[rr] + bb) * w3;
    __syncthreads();
    int r = tid >> 5, l32 = tid & 31;
    float v = sred[r][l32] + sred[r][l32 + 32] + sred[r][l32 + 64] + sred[r][l32 + 96];
    v += __shfl_xor(v, 1); v += __shfl_xor(v, 2); v += __shfl_xor(v, 4);
    v += __shfl_xor(v, 8); v += __shfl_xor(v, 16);
    if (l32 == 0) scores[rbase + r] = 10.f * (v + ba3[0]);
}

// --- per-b: critic, masked log_softmax/entropy/log_a, gathers ---
__global__ __launch_bounds__(128) void k_final(const float* __restrict__ t3,
                                               const float* __restrict__ stats3,
                                               const float* __restrict__ hpool,
                                               const float* __restrict__ scores,
                                               const void* __restrict__ mask_p,
                                               const void* __restrict__ maskmch_p,
                                               const int* __restrict__ flags,
                                               const float* __restrict__ dur,
                                               const int* __restrict__ a_index,
                                               const int* __restrict__ old_action,
                                               const float* __restrict__ Wc1,
                                               const float* __restrict__ bc1,
                                               const float* __restrict__ Wc2,
                                               const float* __restrict__ bc2,
                                               float* __restrict__ out) {
    __shared__ float sm_mean[HH], sm_inv[HH], sh_hp[HH], sh_red[HH];
    __shared__ float sh_s[32], sh_lp[32];
    __shared__ int sh_m[32];
    int b = blockIdx.x, t = threadIdx.x;
    {
        float s = stats3[t], q = stats3[HH + t];
        float m = s * (1.f / NROWS);
        sm_mean[t] = m;
        sm_inv[t] = 1.f / sqrtf(q * (1.f / NROWS) - m * m + 1e-5f);
    }
    sh_hp[t] = hpool[b * HH + t];
    __syncthreads();

    float acc = bc1[t];
    for (int k = 0; k < HH; ++k) acc += sh_hp[k] * Wc1[k * HH + t];
    sh_red[t] = tanhf(acc) * Wc2[t];
    __syncthreads();
    for (int st = 64; st > 0; st >>= 1) {
        if (t < st) sh_red[t] += sh_red[t + st];
        __syncthreads();
    }
    if (t == 0) out[OUT_V + b] = sh_red[0] + bc2[0];

    int fA = flags[0], fB = flags[1];
    int layA = (fA & 1) ? 2 : ((fA & 2) ? 1 : 0);
    int layB = (fB & 1) ? 2 : ((fB & 2) ? 1 : 0);
    if (t < NJ) {
        sh_s[t] = scores[b * NJ + t];
        sh_m[t] = mask_at(mask_p, layA, (long)b * NJ + t) ? 1 : 0;
    }
    __syncthreads();
    if (t == 0) {
        float mx = -1e30f;
        for (int j = 0; j < NJ; ++j)
            if (!sh_m[j] && sh_s[j] > mx) mx = sh_s[j];
        float sum = 0.f;
        for (int j = 0; j < NJ; ++j)
            if (!sh_m[j]) sum += expf(sh_s[j] - mx);
        float lse = mx + logf(sum);
        float ent = 0.f;
        for (int j = 0; j < NJ; ++j) {
            if (!sh_m[j]) {
                float lp = sh_s[j] - lse;
                sh_lp[j] = lp;
                float pi = expf(lp);
                if (pi > 0.f) ent -= pi * lp;
            }
        }
        out[OUT_ENT + b] = ent;
        out[OUT_LOGA + b] = sh_lp[a_index[b]];
    }

    int old = old_action[b];
    if (t < NM) {
        out[OUT_ANODE + b * NM + t] = dur[((size_t)b * NN + old) * NM + t];
        out[OUT_MMCH + b * NM + t] =
            mask_at(maskmch_p, layB, ((size_t)b * NN + old) * NM + t) ? 1.f : 0.f;
    }
    {
        float v = t3[((size_t)b * NN + old) * HH + t];
        out[OUT_AFEAT + b * HH + t] = fmaxf((v - sm_mean[t]) * sm_inv[t], 0.f);
        out[OUT_HPOOL + b * HH + t] = sh_hp[t];
    }
}

extern "C" void kernel_launch(void* const* d_in, const int* in_sizes, int n_in,
                              void* d_out, int out_size, void* d_ws, size_t ws_size,
                              hipStream_t stream) {
    (void)in_sizes; (void)n_in; (void)out_size; (void)ws_size;
    const float* x         = (const float*)d_in[0];
    const float* gp        = (const float*)d_in[1];
    const float* adj       = (const float*)d_in[3];
    const int*   cand      = (const int*)d_in[4];
    const void*  mask_p    = d_in[5];
    const void*  maskmch_p = d_in[6];
    const float* dur       = (const float*)d_in[7];
    const int*   a_index   = (const int*)d_in[8];
    const int*   old_act   = (const int*)d_in[9];
    const float* mch_pool  = (const float*)d_in[10];
    const float* W1_0 = (const float*)d_in[11];
    const float* W2_0 = (const float*)d_in[13];
    const float* W1_1 = (const float*)d_in[15];
    const float* W2_1 = (const float*)d_in[17];
    const float* Wa1  = (const float*)d_in[19];
    const float* ba1  = (const float*)d_in[20];
    const float* Wa2  = (const float*)d_in[21];
    const float* ba2  = (const float*)d_in[22];
    const float* Wa3  = (const float*)d_in[23];
    const float* ba3  = (const float*)d_in[24];
    const float* Wc1  = (const float*)d_in[25];
    const float* bc1  = (const float*)d_in[26];
    const float* Wc2  = (const float*)d_in[27];
    const float* bc2  = (const float*)d_in[28];

    char* ws = (char*)d_ws;
    float* stats   = (float*)(ws + STATS_B);     // slot s at stats + s*256
    float* hpool   = (float*)(ws + HPOOL_B);
    int*   flags   = (int*)(ws + FLAGS_B);
    unsigned short* wtb = (unsigned short*)(ws + WTB_B);
    float* scores  = (float*)(ws + SCORES_B);
    int*   nbr_cnt = (int*)(ws + NBRCNT_B);
    int*   nbr_idx = (int*)(ws + NBRIDX_B);
    float* concat  = (float*)(ws + CONCAT_B);
    float* a1      = (float*)(ws + A1_B);
    float* pooled0 = (float*)(ws + POOLED0_B);
    float* t1      = (float*)(ws + T1_B);        // then t2
    float* p1b     = (float*)(ws + P1_B);        // pooled1, then t3
    float* out     = (float*)d_out;

    hipMemsetAsync(ws, 0, ZERO_B, stream);
    k_detect<<<25, 256, 0, stream>>>(mask_p, maskmch_p, flags);
    k_wconv<<<192, 256, 0, stream>>>(W2_0, W1_1, W2_1, wtb);
    k_sparse<<<NROWS / 4, 256, 0, stream>>>(adj, x, nbr_cnt, nbr_idx, pooled0);
    k_p0stats<<<NROWS / 256, 256, 0, stream>>>(pooled0, stats);
    // t1 = relu(BN0(pooled0 @ W1_0)) @ W2_0   [+ stats1]
    k_stage<0><<<600, 256, 0, stream>>>(nullptr, pooled0, W1_0, wtb, stats, t1, stats + 256);
    // pooled1 = sum_nbr relu(BN1(t1))
    k_pool1<<<NROWS / 8, 256, 0, stream>>>(t1, nbr_cnt, nbr_idx, stats + 256, p1b);
    // t2 = pooled1 @ W1_1   [+ stats2]  (t2 aliases t1 buffer)
    k_stage<2><<<600, 256, 0, stream>>>(p1b, nullptr, nullptr, wtb + 16384, stats, t1, stats + 512);
    // t3 = relu(BN2(t2)) @ W2_1   [+ stats3]  (t3 aliases pooled1 buffer)
    k_stage<1><<<600, 256, 0, stream>>>(t1, nullptr, nullptr, wtb + 32768, stats + 512, p1b, stats + 768);
    k_hpool<<<BB * 8, 256, 0, stream>>>(p1b, gp, stats + 768, hpool);
    k_concat<<<BB * NJ, 128, 0, stream>>>(p1b, cand, hpool, mch_pool, stats + 768, concat);
    k_a1<<<240, 256, 0, stream>>>(concat, Wa1, ba1, a1);
    k_a2s<<<240, 256, 0, stream>>>(a1, Wa2, ba2, Wa3, ba3, scores);
    k_final<<<BB, 128, 0, stream>>>(p1b, stats + 768, hpool, scores, mask_p, maskmch_p, flags,
                                    dur, a_index, old_act, Wc1, bc1, Wc2, bc2, out);
}

// Round 4
// 382.275 us; speedup vs baseline: 2.1506x; 1.0551x over previous
//
#include <hip/hip_runtime.h>
#include <hip/hip_bf16.h>

#define BB 64
#define NJ 30
#define NM 20
#define NN 600
#define HH 128
#define NROWS (BB*NN)   // 38400
#define CAP 48          // max neighbors kept (E~7, P(>47) ~ 0)

typedef __attribute__((ext_vector_type(8))) short short8;
typedef __attribute__((ext_vector_type(4))) float f32x4;

// ---- workspace byte offsets (peak < round-1-proven 49.34 MB) ----
#define STATS_B   0           // slot0: 5 scalars (S0,S1,Q0,Q1,P01); slots1-3: sum[128],sq[128]
#define HPOOL_B   4096
#define FLAGS_B   36864
#define ZERO_B    36880       // memset range
#define WTB_B     37120       // 3 x 128x128 bf16 transposed weights (98304 B)
#define SCORES_B  135424
#define NBRCNT_B  143104
#define NBRIDX_B  296704      // NROWS*CAP ints (7372800 B)
#define CONCAT_B  296704      // alias: nbr data dead after k_pool1
#define A1_B      3245824     // alias inside NBRIDX region
#define POOLED0_B 7669504     // NROWS * 2 floats
#define T1_B      7976704     // NROWS*H bf16 (t1, then t2) = 9.83 MB
#define P1_B      27637504    // NROWS*H: bf16 pooled1, then fp32 t3 (19.66 MB)

// ---- output float offsets ----
#define OUT_ENT   0
#define OUT_V     64
#define OUT_LOGA  128
#define OUT_ANODE 192
#define OUT_AFEAT 1472
#define OUT_MMCH  9664
#define OUT_HPOOL 10944

__device__ __forceinline__ bool mask_at(const void* p, int layout, long i) {
    if (layout == 2) return ((const float*)p)[i] != 0.f;
    if (layout == 1) return ((const unsigned char*)p)[i] != 0;
    return ((const int*)p)[i] != 0;
}

__device__ __forceinline__ short bf16rne(float f) {
    unsigned u = __float_as_uint(f);
    return (short)((u + 0x7fffu + ((u >> 16) & 1u)) >> 16);
}
__device__ __forceinline__ float bf2f(unsigned h) {
    return __uint_as_float(h << 16);
}
__device__ __forceinline__ unsigned packbf(float a, float b) {
    return ((unsigned)(unsigned short)bf16rne(a)) |
           (((unsigned)(unsigned short)bf16rne(b)) << 16);
}

// --- detect byte layout of bool inputs (f32 / u8 / i32) ---
__global__ __launch_bounds__(256) void k_detect(const void* mask_p, const void* maskmch_p,
                                                int* flags) {
    unsigned agg = 0;
    int which;
    int tid = threadIdx.x;
    if (blockIdx.x == 0) {
        which = 0;
        const unsigned* p = (const unsigned*)mask_p;     // scan 480 words = 1920 B
        unsigned w0 = (tid < 480) ? p[tid] : 0u;
        unsigned w1 = (tid + 256 < 480) ? p[tid + 256] : 0u;
        agg = w0 | w1;
    } else {
        which = 1;
        const unsigned* p = (const unsigned*)maskmch_p + (size_t)(blockIdx.x - 1) * 800;
        unsigned w0 = p[tid];                            // 24 blocks x 800 words = 76800 B
        unsigned w1 = (tid + 256 < 800) ? p[tid + 256] : 0u;
        unsigned w2 = (tid + 512 < 800) ? p[tid + 512] : 0u;
        unsigned w3 = (tid + 768 < 800) ? p[tid + 768] : 0u;
        agg = w0 | w1 | w2 | w3;
    }
    int f = 0;
    if (((agg >> 24) & 0xffu) == 0x3fu) f |= 1;
    if ((((agg >> 8) & 0xffu) == 1u) || (((agg >> 16) & 0xffu) == 1u) ||
        (((agg >> 24) & 0xffu) == 1u)) f |= 2;
#pragma unroll
    for (int off = 1; off < 64; off <<= 1) f |= __shfl_xor(f, off);
    if ((tid & 63) == 0 && f) atomicOr(&flags[which], f);
}

// --- pre-transpose + cvt trunk GEMM weights to bf16: wT[c][k] = W[k][c] ---
__global__ void k_wconv(const float* __restrict__ Wa, const float* __restrict__ Wb,
                        const float* __restrict__ Wc, unsigned short* __restrict__ wT) {
    int mat = blockIdx.x >> 6;
    int idx = ((blockIdx.x & 63) << 8) + threadIdx.x;   // 0..16383
    const float* W = mat == 0 ? Wa : (mat == 1 ? Wb : Wc);
    int k = idx >> 7, c = idx & 127;
    wT[mat * 16384 + c * HH + k] = (unsigned short)bf16rne(W[idx]);
}

// --- scan adj once: neighbor lists + pooled0 = sum_nbr x.
//     All 3 adj float4 loads hoisted before the ballot chain -> single HBM
//     latency exposure per row (was 3 serial round trips). ---
__global__ __launch_bounds__(256) void k_sparse(const float* __restrict__ adj,
                                                const float* __restrict__ x,
                                                int* __restrict__ nbr_cnt,
                                                int* __restrict__ nbr_idx,
                                                float* __restrict__ pooled0) {
    int wrow = blockIdx.x * 4 + (threadIdx.x >> 6);
    int lane = threadIdx.x & 63;
    int b = wrow / NN;
    const float4* arow = (const float4*)(adj + (size_t)wrow * NN);
    int* irow = nbr_idx + (size_t)wrow * CAP;
    const float* xb = x + (size_t)b * NN * 2;
    float4 vv[3];
    vv[0] = arow[lane];                                  // 0..63   < 150
    vv[1] = arow[64 + lane];                             // 64..127 < 150
    vv[2] = (128 + lane < 150) ? arow[128 + lane] : make_float4(0.f, 0.f, 0.f, 0.f);
    int cnt = 0;
    float p0 = 0.f, p1 = 0.f;
#pragma unroll
    for (int it = 0; it < 3; ++it) {
        int fi = it * 64 + lane;
#pragma unroll
        for (int s = 0; s < 4; ++s) {
            float c = s == 0 ? vv[it].x : (s == 1 ? vv[it].y : (s == 2 ? vv[it].z : vv[it].w));
            bool pred = (c != 0.f);
            unsigned long long bal = __ballot(pred);
            if (pred) {
                int pos = cnt + __popcll(bal & ((1ull << lane) - 1ull));
                int m = fi * 4 + s;
                if (pos < CAP) irow[pos] = m;
                float2 xv = *(const float2*)&xb[m * 2];
                p0 += xv.x; p1 += xv.y;
            }
            cnt += __popcll(bal);
        }
    }
#pragma unroll
    for (int off = 1; off < 64; off <<= 1) {
        p0 += __shfl_xor(p0, off);
        p1 += __shfl_xor(p1, off);
    }
    if (lane == 0) {
        nbr_cnt[wrow] = cnt < CAP ? cnt : CAP;
        pooled0[(size_t)wrow * 2]     = p0;
        pooled0[(size_t)wrow * 2 + 1] = p1;
    }
}

// --- 5-scalar stats over pooled0 (BN0 stats are rank-2 in (p0,p1)) ---
__global__ __launch_bounds__(256) void k_p0stats(const float* __restrict__ pooled0,
                                                 float* __restrict__ out5) {
    __shared__ float red[4][5];
    int i = blockIdx.x * 256 + threadIdx.x;
    float p0 = pooled0[(size_t)i * 2], p1 = pooled0[(size_t)i * 2 + 1];
    float v[5] = {p0, p1, p0 * p0, p1 * p1, p0 * p1};
#pragma unroll
    for (int j = 0; j < 5; ++j)
#pragma unroll
        for (int off = 1; off < 64; off <<= 1) v[j] += __shfl_xor(v[j], off);
    int lane = threadIdx.x & 63, w = threadIdx.x >> 6;
    if (lane == 0)
#pragma unroll
        for (int j = 0; j < 5; ++j) red[w][j] = v[j];
    __syncthreads();
    if (threadIdx.x == 0)
#pragma unroll
        for (int j = 0; j < 5; ++j)
            atomicAdd(&out5[j], red[0][j] + red[1][j] + red[2][j] + red[3][j]);
}

// --- MFMA GEMM stage: t_out[38400x128] = A @ W(bf16,transposed), + BN stats of t_out.
//     MODE 0: A = relu(BN0(pooled0 @ W1)) synthesized from (p0,p1); t_in unused
//     MODE 1: A = relu(BN(t_in bf16))     (stats_in = sum/sq slot)
//     MODE 2: A = t_in bf16 raw           (pooled activations; zero-cost load)
//     OUTBF: 1 -> t_out bf16, 0 -> fp32. Stats always from fp32 accumulators. ---
template<int MODE, int OUTBF>
__global__ __launch_bounds__(256) void k_stage(const void* __restrict__ t_in_v,
                                               const float* __restrict__ pooled0,
                                               const float* __restrict__ W1,
                                               const unsigned short* __restrict__ wT,
                                               const float* __restrict__ stats_in,
                                               void* __restrict__ t_out_v,
                                               float* __restrict__ stats_out) {
    __shared__ float sm_mean[HH], sm_inv[HH];
    __shared__ float smS[4][HH], smQ[4][HH];
    int tid = threadIdx.x;
    if (MODE == 0 && tid < HH) {
        float S0 = stats_in[0], S1 = stats_in[1], Q0 = stats_in[2], Q1 = stats_in[3], P01 = stats_in[4];
        float w0 = W1[tid], w1 = W1[HH + tid];
        float m = (S0 * w0 + S1 * w1) * (1.f / NROWS);
        float eq = (Q0 * w0 * w0 + Q1 * w1 * w1 + 2.f * P01 * w0 * w1) * (1.f / NROWS);
        sm_mean[tid] = m;
        sm_inv[tid] = 1.f / sqrtf(eq - m * m + 1e-5f);
    }
    if (MODE == 1 && tid < HH) {
        float s = stats_in[tid], q = stats_in[HH + tid];
        float m = s * (1.f / NROWS);
        sm_mean[tid] = m;
        sm_inv[tid] = 1.f / sqrtf(q * (1.f / NROWS) - m * m + 1e-5f);
    }
    if (MODE != 2) __syncthreads();

    const unsigned short* tin = (const unsigned short*)t_in_v;
    int lane = tid & 63, wave = tid >> 6;
    int r16 = lane & 15, kg = lane >> 4;
    int rowbase = blockIdx.x * 64 + wave * 16;

    f32x4 acc[8];
#pragma unroll
    for (int t = 0; t < 8; ++t)
#pragma unroll
        for (int i = 0; i < 4; ++i) acc[t][i] = 0.f;

    float p0 = 0.f, p1 = 0.f;
    if (MODE == 0) {
        p0 = pooled0[(size_t)(rowbase + r16) * 2];
        p1 = pooled0[(size_t)(rowbase + r16) * 2 + 1];
    }

#pragma unroll
    for (int ks = 0; ks < 4; ++ks) {
        int kb = ks * 32 + kg * 8;
        short8 afr;
        if (MODE == 2) {
            afr = *(const short8*)&tin[(size_t)(rowbase + r16) * HH + kb];
        } else {
            float av[8];
            if (MODE == 0) {
                float4 wa0 = *(const float4*)&W1[kb];
                float4 wa1 = *(const float4*)&W1[kb + 4];
                float4 wb0 = *(const float4*)&W1[HH + kb];
                float4 wb1 = *(const float4*)&W1[HH + kb + 4];
                av[0] = p0 * wa0.x + p1 * wb0.x; av[1] = p0 * wa0.y + p1 * wb0.y;
                av[2] = p0 * wa0.z + p1 * wb0.z; av[3] = p0 * wa0.w + p1 * wb0.w;
                av[4] = p0 * wa1.x + p1 * wb1.x; av[5] = p0 * wa1.y + p1 * wb1.y;
                av[6] = p0 * wa1.z + p1 * wb1.z; av[7] = p0 * wa1.w + p1 * wb1.w;
            } else {
                short8 raw = *(const short8*)&tin[(size_t)(rowbase + r16) * HH + kb];
#pragma unroll
                for (int j = 0; j < 8; ++j) av[j] = bf2f((unsigned short)raw[j]);
            }
            float4 m0 = *(const float4*)&sm_mean[kb];
            float4 m1 = *(const float4*)&sm_mean[kb + 4];
            float4 i0 = *(const float4*)&sm_inv[kb];
            float4 i1 = *(const float4*)&sm_inv[kb + 4];
            av[0] = fmaxf((av[0] - m0.x) * i0.x, 0.f);
            av[1] = fmaxf((av[1] - m0.y) * i0.y, 0.f);
            av[2] = fmaxf((av[2] - m0.z) * i0.z, 0.f);
            av[3] = fmaxf((av[3] - m0.w) * i0.w, 0.f);
            av[4] = fmaxf((av[4] - m1.x) * i1.x, 0.f);
            av[5] = fmaxf((av[5] - m1.y) * i1.y, 0.f);
            av[6] = fmaxf((av[6] - m1.z) * i1.z, 0.f);
            av[7] = fmaxf((av[7] - m1.w) * i1.w, 0.f);
#pragma unroll
            for (int j = 0; j < 8; ++j) afr[j] = bf16rne(av[j]);
        }
#pragma unroll
        for (int t = 0; t < 8; ++t) {
            short8 bfr = *(const short8*)&wT[(size_t)(t * 16 + r16) * HH + kb];
            acc[t] = __builtin_amdgcn_mfma_f32_16x16x32_bf16(afr, bfr, acc[t], 0, 0, 0);
        }
    }

    // epilogue: write C (no bias — BN makes trunk biases no-ops) + column stats
#pragma unroll
    for (int t = 0; t < 8; ++t) {
        int col = t * 16 + r16;
        float s = 0.f, q = 0.f;
#pragma unroll
        for (int i = 0; i < 4; ++i) {
            float v = acc[t][i];
            if (OUTBF)
                ((unsigned short*)t_out_v)[(size_t)(rowbase + kg * 4 + i) * HH + col] =
                    (unsigned short)bf16rne(v);
            else
                ((float*)t_out_v)[(size_t)(rowbase + kg * 4 + i) * HH + col] = v;
            s += v; q += v * v;
        }
        s += __shfl_xor(s, 16); q += __shfl_xor(q, 16);
        s += __shfl_xor(s, 32); q += __shfl_xor(q, 32);
        if (kg == 0) { smS[wave][col] = s; smQ[wave][col] = q; }
    }
    __syncthreads();
    if (tid < HH) {
        atomicAdd(&stats_out[tid],      smS[0][tid] + smS[1][tid] + smS[2][tid] + smS[3][tid]);
        atomicAdd(&stats_out[HH + tid], smQ[0][tid] + smQ[1][tid] + smQ[2][tid] + smQ[3][tid]);
    }
}

// --- pooled1(bf16) = sum_nbr relu(BN1(t1 bf16)); 2-way unrolled gather ---
__global__ __launch_bounds__(256) void k_pool1(const unsigned short* __restrict__ t1,
                                               const int* __restrict__ nbr_cnt,
                                               const int* __restrict__ nbr_idx,
                                               const float* __restrict__ stats1,
                                               unsigned short* __restrict__ pooled1) {
    __shared__ float sm_mean[HH], sm_inv[HH];
    int tid = threadIdx.x;
    if (tid < HH) {
        float s = stats1[tid], q = stats1[HH + tid];
        float m = s * (1.f / NROWS);
        sm_mean[tid] = m;
        sm_inv[tid] = 1.f / sqrtf(q * (1.f / NROWS) - m * m + 1e-5f);
    }
    __syncthreads();
    int c4 = tid & 31, rl = tid >> 5;
    int row = blockIdx.x * 8 + rl;
    int b = row / NN;
    float4 mm = *(const float4*)&sm_mean[c4 * 4];
    float4 iv = *(const float4*)&sm_inv[c4 * 4];
    int cnt = nbr_cnt[row];
    const int* ir = nbr_idx + (size_t)row * CAP;
    const unsigned short* tb = t1 + (size_t)b * NN * HH;
    float a0 = 0.f, a1 = 0.f, a2 = 0.f, a3 = 0.f;
    int i = 0;
    for (; i + 1 < cnt; i += 2) {
        int m0 = ir[i], m1 = ir[i + 1];
        uint2 w0 = *(const uint2*)&tb[(size_t)m0 * HH + c4 * 4];
        uint2 w1 = *(const uint2*)&tb[(size_t)m1 * HH + c4 * 4];
        a0 += fmaxf((bf2f(w0.x & 0xffffu) - mm.x) * iv.x, 0.f)
            + fmaxf((bf2f(w1.x & 0xffffu) - mm.x) * iv.x, 0.f);
        a1 += fmaxf((bf2f(w0.x >> 16)     - mm.y) * iv.y, 0.f)
            + fmaxf((bf2f(w1.x >> 16)     - mm.y) * iv.y, 0.f);
        a2 += fmaxf((bf2f(w0.y & 0xffffu) - mm.z) * iv.z, 0.f)
            + fmaxf((bf2f(w1.y & 0xffffu) - mm.z) * iv.z, 0.f);
        a3 += fmaxf((bf2f(w0.y >> 16)     - mm.w) * iv.w, 0.f)
            + fmaxf((bf2f(w1.y >> 16)     - mm.w) * iv.w, 0.f);
    }
    if (i < cnt) {
        int m0 = ir[i];
        uint2 w0 = *(const uint2*)&tb[(size_t)m0 * HH + c4 * 4];
        a0 += fmaxf((bf2f(w0.x & 0xffffu) - mm.x) * iv.x, 0.f);
        a1 += fmaxf((bf2f(w0.x >> 16)     - mm.y) * iv.y, 0.f);
        a2 += fmaxf((bf2f(w0.y & 0xffffu) - mm.z) * iv.z, 0.f);
        a3 += fmaxf((bf2f(w0.y >> 16)     - mm.w) * iv.w, 0.f);
    }
    uint2 o;
    o.x = packbf(a0, a1);
    o.y = packbf(a2, a3);
    *(uint2*)&pooled1[(size_t)row * HH + c4 * 4] = o;
}

// --- h_pooled = sum_n gp * relu(BN3(t3)) ---
__global__ __launch_bounds__(256) void k_hpool(const float* __restrict__ t3,
                                               const float* __restrict__ gp,
                                               const float* __restrict__ stats3,
                                               float* __restrict__ hpool) {
    __shared__ float sm_mean[HH], sm_inv[HH];
    __shared__ float red[256];
    int tid = threadIdx.x;
    if (tid < HH) {
        float s = stats3[tid], q = stats3[HH + tid];
        float m = s * (1.f / NROWS);
        sm_mean[tid] = m;
        sm_inv[tid] = 1.f / sqrtf(q * (1.f / NROWS) - m * m + 1e-5f);
    }
    __syncthreads();
    int b = blockIdx.x >> 3, chunk = blockIdx.x & 7;
    int c = tid & 127, rr = tid >> 7;
    float m = sm_mean[c], iv = sm_inv[c];
    float acc = 0.f;
    for (int n = chunk * 75 + rr; n < chunk * 75 + 75; n += 2) {
        float w = gp[b * NN + n];
        float v = t3[((size_t)b * NN + n) * HH + c];
        acc += w * fmaxf((v - m) * iv, 0.f);
    }
    red[tid] = acc;
    __syncthreads();
    if (tid < HH) atomicAdd(&hpool[b * HH + c], red[c] + red[c + 128]);
}

// --- concat rows: [relu(BN3(t3[cand])), h_pooled, mch_pool] ---
__global__ __launch_bounds__(128) void k_concat(const float* __restrict__ t3,
                                                const int* __restrict__ cand,
                                                const float* __restrict__ hpool,
                                                const float* __restrict__ mch,
                                                const float* __restrict__ stats3,
                                                float* __restrict__ concat) {
    __shared__ float sm_mean[HH], sm_inv[HH];
    int t = threadIdx.x;
    {
        float s = stats3[t], q = stats3[HH + t];
        float m = s * (1.f / NROWS);
        sm_mean[t] = m;
        sm_inv[t] = 1.f / sqrtf(q * (1.f / NROWS) - m * m + 1e-5f);
    }
    __syncthreads();
    int row = blockIdx.x;
    int b = row / NJ;
    int cd = cand[row];
    float v = t3[((size_t)b * NN + cd) * HH + t];
    concat[(size_t)row * 384 + t]       = fmaxf((v - sm_mean[t]) * sm_inv[t], 0.f);
    concat[(size_t)row * 384 + 128 + t] = hpool[b * HH + t];
    concat[(size_t)row * 384 + 256 + t] = mch[b * HH + t];
}

// --- a1 = tanh(concat @ Wa1 + ba1), 8 rows/block, LDS-broadcast rows ---
__global__ __launch_bounds__(256) void k_a1(const float* __restrict__ concat,
                                            const float* __restrict__ Wa1,
                                            const float* __restrict__ ba1,
                                            float* __restrict__ a1out) {
    __shared__ float sh[8 * 384];
    int tid = threadIdx.x;
    int rbase = blockIdx.x * 8;
    const float4* src = (const float4*)(concat + (size_t)rbase * 384);
    float4* dst = (float4*)sh;
    for (int i = tid; i < 768; i += 256) dst[i] = src[i];
    __syncthreads();
    int c = tid & 127, slot = tid >> 7;
    float acc[4] = {0.f, 0.f, 0.f, 0.f};
    for (int k = 0; k < 384; ++k) {
        float w = Wa1[(size_t)k * HH + c];
#pragma unroll
        for (int rr = 0; rr < 4; ++rr)
            acc[rr] += sh[(slot * 4 + rr) * 384 + k] * w;
    }
    float bb = ba1[c];
#pragma unroll
    for (int rr = 0; rr < 4; ++rr)
        a1out[(size_t)(rbase + slot * 4 + rr) * HH + c] = tanhf(acc[rr] + bb);
}

// --- a2 = tanh(a1 @ Wa2 + ba2); scores = 10*(a2 . Wa3 + ba3) ---
__global__ __launch_bounds__(256) void k_a2s(const float* __restrict__ a1,
                                             const float* __restrict__ Wa2,
                                             const float* __restrict__ ba2,
                                             const float* __restrict__ Wa3,
                                             const float* __restrict__ ba3,
                                             float* __restrict__ scores) {
    __shared__ float sh[8 * HH];
    __shared__ float sred[8][HH];
    int tid = threadIdx.x;
    int rbase = blockIdx.x * 8;
    const float4* src = (const float4*)(a1 + (size_t)rbase * HH);
    float4* dst = (float4*)sh;
    dst[tid] = src[tid];   // 256 float4 = 8x128 floats
    __syncthreads();
    int c = tid & 127, slot = tid >> 7;
    float acc[4] = {0.f, 0.f, 0.f, 0.f};
    for (int k = 0; k < HH; ++k) {
        float w = Wa2[(size_t)k * HH + c];
#pragma unroll
        for (int rr = 0; rr < 4; ++rr)
            acc[rr] += sh[(slot * 4 + rr) * HH + k] * w;
    }
    float w3 = Wa3[c], bb = ba2[c];
#pragma unroll
    for (int rr = 0; rr < 4; ++rr)
        sred[slot * 4 + rr][c] = tanhf(acc[rr] + bb) * w3;
    __syncthreads();
    int r = tid >> 5, l32 = tid & 31;
    float v = sred[r][l32] + sred[r][l32 + 32] + sred[r][l32 + 64] + sred[r][l32 + 96];
    v += __shfl_xor(v, 1); v += __shfl_xor(v, 2); v += __shfl_xor(v, 4);
    v += __shfl_xor(v, 8); v += __shfl_xor(v, 16);
    if (l32 == 0) scores[rbase + r] = 10.f * (v + ba3[0]);
}

// --- per-b: critic, masked log_softmax/entropy/log_a, gathers ---
__global__ __launch_bounds__(128) void k_final(const float* __restrict__ t3,
                                               const float* __restrict__ stats3,
                                               const float* __restrict__ hpool,
                                               const float* __restrict__ scores,
                                               const void* __restrict__ mask_p,
                                               const void* __restrict__ maskmch_p,
                                               const int* __restrict__ flags,
                                               const float* __restrict__ dur,
                                               const int* __restrict__ a_index,
                                               const int* __restrict__ old_action,
                                               const float* __restrict__ Wc1,
                                               const float* __restrict__ bc1,
                                               const float* __restrict__ Wc2,
                                               const float* __restrict__ bc2,
                                               float* __restrict__ out) {
    __shared__ float sm_mean[HH], sm_inv[HH], sh_hp[HH], sh_red[HH];
    __shared__ float sh_s[32], sh_lp[32];
    __shared__ int sh_m[32];
    int b = blockIdx.x, t = threadIdx.x;
    {
        float s = stats3[t], q = stats3[HH + t];
        float m = s * (1.f / NROWS);
        sm_mean[t] = m;
        sm_inv[t] = 1.f / sqrtf(q * (1.f / NROWS) - m * m + 1e-5f);
    }
    sh_hp[t] = hpool[b * HH + t];
    __syncthreads();

    float acc = bc1[t];
    for (int k = 0; k < HH; ++k) acc += sh_hp[k] * Wc1[k * HH + t];
    sh_red[t] = tanhf(acc) * Wc2[t];
    __syncthreads();
    for (int st = 64; st > 0; st >>= 1) {
        if (t < st) sh_red[t] += sh_red[t + st];
        __syncthreads();
    }
    if (t == 0) out[OUT_V + b] = sh_red[0] + bc2[0];

    int fA = flags[0], fB = flags[1];
    int layA = (fA & 1) ? 2 : ((fA & 2) ? 1 : 0);
    int layB = (fB & 1) ? 2 : ((fB & 2) ? 1 : 0);
    if (t < NJ) {
        sh_s[t] = scores[b * NJ + t];
        sh_m[t] = mask_at(mask_p, layA, (long)b * NJ + t) ? 1 : 0;
    }
    __syncthreads();
    if (t == 0) {
        float mx = -1e30f;
        for (int j = 0; j < NJ; ++j)
            if (!sh_m[j] && sh_s[j] > mx) mx = sh_s[j];
        float sum = 0.f;
        for (int j = 0; j < NJ; ++j)
            if (!sh_m[j]) sum += expf(sh_s[j] - mx);
        float lse = mx + logf(sum);
        float ent = 0.f;
        for (int j = 0; j < NJ; ++j) {
            if (!sh_m[j]) {
                float lp = sh_s[j] - lse;
                sh_lp[j] = lp;
                float pi = expf(lp);
                if (pi > 0.f) ent -= pi * lp;
            }
        }
        out[OUT_ENT + b] = ent;
        out[OUT_LOGA + b] = sh_lp[a_index[b]];
    }

    int old = old_action[b];
    if (t < NM) {
        out[OUT_ANODE + b * NM + t] = dur[((size_t)b * NN + old) * NM + t];
        out[OUT_MMCH + b * NM + t] =
            mask_at(maskmch_p, layB, ((size_t)b * NN + old) * NM + t) ? 1.f : 0.f;
    }
    {
        float v = t3[((size_t)b * NN + old) * HH + t];
        out[OUT_AFEAT + b * HH + t] = fmaxf((v - sm_mean[t]) * sm_inv[t], 0.f);
        out[OUT_HPOOL + b * HH + t] = sh_hp[t];
    }
}

extern "C" void kernel_launch(void* const* d_in, const int* in_sizes, int n_in,
                              void* d_out, int out_size, void* d_ws, size_t ws_size,
                              hipStream_t stream) {
    (void)in_sizes; (void)n_in; (void)out_size; (void)ws_size;
    const float* x         = (const float*)d_in[0];
    const float* gp        = (const float*)d_in[1];
    const float* adj       = (const float*)d_in[3];
    const int*   cand      = (const int*)d_in[4];
    const void*  mask_p    = d_in[5];
    const void*  maskmch_p = d_in[6];
    const float* dur       = (const float*)d_in[7];
    const int*   a_index   = (const int*)d_in[8];
    const int*   old_act   = (const int*)d_in[9];
    const float* mch_pool  = (const float*)d_in[10];
    const float* W1_0 = (const float*)d_in[11];
    const float* W2_0 = (const float*)d_in[13];
    const float* W1_1 = (const float*)d_in[15];
    const float* W2_1 = (const float*)d_in[17];
    const float* Wa1  = (const float*)d_in[19];
    const float* ba1  = (const float*)d_in[20];
    const float* Wa2  = (const float*)d_in[21];
    const float* ba2  = (const float*)d_in[22];
    const float* Wa3  = (const float*)d_in[23];
    const float* ba3  = (const float*)d_in[24];
    const float* Wc1  = (const float*)d_in[25];
    const float* bc1  = (const float*)d_in[26];
    const float* Wc2  = (const float*)d_in[27];
    const float* bc2  = (const float*)d_in[28];

    char* ws = (char*)d_ws;
    float* stats   = (float*)(ws + STATS_B);     // slot s at stats + s*256
    float* hpool   = (float*)(ws + HPOOL_B);
    int*   flags   = (int*)(ws + FLAGS_B);
    unsigned short* wtb = (unsigned short*)(ws + WTB_B);
    float* scores  = (float*)(ws + SCORES_B);
    int*   nbr_cnt = (int*)(ws + NBRCNT_B);
    int*   nbr_idx = (int*)(ws + NBRIDX_B);
    float* concat  = (float*)(ws + CONCAT_B);
    float* a1      = (float*)(ws + A1_B);
    float* pooled0 = (float*)(ws + POOLED0_B);
    unsigned short* t1_16 = (unsigned short*)(ws + T1_B);  // t1, then t2 (bf16)
    unsigned short* p1_16 = (unsigned short*)(ws + P1_B);  // pooled1 (bf16)
    float* t3      = (float*)(ws + P1_B);                  // t3 fp32 (pooled1 dead by then)
    float* out     = (float*)d_out;

    hipMemsetAsync(ws, 0, ZERO_B, stream);
    k_detect<<<25, 256, 0, stream>>>(mask_p, maskmch_p, flags);
    k_wconv<<<192, 256, 0, stream>>>(W2_0, W1_1, W2_1, wtb);
    k_sparse<<<NROWS / 4, 256, 0, stream>>>(adj, x, nbr_cnt, nbr_idx, pooled0);
    k_p0stats<<<NROWS / 256, 256, 0, stream>>>(pooled0, stats);
    // t1(bf16) = relu(BN0(pooled0 @ W1_0)) @ W2_0   [+ stats1]
    k_stage<0, 1><<<600, 256, 0, stream>>>(nullptr, pooled0, W1_0, wtb, stats, t1_16, stats + 256);
    // pooled1(bf16) = sum_nbr relu(BN1(t1))
    k_pool1<<<NROWS / 8, 256, 0, stream>>>(t1_16, nbr_cnt, nbr_idx, stats + 256, p1_16);
    // t2(bf16) = pooled1 @ W1_1   [+ stats2]  (t2 aliases t1 buffer)
    k_stage<2, 1><<<600, 256, 0, stream>>>(p1_16, nullptr, nullptr, wtb + 16384, stats, t1_16, stats + 512);
    // t3(fp32) = relu(BN2(t2)) @ W2_1   [+ stats3]  (t3 aliases pooled1 buffer)
    k_stage<1, 0><<<600, 256, 0, stream>>>(t1_16, nullptr, nullptr, wtb + 32768, stats + 512, t3, stats + 768);
    k_hpool<<<BB * 8, 256, 0, stream>>>(t3, gp, stats + 768, hpool);
    k_concat<<<BB * NJ, 128, 0, stream>>>(t3, cand, hpool, mch_pool, stats + 768, concat);
    k_a1<<<240, 256, 0, stream>>>(concat, Wa1, ba1, a1);
    k_a2s<<<240, 256, 0, stream>>>(a1, Wa2, ba2, Wa3, ba3, scores);
    k_final<<<BB, 128, 0, stream>>>(t3, stats + 768, hpool, scores, mask_p, maskmch_p, flags,
                                    dur, a_index, old_act, Wc1, bc1, Wc2, bc2, out);
}

// Round 5
// 379.949 us; speedup vs baseline: 2.1637x; 1.0061x over previous
//
#include <hip/hip_runtime.h>
#include <hip/hip_bf16.h>

#define BB 64
#define NJ 30
#define NM 20
#define NN 600
#define HH 128
#define NROWS (BB*NN)   // 38400
#define CAP 48          // max neighbors kept (E~7, P(>47) ~ 0)

typedef __attribute__((ext_vector_type(8))) short short8;
typedef __attribute__((ext_vector_type(4))) float f32x4;

// ---- workspace byte offsets ----
#define STATS_B   0           // slot0: 5 scalars; slots1-3: sum[128],sq[128]
#define HPOOL_B   4096
#define FLAGS_B   36864
#define ZERO_B    36880       // memset range
#define WTB_B     37120       // 3 x 128x128 bf16 transposed weights (98304 B)
#define SCORES_B  135424
#define NBRCNT_B  143104
#define NBRIDX_B  296704      // NROWS*CAP ints (7372800 B)
#define POOLED0_B 7669504     // NROWS * 2 floats
#define T1_B      7976704     // NROWS*H bf16 (t1, then t2) = 9.83 MB
#define P1_B      27637504    // NROWS*H bf16: pooled1, then t3 (9.83 MB)

// ---- output float offsets ----
#define OUT_ENT   0
#define OUT_V     64
#define OUT_LOGA  128
#define OUT_ANODE 192
#define OUT_AFEAT 1472
#define OUT_MMCH  9664
#define OUT_HPOOL 10944

__device__ __forceinline__ bool mask_at(const void* p, int layout, long i) {
    if (layout == 2) return ((const float*)p)[i] != 0.f;
    if (layout == 1) return ((const unsigned char*)p)[i] != 0;
    return ((const int*)p)[i] != 0;
}

__device__ __forceinline__ short bf16rne(float f) {
    unsigned u = __float_as_uint(f);
    return (short)((u + 0x7fffu + ((u >> 16) & 1u)) >> 16);
}
__device__ __forceinline__ float bf2f(unsigned h) {
    return __uint_as_float(h << 16);
}
__device__ __forceinline__ unsigned packbf(float a, float b) {
    return ((unsigned)(unsigned short)bf16rne(a)) |
           (((unsigned)(unsigned short)bf16rne(b)) << 16);
}

// --- detect byte layout of bool inputs (f32 / u8 / i32) ---
__global__ __launch_bounds__(256) void k_detect(const void* mask_p, const void* maskmch_p,
                                                int* flags) {
    unsigned agg = 0;
    int which;
    int tid = threadIdx.x;
    if (blockIdx.x == 0) {
        which = 0;
        const unsigned* p = (const unsigned*)mask_p;     // scan 480 words = 1920 B
        unsigned w0 = (tid < 480) ? p[tid] : 0u;
        unsigned w1 = (tid + 256 < 480) ? p[tid + 256] : 0u;
        agg = w0 | w1;
    } else {
        which = 1;
        const unsigned* p = (const unsigned*)maskmch_p + (size_t)(blockIdx.x - 1) * 800;
        unsigned w0 = p[tid];                            // 24 blocks x 800 words
        unsigned w1 = (tid + 256 < 800) ? p[tid + 256] : 0u;
        unsigned w2 = (tid + 512 < 800) ? p[tid + 512] : 0u;
        unsigned w3 = (tid + 768 < 800) ? p[tid + 768] : 0u;
        agg = w0 | w1 | w2 | w3;
    }
    int f = 0;
    if (((agg >> 24) & 0xffu) == 0x3fu) f |= 1;
    if ((((agg >> 8) & 0xffu) == 1u) || (((agg >> 16) & 0xffu) == 1u) ||
        (((agg >> 24) & 0xffu) == 1u)) f |= 2;
#pragma unroll
    for (int off = 1; off < 64; off <<= 1) f |= __shfl_xor(f, off);
    if ((tid & 63) == 0 && f) atomicOr(&flags[which], f);
}

// --- pre-transpose + cvt trunk GEMM weights to bf16: wT[c][k] = W[k][c] ---
__global__ void k_wconv(const float* __restrict__ Wa, const float* __restrict__ Wb,
                        const float* __restrict__ Wc, unsigned short* __restrict__ wT) {
    int mat = blockIdx.x >> 6;
    int idx = ((blockIdx.x & 63) << 8) + threadIdx.x;
    const float* W = mat == 0 ? Wa : (mat == 1 ? Wb : Wc);
    int k = idx >> 7, c = idx & 127;
    wT[mat * 16384 + c * HH + k] = (unsigned short)bf16rne(W[idx]);
}

// --- scan adj once: neighbor lists + pooled0 = sum_nbr x (loads hoisted) ---
__global__ __launch_bounds__(256) void k_sparse(const float* __restrict__ adj,
                                                const float* __restrict__ x,
                                                int* __restrict__ nbr_cnt,
                                                int* __restrict__ nbr_idx,
                                                float* __restrict__ pooled0) {
    int wrow = blockIdx.x * 4 + (threadIdx.x >> 6);
    int lane = threadIdx.x & 63;
    int b = wrow / NN;
    const float4* arow = (const float4*)(adj + (size_t)wrow * NN);
    int* irow = nbr_idx + (size_t)wrow * CAP;
    const float* xb = x + (size_t)b * NN * 2;
    float4 vv[3];
    vv[0] = arow[lane];
    vv[1] = arow[64 + lane];
    vv[2] = (128 + lane < 150) ? arow[128 + lane] : make_float4(0.f, 0.f, 0.f, 0.f);
    int cnt = 0;
    float p0 = 0.f, p1 = 0.f;
#pragma unroll
    for (int it = 0; it < 3; ++it) {
        int fi = it * 64 + lane;
#pragma unroll
        for (int s = 0; s < 4; ++s) {
            float c = s == 0 ? vv[it].x : (s == 1 ? vv[it].y : (s == 2 ? vv[it].z : vv[it].w));
            bool pred = (c != 0.f);
            unsigned long long bal = __ballot(pred);
            if (pred) {
                int pos = cnt + __popcll(bal & ((1ull << lane) - 1ull));
                int m = fi * 4 + s;
                if (pos < CAP) irow[pos] = m;
                float2 xv = *(const float2*)&xb[m * 2];
                p0 += xv.x; p1 += xv.y;
            }
            cnt += __popcll(bal);
        }
    }
#pragma unroll
    for (int off = 1; off < 64; off <<= 1) {
        p0 += __shfl_xor(p0, off);
        p1 += __shfl_xor(p1, off);
    }
    if (lane == 0) {
        nbr_cnt[wrow] = cnt < CAP ? cnt : CAP;
        pooled0[(size_t)wrow * 2]     = p0;
        pooled0[(size_t)wrow * 2 + 1] = p1;
    }
}

// --- 5-scalar stats over pooled0 ---
__global__ __launch_bounds__(256) void k_p0stats(const float* __restrict__ pooled0,
                                                 float* __restrict__ out5) {
    __shared__ float red[4][5];
    int i = blockIdx.x * 256 + threadIdx.x;
    float p0 = pooled0[(size_t)i * 2], p1 = pooled0[(size_t)i * 2 + 1];
    float v[5] = {p0, p1, p0 * p0, p1 * p1, p0 * p1};
#pragma unroll
    for (int j = 0; j < 5; ++j)
#pragma unroll
        for (int off = 1; off < 64; off <<= 1) v[j] += __shfl_xor(v[j], off);
    int lane = threadIdx.x & 63, w = threadIdx.x >> 6;
    if (lane == 0)
#pragma unroll
        for (int j = 0; j < 5; ++j) red[w][j] = v[j];
    __syncthreads();
    if (threadIdx.x == 0)
#pragma unroll
        for (int j = 0; j < 5; ++j)
            atomicAdd(&out5[j], red[0][j] + red[1][j] + red[2][j] + red[3][j]);
}

// --- MFMA GEMM stage (see round-4 comments); all t_out now bf16 ---
template<int MODE>
__global__ __launch_bounds__(256) void k_stage(const void* __restrict__ t_in_v,
                                               const float* __restrict__ pooled0,
                                               const float* __restrict__ W1,
                                               const unsigned short* __restrict__ wT,
                                               const float* __restrict__ stats_in,
                                               unsigned short* __restrict__ t_out,
                                               float* __restrict__ stats_out) {
    __shared__ float sm_mean[HH], sm_inv[HH];
    __shared__ float smS[4][HH], smQ[4][HH];
    int tid = threadIdx.x;
    if (MODE == 0 && tid < HH) {
        float S0 = stats_in[0], S1 = stats_in[1], Q0 = stats_in[2], Q1 = stats_in[3], P01 = stats_in[4];
        float w0 = W1[tid], w1 = W1[HH + tid];
        float m = (S0 * w0 + S1 * w1) * (1.f / NROWS);
        float eq = (Q0 * w0 * w0 + Q1 * w1 * w1 + 2.f * P01 * w0 * w1) * (1.f / NROWS);
        sm_mean[tid] = m;
        sm_inv[tid] = 1.f / sqrtf(eq - m * m + 1e-5f);
    }
    if (MODE == 1 && tid < HH) {
        float s = stats_in[tid], q = stats_in[HH + tid];
        float m = s * (1.f / NROWS);
        sm_mean[tid] = m;
        sm_inv[tid] = 1.f / sqrtf(q * (1.f / NROWS) - m * m + 1e-5f);
    }
    if (MODE != 2) __syncthreads();

    const unsigned short* tin = (const unsigned short*)t_in_v;
    int lane = tid & 63, wave = tid >> 6;
    int r16 = lane & 15, kg = lane >> 4;
    int rowbase = blockIdx.x * 64 + wave * 16;

    f32x4 acc[8];
#pragma unroll
    for (int t = 0; t < 8; ++t)
#pragma unroll
        for (int i = 0; i < 4; ++i) acc[t][i] = 0.f;

    float p0 = 0.f, p1 = 0.f;
    if (MODE == 0) {
        p0 = pooled0[(size_t)(rowbase + r16) * 2];
        p1 = pooled0[(size_t)(rowbase + r16) * 2 + 1];
    }

#pragma unroll
    for (int ks = 0; ks < 4; ++ks) {
        int kb = ks * 32 + kg * 8;
        short8 afr;
        if (MODE == 2) {
            afr = *(const short8*)&tin[(size_t)(rowbase + r16) * HH + kb];
        } else {
            float av[8];
            if (MODE == 0) {
                float4 wa0 = *(const float4*)&W1[kb];
                float4 wa1 = *(const float4*)&W1[kb + 4];
                float4 wb0 = *(const float4*)&W1[HH + kb];
                float4 wb1 = *(const float4*)&W1[HH + kb + 4];
                av[0] = p0 * wa0.x + p1 * wb0.x; av[1] = p0 * wa0.y + p1 * wb0.y;
                av[2] = p0 * wa0.z + p1 * wb0.z; av[3] = p0 * wa0.w + p1 * wb0.w;
                av[4] = p0 * wa1.x + p1 * wb1.x; av[5] = p0 * wa1.y + p1 * wb1.y;
                av[6] = p0 * wa1.z + p1 * wb1.z; av[7] = p0 * wa1.w + p1 * wb1.w;
            } else {
                short8 raw = *(const short8*)&tin[(size_t)(rowbase + r16) * HH + kb];
#pragma unroll
                for (int j = 0; j < 8; ++j) av[j] = bf2f((unsigned short)raw[j]);
            }
            float4 m0 = *(const float4*)&sm_mean[kb];
            float4 m1 = *(const float4*)&sm_mean[kb + 4];
            float4 i0 = *(const float4*)&sm_inv[kb];
            float4 i1 = *(const float4*)&sm_inv[kb + 4];
            av[0] = fmaxf((av[0] - m0.x) * i0.x, 0.f);
            av[1] = fmaxf((av[1] - m0.y) * i0.y, 0.f);
            av[2] = fmaxf((av[2] - m0.z) * i0.z, 0.f);
            av[3] = fmaxf((av[3] - m0.w) * i0.w, 0.f);
            av[4] = fmaxf((av[4] - m1.x) * i1.x, 0.f);
            av[5] = fmaxf((av[5] - m1.y) * i1.y, 0.f);
            av[6] = fmaxf((av[6] - m1.z) * i1.z, 0.f);
            av[7] = fmaxf((av[7] - m1.w) * i1.w, 0.f);
#pragma unroll
            for (int j = 0; j < 8; ++j) afr[j] = bf16rne(av[j]);
        }
#pragma unroll
        for (int t = 0; t < 8; ++t) {
            short8 bfr = *(const short8*)&wT[(size_t)(t * 16 + r16) * HH + kb];
            acc[t] = __builtin_amdgcn_mfma_f32_16x16x32_bf16(afr, bfr, acc[t], 0, 0, 0);
        }
    }

#pragma unroll
    for (int t = 0; t < 8; ++t) {
        int col = t * 16 + r16;
        float s = 0.f, q = 0.f;
#pragma unroll
        for (int i = 0; i < 4; ++i) {
            float v = acc[t][i];
            t_out[(size_t)(rowbase + kg * 4 + i) * HH + col] = (unsigned short)bf16rne(v);
            s += v; q += v * v;
        }
        s += __shfl_xor(s, 16); q += __shfl_xor(q, 16);
        s += __shfl_xor(s, 32); q += __shfl_xor(q, 32);
        if (kg == 0) { smS[wave][col] = s; smQ[wave][col] = q; }
    }
    __syncthreads();
    if (tid < HH) {
        atomicAdd(&stats_out[tid],      smS[0][tid] + smS[1][tid] + smS[2][tid] + smS[3][tid]);
        atomicAdd(&stats_out[HH + tid], smQ[0][tid] + smQ[1][tid] + smQ[2][tid] + smQ[3][tid]);
    }
}

// --- pooled1(bf16) = sum_nbr relu(BN1(t1 bf16)); 2-way unrolled gather ---
__global__ __launch_bounds__(256) void k_pool1(const unsigned short* __restrict__ t1,
                                               const int* __restrict__ nbr_cnt,
                                               const int* __restrict__ nbr_idx,
                                               const float* __restrict__ stats1,
                                               unsigned short* __restrict__ pooled1) {
    __shared__ float sm_mean[HH], sm_inv[HH];
    int tid = threadIdx.x;
    if (tid < HH) {
        float s = stats1[tid], q = stats1[HH + tid];
        float m = s * (1.f / NROWS);
        sm_mean[tid] = m;
        sm_inv[tid] = 1.f / sqrtf(q * (1.f / NROWS) - m * m + 1e-5f);
    }
    __syncthreads();
    int c4 = tid & 31, rl = tid >> 5;
    int row = blockIdx.x * 8 + rl;
    int b = row / NN;
    float4 mm = *(const float4*)&sm_mean[c4 * 4];
    float4 iv = *(const float4*)&sm_inv[c4 * 4];
    int cnt = nbr_cnt[row];
    const int* ir = nbr_idx + (size_t)row * CAP;
    const unsigned short* tb = t1 + (size_t)b * NN * HH;
    float a0 = 0.f, a1 = 0.f, a2 = 0.f, a3 = 0.f;
    int i = 0;
    for (; i + 1 < cnt; i += 2) {
        int m0 = ir[i], m1 = ir[i + 1];
        uint2 w0 = *(const uint2*)&tb[(size_t)m0 * HH + c4 * 4];
        uint2 w1 = *(const uint2*)&tb[(size_t)m1 * HH + c4 * 4];
        a0 += fmaxf((bf2f(w0.x & 0xffffu) - mm.x) * iv.x, 0.f)
            + fmaxf((bf2f(w1.x & 0xffffu) - mm.x) * iv.x, 0.f);
        a1 += fmaxf((bf2f(w0.x >> 16)     - mm.y) * iv.y, 0.f)
            + fmaxf((bf2f(w1.x >> 16)     - mm.y) * iv.y, 0.f);
        a2 += fmaxf((bf2f(w0.y & 0xffffu) - mm.z) * iv.z, 0.f)
            + fmaxf((bf2f(w1.y & 0xffffu) - mm.z) * iv.z, 0.f);
        a3 += fmaxf((bf2f(w0.y >> 16)     - mm.w) * iv.w, 0.f)
            + fmaxf((bf2f(w1.y >> 16)     - mm.w) * iv.w, 0.f);
    }
    if (i < cnt) {
        int m0 = ir[i];
        uint2 w0 = *(const uint2*)&tb[(size_t)m0 * HH + c4 * 4];
        a0 += fmaxf((bf2f(w0.x & 0xffffu) - mm.x) * iv.x, 0.f);
        a1 += fmaxf((bf2f(w0.x >> 16)     - mm.y) * iv.y, 0.f);
        a2 += fmaxf((bf2f(w0.y & 0xffffu) - mm.z) * iv.z, 0.f);
        a3 += fmaxf((bf2f(w0.y >> 16)     - mm.w) * iv.w, 0.f);
    }
    uint2 o;
    o.x = packbf(a0, a1);
    o.y = packbf(a2, a3);
    *(uint2*)&pooled1[(size_t)row * HH + c4 * 4] = o;
}

// --- h_pooled = sum_n gp * relu(BN3(t3 bf16)) ---
__global__ __launch_bounds__(256) void k_hpool(const unsigned short* __restrict__ t3,
                                               const float* __restrict__ gp,
                                               const float* __restrict__ stats3,
                                               float* __restrict__ hpool) {
    __shared__ float sm_mean[HH], sm_inv[HH];
    __shared__ float red[256];
    int tid = threadIdx.x;
    if (tid < HH) {
        float s = stats3[tid], q = stats3[HH + tid];
        float m = s * (1.f / NROWS);
        sm_mean[tid] = m;
        sm_inv[tid] = 1.f / sqrtf(q * (1.f / NROWS) - m * m + 1e-5f);
    }
    __syncthreads();
    int b = blockIdx.x >> 3, chunk = blockIdx.x & 7;
    int c = tid & 127, rr = tid >> 7;
    float m = sm_mean[c], iv = sm_inv[c];
    float acc = 0.f;
    for (int n = chunk * 75 + rr; n < chunk * 75 + 75; n += 2) {
        float w = gp[b * NN + n];
        float v = bf2f(t3[((size_t)b * NN + n) * HH + c]);
        acc += w * fmaxf((v - m) * iv, 0.f);
    }
    red[tid] = acc;
    __syncthreads();
    if (tid < HH) atomicAdd(&hpool[b * HH + c], red[c] + red[c + 128]);
}

// --- fused actor head: build concat rows in LDS, a1 = tanh(concat@Wa1+ba1),
//     a2 = tanh(a1@Wa2+ba2), scores = 10*(a2.Wa3+ba3). 8 rows/block. ---
__global__ __launch_bounds__(256) void k_actor(const unsigned short* __restrict__ t3,
                                               const int* __restrict__ cand,
                                               const float* __restrict__ hpool,
                                               const float* __restrict__ mch,
                                               const float* __restrict__ stats3,
                                               const float* __restrict__ Wa1,
                                               const float* __restrict__ ba1,
                                               const float* __restrict__ Wa2,
                                               const float* __restrict__ ba2,
                                               const float* __restrict__ Wa3,
                                               const float* __restrict__ ba3,
                                               float* __restrict__ scores) {
    __shared__ float sh_c[8 * 384];
    __shared__ float sh_a1[8 * HH];
    __shared__ float sred[8][HH];
    int tid = threadIdx.x;
    int rbase = blockIdx.x * 8;
    int c = tid & 127, slot = tid >> 7;

    float mean_c, inv_c;
    {
        float s = stats3[c], q = stats3[HH + c];
        float m = s * (1.f / NROWS);
        mean_c = m;
        inv_c = 1.f / sqrtf(q * (1.f / NROWS) - m * m + 1e-5f);
    }
#pragma unroll
    for (int rr = 0; rr < 4; ++rr) {
        int r = slot * 4 + rr;
        int row = rbase + r;
        int b = row / NJ;
        int cd = cand[row];
        float v = bf2f(t3[((size_t)b * NN + cd) * HH + c]);
        sh_c[r * 384 + c]       = fmaxf((v - mean_c) * inv_c, 0.f);
        sh_c[r * 384 + 128 + c] = hpool[b * HH + c];
        sh_c[r * 384 + 256 + c] = mch[b * HH + c];
    }
    __syncthreads();

    // a1
    float acc[4] = {0.f, 0.f, 0.f, 0.f};
    for (int k = 0; k < 384; ++k) {
        float w = Wa1[(size_t)k * HH + c];
#pragma unroll
        for (int rr = 0; rr < 4; ++rr)
            acc[rr] += sh_c[(slot * 4 + rr) * 384 + k] * w;
    }
    float bb = ba1[c];
#pragma unroll
    for (int rr = 0; rr < 4; ++rr)
        sh_a1[(slot * 4 + rr) * HH + c] = tanhf(acc[rr] + bb);
    __syncthreads();

    // a2 + dot(Wa3)
    float acc2[4] = {0.f, 0.f, 0.f, 0.f};
    for (int k = 0; k < HH; ++k) {
        float w = Wa2[(size_t)k * HH + c];
#pragma unroll
        for (int rr = 0; rr < 4; ++rr)
            acc2[rr] += sh_a1[(slot * 4 + rr) * HH + k] * w;
    }
    float w3 = Wa3[c], bb2 = ba2[c];
#pragma unroll
    for (int rr = 0; rr < 4; ++rr)
        sred[slot * 4 + rr][c] = tanhf(acc2[rr] + bb2) * w3;
    __syncthreads();
    int r = tid >> 5, l32 = tid & 31;
    float v = sred[r][l32] + sred[r][l32 + 32] + sred[r][l32 + 64] + sred[r][l32 + 96];
    v += __shfl_xor(v, 1); v += __shfl_xor(v, 2); v += __shfl_xor(v, 4);
    v += __shfl_xor(v, 8); v += __shfl_xor(v, 16);
    if (l32 == 0) scores[rbase + r] = 10.f * (v + ba3[0]);
}

// --- per-b: critic, masked log_softmax/entropy/log_a, gathers ---
__global__ __launch_bounds__(128) void k_final(const unsigned short* __restrict__ t3,
                                               const float* __restrict__ stats3,
                                               const float* __restrict__ hpool,
                                               const float* __restrict__ scores,
                                               const void* __restrict__ mask_p,
                                               const void* __restrict__ maskmch_p,
                                               const int* __restrict__ flags,
                                               const float* __restrict__ dur,
                                               const int* __restrict__ a_index,
                                               const int* __restrict__ old_action,
                                               const float* __restrict__ Wc1,
                                               const float* __restrict__ bc1,
                                               const float* __restrict__ Wc2,
                                               const float* __restrict__ bc2,
                                               float* __restrict__ out) {
    __shared__ float sm_mean[HH], sm_inv[HH], sh_hp[HH], sh_red[HH];
    __shared__ float sh_s[32], sh_lp[32];
    __shared__ int sh_m[32];
    int b = blockIdx.x, t = threadIdx.x;
    {
        float s = stats3[t], q = stats3[HH + t];
        float m = s * (1.f / NROWS);
        sm_mean[t] = m;
        sm_inv[t] = 1.f / sqrtf(q * (1.f / NROWS) - m * m + 1e-5f);
    }
    sh_hp[t] = hpool[b * HH + t];
    __syncthreads();

    float acc = bc1[t];
    for (int k = 0; k < HH; ++k) acc += sh_hp[k] * Wc1[k * HH + t];
    sh_red[t] = tanhf(acc) * Wc2[t];
    __syncthreads();
    for (int st = 64; st > 0; st >>= 1) {
        if (t < st) sh_red[t] += sh_red[t + st];
        __syncthreads();
    }
    if (t == 0) out[OUT_V + b] = sh_red[0] + bc2[0];

    int fA = flags[0], fB = flags[1];
    int layA = (fA & 1) ? 2 : ((fA & 2) ? 1 : 0);
    int layB = (fB & 1) ? 2 : ((fB & 2) ? 1 : 0);
    if (t < NJ) {
        sh_s[t] = scores[b * NJ + t];
        sh_m[t] = mask_at(mask_p, layA, (long)b * NJ + t) ? 1 : 0;
    }
    __syncthreads();
    if (t == 0) {
        float mx = -1e30f;
        for (int j = 0; j < NJ; ++j)
            if (!sh_m[j] && sh_s[j] > mx) mx = sh_s[j];
        float sum = 0.f;
        for (int j = 0; j < NJ; ++j)
            if (!sh_m[j]) sum += expf(sh_s[j] - mx);
        float lse = mx + logf(sum);
        float ent = 0.f;
        for (int j = 0; j < NJ; ++j) {
            if (!sh_m[j]) {
                float lp = sh_s[j] - lse;
                sh_lp[j] = lp;
                float pi = expf(lp);
                if (pi > 0.f) ent -= pi * lp;
            }
        }
        out[OUT_ENT + b] = ent;
        out[OUT_LOGA + b] = sh_lp[a_index[b]];
    }

    int old = old_action[b];
    if (t < NM) {
        out[OUT_ANODE + b * NM + t] = dur[((size_t)b * NN + old) * NM + t];
        out[OUT_MMCH + b * NM + t] =
            mask_at(maskmch_p, layB, ((size_t)b * NN + old) * NM + t) ? 1.f : 0.f;
    }
    {
        float v = bf2f(t3[((size_t)b * NN + old) * HH + t]);
        out[OUT_AFEAT + b * HH + t] = fmaxf((v - sm_mean[t]) * sm_inv[t], 0.f);
        out[OUT_HPOOL + b * HH + t] = sh_hp[t];
    }
}

extern "C" void kernel_launch(void* const* d_in, const int* in_sizes, int n_in,
                              void* d_out, int out_size, void* d_ws, size_t ws_size,
                              hipStream_t stream) {
    (void)in_sizes; (void)n_in; (void)out_size; (void)ws_size;
    const float* x         = (const float*)d_in[0];
    const float* gp        = (const float*)d_in[1];
    const float* adj       = (const float*)d_in[3];
    const int*   cand      = (const int*)d_in[4];
    const void*  mask_p    = d_in[5];
    const void*  maskmch_p = d_in[6];
    const float* dur       = (const float*)d_in[7];
    const int*   a_index   = (const int*)d_in[8];
    const int*   old_act   = (const int*)d_in[9];
    const float* mch_pool  = (const float*)d_in[10];
    const float* W1_0 = (const float*)d_in[11];
    const float* W2_0 = (const float*)d_in[13];
    const float* W1_1 = (const float*)d_in[15];
    const float* W2_1 = (const float*)d_in[17];
    const float* Wa1  = (const float*)d_in[19];
    const float* ba1  = (const float*)d_in[20];
    const float* Wa2  = (const float*)d_in[21];
    const float* ba2  = (const float*)d_in[22];
    const float* Wa3  = (const float*)d_in[23];
    const float* ba3  = (const float*)d_in[24];
    const float* Wc1  = (const float*)d_in[25];
    const float* bc1  = (const float*)d_in[26];
    const float* Wc2  = (const float*)d_in[27];
    const float* bc2  = (const float*)d_in[28];

    char* ws = (char*)d_ws;
    float* stats   = (float*)(ws + STATS_B);
    float* hpool   = (float*)(ws + HPOOL_B);
    int*   flags   = (int*)(ws + FLAGS_B);
    unsigned short* wtb = (unsigned short*)(ws + WTB_B);
    float* scores  = (float*)(ws + SCORES_B);
    int*   nbr_cnt = (int*)(ws + NBRCNT_B);
    int*   nbr_idx = (int*)(ws + NBRIDX_B);
    float* pooled0 = (float*)(ws + POOLED0_B);
    unsigned short* t1_16 = (unsigned short*)(ws + T1_B);  // t1, then t2 (bf16)
    unsigned short* p1_16 = (unsigned short*)(ws + P1_B);  // pooled1, then t3 (bf16)
    float* out     = (float*)d_out;

    hipMemsetAsync(ws, 0, ZERO_B, stream);
    k_detect<<<25, 256, 0, stream>>>(mask_p, maskmch_p, flags);
    k_wconv<<<192, 256, 0, stream>>>(W2_0, W1_1, W2_1, wtb);
    k_sparse<<<NROWS / 4, 256, 0, stream>>>(adj, x, nbr_cnt, nbr_idx, pooled0);
    k_p0stats<<<NROWS / 256, 256, 0, stream>>>(pooled0, stats);
    // t1(bf16) = relu(BN0(pooled0 @ W1_0)) @ W2_0   [+ stats1]
    k_stage<0><<<600, 256, 0, stream>>>(nullptr, pooled0, W1_0, wtb, stats, t1_16, stats + 256);
    // pooled1(bf16) = sum_nbr relu(BN1(t1))
    k_pool1<<<NROWS / 8, 256, 0, stream>>>(t1_16, nbr_cnt, nbr_idx, stats + 256, p1_16);
    // t2(bf16) = pooled1 @ W1_1   [+ stats2]  (t2 aliases t1 buffer)
    k_stage<2><<<600, 256, 0, stream>>>(p1_16, nullptr, nullptr, wtb + 16384, stats, t1_16, stats + 512);
    // t3(bf16) = relu(BN2(t2)) @ W2_1   [+ stats3]  (t3 aliases pooled1 buffer)
    k_stage<1><<<600, 256, 0, stream>>>(t1_16, nullptr, nullptr, wtb + 32768, stats + 512, p1_16, stats + 768);
    k_hpool<<<BB * 8, 256, 0, stream>>>(p1_16, gp, stats + 768, hpool);
    k_actor<<<240, 256, 0, stream>>>(p1_16, cand, hpool, mch_pool, stats + 768,
                                     Wa1, ba1, Wa2, ba2, Wa3, ba3, scores);
    k_a_unused_guard: ;
    k_final<<<BB, 128, 0, stream>>>(p1_16, stats + 768, hpool, scores, mask_p, maskmch_p, flags,
                                    dur, a_index, old_act, Wc1, bc1, Wc2, bc2, out);
}

// Round 6
// 368.427 us; speedup vs baseline: 2.2314x; 1.0313x over previous
//
#include <hip/hip_runtime.h>
#include <hip/hip_bf16.h>

#define BB 64
#define NJ 30
#define NM 20
#define NN 600
#define HH 128
#define NROWS (BB*NN)   // 38400
#define CAP 48          // max neighbors kept (E~7, P(>47) ~ 0)

typedef __attribute__((ext_vector_type(8))) short short8;
typedef __attribute__((ext_vector_type(4))) float f32x4;

// ---- workspace byte offsets ----
#define STATS_B   0           // slot0: 5 scalars; slots1-3: sum[128],sq[128]
#define HPOOL_B   4096
#define FLAGS_B   36864
#define ZERO_B    36880       // memset range
#define WTB_B     37120       // 3 x 128x128 bf16 transposed weights (98304 B)
#define SCORES_B  135424
#define NBRCNT_B  143104
#define NBRIDX_B  296704      // NROWS*CAP ints (7372800 B)
#define POOLED0_B 7669504     // NROWS * 2 floats
#define T1_B      7976704     // NROWS*H bf16 (t1, then t2) = 9.83 MB
#define P1_B      27637504    // NROWS*H bf16: pooled1, then t3 (9.83 MB)

// ---- output float offsets ----
#define OUT_ENT   0
#define OUT_V     64
#define OUT_LOGA  128
#define OUT_ANODE 192
#define OUT_AFEAT 1472
#define OUT_MMCH  9664
#define OUT_HPOOL 10944

__device__ __forceinline__ bool mask_at(const void* p, int layout, long i) {
    if (layout == 2) return ((const float*)p)[i] != 0.f;
    if (layout == 1) return ((const unsigned char*)p)[i] != 0;
    return ((const int*)p)[i] != 0;
}

__device__ __forceinline__ short bf16rne(float f) {
    unsigned u = __float_as_uint(f);
    return (short)((u + 0x7fffu + ((u >> 16) & 1u)) >> 16);
}
__device__ __forceinline__ float bf2f(unsigned h) {
    return __uint_as_float(h << 16);
}
__device__ __forceinline__ unsigned packbf(float a, float b) {
    return ((unsigned)(unsigned short)bf16rne(a)) |
           (((unsigned)(unsigned short)bf16rne(b)) << 16);
}

// --- merged prologue: mask-layout detection (blocks 0..96) + weight
//     transpose/cvt (blocks 97..288). One node instead of two. ---
__global__ __launch_bounds__(256) void k_pre(const void* mask_p, const void* maskmch_p,
                                             int* flags,
                                             const float* __restrict__ Wa,
                                             const float* __restrict__ Wb,
                                             const float* __restrict__ Wc,
                                             unsigned short* __restrict__ wT) {
    int bid = blockIdx.x;
    int tid = threadIdx.x;
    if (bid >= 97) {   // wconv: wT[c][k] = bf16(W[k][c])
        int bid2 = bid - 97;
        int mat = bid2 >> 6;
        int idx = ((bid2 & 63) << 8) + tid;
        const float* W = mat == 0 ? Wa : (mat == 1 ? Wb : Wc);
        int k = idx >> 7, c = idx & 127;
        wT[mat * 16384 + c * HH + k] = (unsigned short)bf16rne(W[idx]);
        return;
    }
    unsigned agg = 0;
    int which;
    if (bid == 0) {
        which = 0;
        const unsigned* p = (const unsigned*)mask_p;     // 480 words
        unsigned w0 = (tid < 480) ? p[tid] : 0u;
        unsigned w1 = (tid + 256 < 480) ? p[tid + 256] : 0u;
        agg = w0 | w1;
    } else {
        which = 1;
        const unsigned* p = (const unsigned*)maskmch_p + (size_t)(bid - 1) * 200;
        agg = (tid < 200) ? p[tid] : 0u;                 // 96 blocks x 200 words
    }
    int f = 0;
    if (((agg >> 24) & 0xffu) == 0x3fu) f |= 1;
    if ((((agg >> 8) & 0xffu) == 1u) || (((agg >> 16) & 0xffu) == 1u) ||
        (((agg >> 24) & 0xffu) == 1u)) f |= 2;
#pragma unroll
    for (int off = 1; off < 64; off <<= 1) f |= __shfl_xor(f, off);
    if ((tid & 63) == 0 && f) atomicOr(&flags[which], f);
}

// --- scan adj once: neighbor lists + pooled0 = sum_nbr x.
//     Per-lane 4-bit masks + one 6-step shfl_up prefix scan per 256-col
//     chunk (was 4 ballot+popcll steps per chunk x 12 chunks). ---
__global__ __launch_bounds__(256) void k_sparse(const float* __restrict__ adj,
                                                const float* __restrict__ x,
                                                int* __restrict__ nbr_cnt,
                                                int* __restrict__ nbr_idx,
                                                float* __restrict__ pooled0) {
    int wrow = blockIdx.x * 4 + (threadIdx.x >> 6);
    int lane = threadIdx.x & 63;
    int b = wrow / NN;
    const float4* arow = (const float4*)(adj + (size_t)wrow * NN);
    int* irow = nbr_idx + (size_t)wrow * CAP;
    const float* xb = x + (size_t)b * NN * 2;
    float4 vv[3];
    vv[0] = arow[lane];
    vv[1] = arow[64 + lane];
    vv[2] = (128 + lane < 150) ? arow[128 + lane] : make_float4(0.f, 0.f, 0.f, 0.f);
    int cnt = 0;
    float p0 = 0.f, p1 = 0.f;
#pragma unroll
    for (int it = 0; it < 3; ++it) {
        float4 v = vv[it];
        int col0 = it * 256 + lane * 4;
        bool m0 = v.x != 0.f, m1 = v.y != 0.f, m2 = v.z != 0.f, m3 = v.w != 0.f;
        int c_lane = (int)m0 + (int)m1 + (int)m2 + (int)m3;
        int inc = c_lane;
#pragma unroll
        for (int off = 1; off < 64; off <<= 1) {
            int t = __shfl_up(inc, off);
            if (lane >= off) inc += t;
        }
        int pos = cnt + inc - c_lane;
        if (m0) {
            if (pos < CAP) irow[pos] = col0;
            float2 xv = *(const float2*)&xb[col0 * 2];
            p0 += xv.x; p1 += xv.y; ++pos;
        }
        if (m1) {
            if (pos < CAP) irow[pos] = col0 + 1;
            float2 xv = *(const float2*)&xb[(col0 + 1) * 2];
            p0 += xv.x; p1 += xv.y; ++pos;
        }
        if (m2) {
            if (pos < CAP) irow[pos] = col0 + 2;
            float2 xv = *(const float2*)&xb[(col0 + 2) * 2];
            p0 += xv.x; p1 += xv.y; ++pos;
        }
        if (m3) {
            if (pos < CAP) irow[pos] = col0 + 3;
            float2 xv = *(const float2*)&xb[(col0 + 3) * 2];
            p0 += xv.x; p1 += xv.y; ++pos;
        }
        cnt += __shfl(inc, 63);
    }
#pragma unroll
    for (int off = 1; off < 64; off <<= 1) {
        p0 += __shfl_xor(p0, off);
        p1 += __shfl_xor(p1, off);
    }
    if (lane == 0) {
        nbr_cnt[wrow] = cnt < CAP ? cnt : CAP;
        pooled0[(size_t)wrow * 2]     = p0;
        pooled0[(size_t)wrow * 2 + 1] = p1;
    }
}

// --- 5-scalar stats over pooled0 ---
__global__ __launch_bounds__(256) void k_p0stats(const float* __restrict__ pooled0,
                                                 float* __restrict__ out5) {
    __shared__ float red[4][5];
    int i = blockIdx.x * 256 + threadIdx.x;
    float p0 = pooled0[(size_t)i * 2], p1 = pooled0[(size_t)i * 2 + 1];
    float v[5] = {p0, p1, p0 * p0, p1 * p1, p0 * p1};
#pragma unroll
    for (int j = 0; j < 5; ++j)
#pragma unroll
        for (int off = 1; off < 64; off <<= 1) v[j] += __shfl_xor(v[j], off);
    int lane = threadIdx.x & 63, w = threadIdx.x >> 6;
    if (lane == 0)
#pragma unroll
        for (int j = 0; j < 5; ++j) red[w][j] = v[j];
    __syncthreads();
    if (threadIdx.x == 0)
#pragma unroll
        for (int j = 0; j < 5; ++j)
            atomicAdd(&out5[j], red[0][j] + red[1][j] + red[2][j] + red[3][j]);
}

// --- MFMA GEMM stage; t_out bf16; BN stats of t_out accumulated fp32 ---
template<int MODE>
__global__ __launch_bounds__(256) void k_stage(const void* __restrict__ t_in_v,
                                               const float* __restrict__ pooled0,
                                               const float* __restrict__ W1,
                                               const unsigned short* __restrict__ wT,
                                               const float* __restrict__ stats_in,
                                               unsigned short* __restrict__ t_out,
                                               float* __restrict__ stats_out) {
    __shared__ float sm_mean[HH], sm_inv[HH];
    __shared__ float smS[4][HH], smQ[4][HH];
    int tid = threadIdx.x;
    if (MODE == 0 && tid < HH) {
        float S0 = stats_in[0], S1 = stats_in[1], Q0 = stats_in[2], Q1 = stats_in[3], P01 = stats_in[4];
        float w0 = W1[tid], w1 = W1[HH + tid];
        float m = (S0 * w0 + S1 * w1) * (1.f / NROWS);
        float eq = (Q0 * w0 * w0 + Q1 * w1 * w1 + 2.f * P01 * w0 * w1) * (1.f / NROWS);
        sm_mean[tid] = m;
        sm_inv[tid] = 1.f / sqrtf(eq - m * m + 1e-5f);
    }
    if (MODE == 1 && tid < HH) {
        float s = stats_in[tid], q = stats_in[HH + tid];
        float m = s * (1.f / NROWS);
        sm_mean[tid] = m;
        sm_inv[tid] = 1.f / sqrtf(q * (1.f / NROWS) - m * m + 1e-5f);
    }
    if (MODE != 2) __syncthreads();

    const unsigned short* tin = (const unsigned short*)t_in_v;
    int lane = tid & 63, wave = tid >> 6;
    int r16 = lane & 15, kg = lane >> 4;
    int rowbase = blockIdx.x * 64 + wave * 16;

    f32x4 acc[8];
#pragma unroll
    for (int t = 0; t < 8; ++t)
#pragma unroll
        for (int i = 0; i < 4; ++i) acc[t][i] = 0.f;

    float p0 = 0.f, p1 = 0.f;
    if (MODE == 0) {
        p0 = pooled0[(size_t)(rowbase + r16) * 2];
        p1 = pooled0[(size_t)(rowbase + r16) * 2 + 1];
    }

#pragma unroll
    for (int ks = 0; ks < 4; ++ks) {
        int kb = ks * 32 + kg * 8;
        short8 afr;
        if (MODE == 2) {
            afr = *(const short8*)&tin[(size_t)(rowbase + r16) * HH + kb];
        } else {
            float av[8];
            if (MODE == 0) {
                float4 wa0 = *(const float4*)&W1[kb];
                float4 wa1 = *(const float4*)&W1[kb + 4];
                float4 wb0 = *(const float4*)&W1[HH + kb];
                float4 wb1 = *(const float4*)&W1[HH + kb + 4];
                av[0] = p0 * wa0.x + p1 * wb0.x; av[1] = p0 * wa0.y + p1 * wb0.y;
                av[2] = p0 * wa0.z + p1 * wb0.z; av[3] = p0 * wa0.w + p1 * wb0.w;
                av[4] = p0 * wa1.x + p1 * wb1.x; av[5] = p0 * wa1.y + p1 * wb1.y;
                av[6] = p0 * wa1.z + p1 * wb1.z; av[7] = p0 * wa1.w + p1 * wb1.w;
            } else {
                short8 raw = *(const short8*)&tin[(size_t)(rowbase + r16) * HH + kb];
#pragma unroll
                for (int j = 0; j < 8; ++j) av[j] = bf2f((unsigned short)raw[j]);
            }
            float4 m0 = *(const float4*)&sm_mean[kb];
            float4 m1 = *(const float4*)&sm_mean[kb + 4];
            float4 i0 = *(const float4*)&sm_inv[kb];
            float4 i1 = *(const float4*)&sm_inv[kb + 4];
            av[0] = fmaxf((av[0] - m0.x) * i0.x, 0.f);
            av[1] = fmaxf((av[1] - m0.y) * i0.y, 0.f);
            av[2] = fmaxf((av[2] - m0.z) * i0.z, 0.f);
            av[3] = fmaxf((av[3] - m0.w) * i0.w, 0.f);
            av[4] = fmaxf((av[4] - m1.x) * i1.x, 0.f);
            av[5] = fmaxf((av[5] - m1.y) * i1.y, 0.f);
            av[6] = fmaxf((av[6] - m1.z) * i1.z, 0.f);
            av[7] = fmaxf((av[7] - m1.w) * i1.w, 0.f);
#pragma unroll
            for (int j = 0; j < 8; ++j) afr[j] = bf16rne(av[j]);
        }
#pragma unroll
        for (int t = 0; t < 8; ++t) {
            short8 bfr = *(const short8*)&wT[(size_t)(t * 16 + r16) * HH + kb];
            acc[t] = __builtin_amdgcn_mfma_f32_16x16x32_bf16(afr, bfr, acc[t], 0, 0, 0);
        }
    }

#pragma unroll
    for (int t = 0; t < 8; ++t) {
        int col = t * 16 + r16;
        float s = 0.f, q = 0.f;
#pragma unroll
        for (int i = 0; i < 4; ++i) {
            float v = acc[t][i];
            t_out[(size_t)(rowbase + kg * 4 + i) * HH + col] = (unsigned short)bf16rne(v);
            s += v; q += v * v;
        }
        s += __shfl_xor(s, 16); q += __shfl_xor(q, 16);
        s += __shfl_xor(s, 32); q += __shfl_xor(q, 32);
        if (kg == 0) { smS[wave][col] = s; smQ[wave][col] = q; }
    }
    __syncthreads();
    if (tid < HH) {
        atomicAdd(&stats_out[tid],      smS[0][tid] + smS[1][tid] + smS[2][tid] + smS[3][tid]);
        atomicAdd(&stats_out[HH + tid], smQ[0][tid] + smQ[1][tid] + smQ[2][tid] + smQ[3][tid]);
    }
}

// --- pooled1(bf16) = sum_nbr relu(BN1(t1 bf16)); 2-way unrolled gather ---
__global__ __launch_bounds__(256) void k_pool1(const unsigned short* __restrict__ t1,
                                               const int* __restrict__ nbr_cnt,
                                               const int* __restrict__ nbr_idx,
                                               const float* __restrict__ stats1,
                                               unsigned short* __restrict__ pooled1) {
    __shared__ float sm_mean[HH], sm_inv[HH];
    int tid = threadIdx.x;
    if (tid < HH) {
        float s = stats1[tid], q = stats1[HH + tid];
        float m = s * (1.f / NROWS);
        sm_mean[tid] = m;
        sm_inv[tid] = 1.f / sqrtf(q * (1.f / NROWS) - m * m + 1e-5f);
    }
    __syncthreads();
    int c4 = tid & 31, rl = tid >> 5;
    int row = blockIdx.x * 8 + rl;
    int b = row / NN;
    float4 mm = *(const float4*)&sm_mean[c4 * 4];
    float4 iv = *(const float4*)&sm_inv[c4 * 4];
    int cnt = nbr_cnt[row];
    const int* ir = nbr_idx + (size_t)row * CAP;
    const unsigned short* tb = t1 + (size_t)b * NN * HH;
    float a0 = 0.f, a1 = 0.f, a2 = 0.f, a3 = 0.f;
    int i = 0;
    for (; i + 1 < cnt; i += 2) {
        int m0 = ir[i], m1 = ir[i + 1];
        uint2 w0 = *(const uint2*)&tb[(size_t)m0 * HH + c4 * 4];
        uint2 w1 = *(const uint2*)&tb[(size_t)m1 * HH + c4 * 4];
        a0 += fmaxf((bf2f(w0.x & 0xffffu) - mm.x) * iv.x, 0.f)
            + fmaxf((bf2f(w1.x & 0xffffu) - mm.x) * iv.x, 0.f);
        a1 += fmaxf((bf2f(w0.x >> 16)     - mm.y) * iv.y, 0.f)
            + fmaxf((bf2f(w1.x >> 16)     - mm.y) * iv.y, 0.f);
        a2 += fmaxf((bf2f(w0.y & 0xffffu) - mm.z) * iv.z, 0.f)
            + fmaxf((bf2f(w1.y & 0xffffu) - mm.z) * iv.z, 0.f);
        a3 += fmaxf((bf2f(w0.y >> 16)     - mm.w) * iv.w, 0.f)
            + fmaxf((bf2f(w1.y >> 16)     - mm.w) * iv.w, 0.f);
    }
    if (i < cnt) {
        int m0 = ir[i];
        uint2 w0 = *(const uint2*)&tb[(size_t)m0 * HH + c4 * 4];
        a0 += fmaxf((bf2f(w0.x & 0xffffu) - mm.x) * iv.x, 0.f);
        a1 += fmaxf((bf2f(w0.x >> 16)     - mm.y) * iv.y, 0.f);
        a2 += fmaxf((bf2f(w0.y & 0xffffu) - mm.z) * iv.z, 0.f);
        a3 += fmaxf((bf2f(w0.y >> 16)     - mm.w) * iv.w, 0.f);
    }
    uint2 o;
    o.x = packbf(a0, a1);
    o.y = packbf(a2, a3);
    *(uint2*)&pooled1[(size_t)row * HH + c4 * 4] = o;
}

// --- h_pooled = sum_n gp * relu(BN3(t3 bf16)); uint2 x 4-col tiles, 8 rows in flight ---
__global__ __launch_bounds__(256) void k_hpool(const unsigned short* __restrict__ t3,
                                               const float* __restrict__ gp,
                                               const float* __restrict__ stats3,
                                               float* __restrict__ hpool) {
    __shared__ float sm_mean[HH], sm_inv[HH];
    __shared__ float red[8][HH];
    int tid = threadIdx.x;
    if (tid < HH) {
        float s = stats3[tid], q = stats3[HH + tid];
        float m = s * (1.f / NROWS);
        sm_mean[tid] = m;
        sm_inv[tid] = 1.f / sqrtf(q * (1.f / NROWS) - m * m + 1e-5f);
    }
    __syncthreads();
    int b = blockIdx.x >> 3, chunk = blockIdx.x & 7;
    int c4 = tid & 31, rl = tid >> 5;
    float4 mm = *(const float4*)&sm_mean[c4 * 4];
    float4 iv = *(const float4*)&sm_inv[c4 * 4];
    float a0 = 0.f, a1 = 0.f, a2 = 0.f, a3 = 0.f;
    int nend = chunk * 75 + 75;
    for (int n = chunk * 75 + rl; n < nend; n += 8) {
        float w = gp[b * NN + n];
        uint2 t = *(const uint2*)&t3[((size_t)b * NN + n) * HH + c4 * 4];
        a0 += w * fmaxf((bf2f(t.x & 0xffffu) - mm.x) * iv.x, 0.f);
        a1 += w * fmaxf((bf2f(t.x >> 16)     - mm.y) * iv.y, 0.f);
        a2 += w * fmaxf((bf2f(t.y & 0xffffu) - mm.z) * iv.z, 0.f);
        a3 += w * fmaxf((bf2f(t.y >> 16)     - mm.w) * iv.w, 0.f);
    }
    *(float4*)&red[rl][c4 * 4] = make_float4(a0, a1, a2, a3);
    __syncthreads();
    if (tid < HH) {
        float s = 0.f;
#pragma unroll
        for (int g = 0; g < 8; ++g) s += red[g][tid];
        atomicAdd(&hpool[b * HH + tid], s);
    }
}

// --- fused actor head: concat rows in LDS -> a1 -> a2 -> scores. 8 rows/block. ---
__global__ __launch_bounds__(256) void k_actor(const unsigned short* __restrict__ t3,
                                               const int* __restrict__ cand,
                                               const float* __restrict__ hpool,
                                               const float* __restrict__ mch,
                                               const float* __restrict__ stats3,
                                               const float* __restrict__ Wa1,
                                               const float* __restrict__ ba1,
                                               const float* __restrict__ Wa2,
                                               const float* __restrict__ ba2,
                                               const float* __restrict__ Wa3,
                                               const float* __restrict__ ba3,
                                               float* __restrict__ scores) {
    __shared__ float sh_c[8 * 384];
    __shared__ float sh_a1[8 * HH];
    __shared__ float sred[8][HH];
    int tid = threadIdx.x;
    int rbase = blockIdx.x * 8;
    int c = tid & 127, slot = tid >> 7;

    float mean_c, inv_c;
    {
        float s = stats3[c], q = stats3[HH + c];
        float m = s * (1.f / NROWS);
        mean_c = m;
        inv_c = 1.f / sqrtf(q * (1.f / NROWS) - m * m + 1e-5f);
    }
#pragma unroll
    for (int rr = 0; rr < 4; ++rr) {
        int r = slot * 4 + rr;
        int row = rbase + r;
        int b = row / NJ;
        int cd = cand[row];
        float v = bf2f(t3[((size_t)b * NN + cd) * HH + c]);
        sh_c[r * 384 + c]       = fmaxf((v - mean_c) * inv_c, 0.f);
        sh_c[r * 384 + 128 + c] = hpool[b * HH + c];
        sh_c[r * 384 + 256 + c] = mch[b * HH + c];
    }
    __syncthreads();

    float acc[4] = {0.f, 0.f, 0.f, 0.f};
    for (int k = 0; k < 384; ++k) {
        float w = Wa1[(size_t)k * HH + c];
#pragma unroll
        for (int rr = 0; rr < 4; ++rr)
            acc[rr] += sh_c[(slot * 4 + rr) * 384 + k] * w;
    }
    float bb = ba1[c];
#pragma unroll
    for (int rr = 0; rr < 4; ++rr)
        sh_a1[(slot * 4 + rr) * HH + c] = tanhf(acc[rr] + bb);
    __syncthreads();

    float acc2[4] = {0.f, 0.f, 0.f, 0.f};
    for (int k = 0; k < HH; ++k) {
        float w = Wa2[(size_t)k * HH + c];
#pragma unroll
        for (int rr = 0; rr < 4; ++rr)
            acc2[rr] += sh_a1[(slot * 4 + rr) * HH + k] * w;
    }
    float w3 = Wa3[c], bb2 = ba2[c];
#pragma unroll
    for (int rr = 0; rr < 4; ++rr)
        sred[slot * 4 + rr][c] = tanhf(acc2[rr] + bb2) * w3;
    __syncthreads();
    int r = tid >> 5, l32 = tid & 31;
    float v = sred[r][l32] + sred[r][l32 + 32] + sred[r][l32 + 64] + sred[r][l32 + 96];
    v += __shfl_xor(v, 1); v += __shfl_xor(v, 2); v += __shfl_xor(v, 4);
    v += __shfl_xor(v, 8); v += __shfl_xor(v, 16);
    if (l32 == 0) scores[rbase + r] = 10.f * (v + ba3[0]);
}

// --- per-b: critic, masked log_softmax/entropy/log_a, gathers ---
__global__ __launch_bounds__(128) void k_final(const unsigned short* __restrict__ t3,
                                               const float* __restrict__ stats3,
                                               const float* __restrict__ hpool,
                                               const float* __restrict__ scores,
                                               const void* __restrict__ mask_p,
                                               const void* __restrict__ maskmch_p,
                                               const int* __restrict__ flags,
                                               const float* __restrict__ dur,
                                               const int* __restrict__ a_index,
                                               const int* __restrict__ old_action,
                                               const float* __restrict__ Wc1,
                                               const float* __restrict__ bc1,
                                               const float* __restrict__ Wc2,
                                               const float* __restrict__ bc2,
                                               float* __restrict__ out) {
    __shared__ float sm_mean[HH], sm_inv[HH], sh_hp[HH], sh_red[HH];
    __shared__ float sh_s[32], sh_lp[32];
    __shared__ int sh_m[32];
    int b = blockIdx.x, t = threadIdx.x;
    {
        float s = stats3[t], q = stats3[HH + t];
        float m = s * (1.f / NROWS);
        sm_mean[t] = m;
        sm_inv[t] = 1.f / sqrtf(q * (1.f / NROWS) - m * m + 1e-5f);
    }
    sh_hp[t] = hpool[b * HH + t];
    __syncthreads();

    float acc = bc1[t];
    for (int k = 0; k < HH; ++k) acc += sh_hp[k] * Wc1[k * HH + t];
    sh_red[t] = tanhf(acc) * Wc2[t];
    __syncthreads();
    for (int st = 64; st > 0; st >>= 1) {
        if (t < st) sh_red[t] += sh_red[t + st];
        __syncthreads();
    }
    if (t == 0) out[OUT_V + b] = sh_red[0] + bc2[0];

    int fA = flags[0], fB = flags[1];
    int layA = (fA & 1) ? 2 : ((fA & 2) ? 1 : 0);
    int layB = (fB & 1) ? 2 : ((fB & 2) ? 1 : 0);
    if (t < NJ) {
        sh_s[t] = scores[b * NJ + t];
        sh_m[t] = mask_at(mask_p, layA, (long)b * NJ + t) ? 1 : 0;
    }
    __syncthreads();
    if (t == 0) {
        float mx = -1e30f;
        for (int j = 0; j < NJ; ++j)
            if (!sh_m[j] && sh_s[j] > mx) mx = sh_s[j];
        float sum = 0.f;
        for (int j = 0; j < NJ; ++j)
            if (!sh_m[j]) sum += expf(sh_s[j] - mx);
        float lse = mx + logf(sum);
        float ent = 0.f;
        for (int j = 0; j < NJ; ++j) {
            if (!sh_m[j]) {
                float lp = sh_s[j] - lse;
                sh_lp[j] = lp;
                float pi = expf(lp);
                if (pi > 0.f) ent -= pi * lp;
            }
        }
        out[OUT_ENT + b] = ent;
        out[OUT_LOGA + b] = sh_lp[a_index[b]];
    }

    int old = old_action[b];
    if (t < NM) {
        out[OUT_ANODE + b * NM + t] = dur[((size_t)b * NN + old) * NM + t];
        out[OUT_MMCH + b * NM + t] =
            mask_at(maskmch_p, layB, ((size_t)b * NN + old) * NM + t) ? 1.f : 0.f;
    }
    {
        float v = bf2f(t3[((size_t)b * NN + old) * HH + t]);
        out[OUT_AFEAT + b * HH + t] = fmaxf((v - sm_mean[t]) * sm_inv[t], 0.f);
        out[OUT_HPOOL + b * HH + t] = sh_hp[t];
    }
}

extern "C" void kernel_launch(void* const* d_in, const int* in_sizes, int n_in,
                              void* d_out, int out_size, void* d_ws, size_t ws_size,
                              hipStream_t stream) {
    (void)in_sizes; (void)n_in; (void)out_size; (void)ws_size;
    const float* x         = (const float*)d_in[0];
    const float* gp        = (const float*)d_in[1];
    const float* adj       = (const float*)d_in[3];
    const int*   cand      = (const int*)d_in[4];
    const void*  mask_p    = d_in[5];
    const void*  maskmch_p = d_in[6];
    const float* dur       = (const float*)d_in[7];
    const int*   a_index   = (const int*)d_in[8];
    const int*   old_act   = (const int*)d_in[9];
    const float* mch_pool  = (const float*)d_in[10];
    const float* W1_0 = (const float*)d_in[11];
    const float* W2_0 = (const float*)d_in[13];
    const float* W1_1 = (const float*)d_in[15];
    const float* W2_1 = (const float*)d_in[17];
    const float* Wa1  = (const float*)d_in[19];
    const float* ba1  = (const float*)d_in[20];
    const float* Wa2  = (const float*)d_in[21];
    const float* ba2  = (const float*)d_in[22];
    const float* Wa3  = (const float*)d_in[23];
    const float* ba3  = (const float*)d_in[24];
    const float* Wc1  = (const float*)d_in[25];
    const float* bc1  = (const float*)d_in[26];
    const float* Wc2  = (const float*)d_in[27];
    const float* bc2  = (const float*)d_in[28];

    char* ws = (char*)d_ws;
    float* stats   = (float*)(ws + STATS_B);
    float* hpool   = (float*)(ws + HPOOL_B);
    int*   flags   = (int*)(ws + FLAGS_B);
    unsigned short* wtb = (unsigned short*)(ws + WTB_B);
    float* scores  = (float*)(ws + SCORES_B);
    int*   nbr_cnt = (int*)(ws + NBRCNT_B);
    int*   nbr_idx = (int*)(ws + NBRIDX_B);
    float* pooled0 = (float*)(ws + POOLED0_B);
    unsigned short* t1_16 = (unsigned short*)(ws + T1_B);  // t1, then t2 (bf16)
    unsigned short* p1_16 = (unsigned short*)(ws + P1_B);  // pooled1, then t3 (bf16)
    float* out     = (float*)d_out;

    hipMemsetAsync(ws, 0, ZERO_B, stream);
    k_pre<<<289, 256, 0, stream>>>(mask_p, maskmch_p, flags, W2_0, W1_1, W2_1, wtb);
    k_sparse<<<NROWS / 4, 256, 0, stream>>>(adj, x, nbr_cnt, nbr_idx, pooled0);
    k_p0stats<<<NROWS / 256, 256, 0, stream>>>(pooled0, stats);
    // t1(bf16) = relu(BN0(pooled0 @ W1_0)) @ W2_0   [+ stats1]
    k_stage<0><<<600, 256, 0, stream>>>(nullptr, pooled0, W1_0, wtb, stats, t1_16, stats + 256);
    // pooled1(bf16) = sum_nbr relu(BN1(t1))
    k_pool1<<<NROWS / 8, 256, 0, stream>>>(t1_16, nbr_cnt, nbr_idx, stats + 256, p1_16);
    // t2(bf16) = pooled1 @ W1_1   [+ stats2]  (t2 aliases t1 buffer)
    k_stage<2><<<600, 256, 0, stream>>>(p1_16, nullptr, nullptr, wtb + 16384, stats, t1_16, stats + 512);
    // t3(bf16) = relu(BN2(t2)) @ W2_1   [+ stats3]  (t3 aliases pooled1 buffer)
    k_stage<1><<<600, 256, 0, stream>>>(t1_16, nullptr, nullptr, wtb + 32768, stats + 512, p1_16, stats + 768);
    k_hpool<<<BB * 8, 256, 0, stream>>>(p1_16, gp, stats + 768, hpool);
    k_actor<<<240, 256, 0, stream>>>(p1_16, cand, hpool, mch_pool, stats + 768,
                                     Wa1, ba1, Wa2, ba2, Wa3, ba3, scores);
    k_final<<<BB, 128, 0, stream>>>(p1_16, stats + 768, hpool, scores, mask_p, maskmch_p, flags,
                                    dur, a_index, old_act, Wc1, bc1, Wc2, bc2, out);
}

// Round 7
// 352.122 us; speedup vs baseline: 2.3347x; 1.0463x over previous
//
#include <hip/hip_runtime.h>
#include <hip/hip_bf16.h>

#define BB 64
#define NJ 30
#define NM 20
#define NN 600
#define HH 128
#define NROWS (BB*NN)   // 38400
#define CAP 48          // max neighbors kept (E~7, P(>47) ~ 0)

typedef __attribute__((ext_vector_type(8))) short short8;
typedef __attribute__((ext_vector_type(4))) float f32x4;

// ---- workspace byte offsets ----
#define STATS_B   0           // slot0: 5 scalars; slots1-3: sum[128],sq[128]
#define HPOOL_B   4096
#define FLAGS_B   36864
#define ZERO_B    36880       // memset range
#define WTB_B     37120       // 3 x 128x128 bf16 transposed weights (98304 B)
#define SCORES_B  135424
#define NBRCNT_B  143104
#define NBRIDX_B  296704      // NROWS*CAP ints (7372800 B)
#define POOLED0_B 7669504     // NROWS * 2 floats
#define T1_B      7976704     // NROWS*H bf16 (t1, then t2) = 9.83 MB
#define P1_B      27637504    // NROWS*H bf16: pooled1, then t3 (9.83 MB)

// ---- output float offsets ----
#define OUT_ENT   0
#define OUT_V     64
#define OUT_LOGA  128
#define OUT_ANODE 192
#define OUT_AFEAT 1472
#define OUT_MMCH  9664
#define OUT_HPOOL 10944

__device__ __forceinline__ bool mask_at(const void* p, int layout, long i) {
    if (layout == 2) return ((const float*)p)[i] != 0.f;
    if (layout == 1) return ((const unsigned char*)p)[i] != 0;
    return ((const int*)p)[i] != 0;
}

__device__ __forceinline__ short bf16rne(float f) {
    unsigned u = __float_as_uint(f);
    return (short)((u + 0x7fffu + ((u >> 16) & 1u)) >> 16);
}
__device__ __forceinline__ float bf2f(unsigned h) {
    return __uint_as_float(h << 16);
}
__device__ __forceinline__ unsigned packbf(float a, float b) {
    return ((unsigned)(unsigned short)bf16rne(a)) |
           (((unsigned)(unsigned short)bf16rne(b)) << 16);
}

// --- merged prologue: mask-layout detection (blocks 0..96) + weight
//     transpose/cvt (blocks 97..288). ---
__global__ __launch_bounds__(256) void k_pre(const void* mask_p, const void* maskmch_p,
                                             int* flags,
                                             const float* __restrict__ Wa,
                                             const float* __restrict__ Wb,
                                             const float* __restrict__ Wc,
                                             unsigned short* __restrict__ wT) {
    int bid = blockIdx.x;
    int tid = threadIdx.x;
    if (bid >= 97) {   // wconv: wT[c][k] = bf16(W[k][c])
        int bid2 = bid - 97;
        int mat = bid2 >> 6;
        int idx = ((bid2 & 63) << 8) + tid;
        const float* W = mat == 0 ? Wa : (mat == 1 ? Wb : Wc);
        int k = idx >> 7, c = idx & 127;
        wT[mat * 16384 + c * HH + k] = (unsigned short)bf16rne(W[idx]);
        return;
    }
    unsigned agg = 0;
    int which;
    if (bid == 0) {
        which = 0;
        const unsigned* p = (const unsigned*)mask_p;     // 480 words
        unsigned w0 = (tid < 480) ? p[tid] : 0u;
        unsigned w1 = (tid + 256 < 480) ? p[tid + 256] : 0u;
        agg = w0 | w1;
    } else {
        which = 1;
        const unsigned* p = (const unsigned*)maskmch_p + (size_t)(bid - 1) * 200;
        agg = (tid < 200) ? p[tid] : 0u;                 // 96 blocks x 200 words
    }
    int f = 0;
    if (((agg >> 24) & 0xffu) == 0x3fu) f |= 1;
    if ((((agg >> 8) & 0xffu) == 1u) || (((agg >> 16) & 0xffu) == 1u) ||
        (((agg >> 24) & 0xffu) == 1u)) f |= 2;
#pragma unroll
    for (int off = 1; off < 64; off <<= 1) f |= __shfl_xor(f, off);
    if ((tid & 63) == 0 && f) atomicOr(&flags[which], f);
}

// --- scan adj once: neighbor lists + pooled0 = sum_nbr x (shfl_up scan) ---
__global__ __launch_bounds__(256) void k_sparse(const float* __restrict__ adj,
                                                const float* __restrict__ x,
                                                int* __restrict__ nbr_cnt,
                                                int* __restrict__ nbr_idx,
                                                float* __restrict__ pooled0) {
    int wrow = blockIdx.x * 4 + (threadIdx.x >> 6);
    int lane = threadIdx.x & 63;
    int b = wrow / NN;
    const float4* arow = (const float4*)(adj + (size_t)wrow * NN);
    int* irow = nbr_idx + (size_t)wrow * CAP;
    const float* xb = x + (size_t)b * NN * 2;
    float4 vv[3];
    vv[0] = arow[lane];
    vv[1] = arow[64 + lane];
    vv[2] = (128 + lane < 150) ? arow[128 + lane] : make_float4(0.f, 0.f, 0.f, 0.f);
    int cnt = 0;
    float p0 = 0.f, p1 = 0.f;
#pragma unroll
    for (int it = 0; it < 3; ++it) {
        float4 v = vv[it];
        int col0 = it * 256 + lane * 4;
        bool m0 = v.x != 0.f, m1 = v.y != 0.f, m2 = v.z != 0.f, m3 = v.w != 0.f;
        int c_lane = (int)m0 + (int)m1 + (int)m2 + (int)m3;
        int inc = c_lane;
#pragma unroll
        for (int off = 1; off < 64; off <<= 1) {
            int t = __shfl_up(inc, off);
            if (lane >= off) inc += t;
        }
        int pos = cnt + inc - c_lane;
        if (m0) {
            if (pos < CAP) irow[pos] = col0;
            float2 xv = *(const float2*)&xb[col0 * 2];
            p0 += xv.x; p1 += xv.y; ++pos;
        }
        if (m1) {
            if (pos < CAP) irow[pos] = col0 + 1;
            float2 xv = *(const float2*)&xb[(col0 + 1) * 2];
            p0 += xv.x; p1 += xv.y; ++pos;
        }
        if (m2) {
            if (pos < CAP) irow[pos] = col0 + 2;
            float2 xv = *(const float2*)&xb[(col0 + 2) * 2];
            p0 += xv.x; p1 += xv.y; ++pos;
        }
        if (m3) {
            if (pos < CAP) irow[pos] = col0 + 3;
            float2 xv = *(const float2*)&xb[(col0 + 3) * 2];
            p0 += xv.x; p1 += xv.y; ++pos;
        }
        cnt += __shfl(inc, 63);
    }
#pragma unroll
    for (int off = 1; off < 64; off <<= 1) {
        p0 += __shfl_xor(p0, off);
        p1 += __shfl_xor(p1, off);
    }
    if (lane == 0) {
        nbr_cnt[wrow] = cnt < CAP ? cnt : CAP;
        pooled0[(size_t)wrow * 2]     = p0;
        pooled0[(size_t)wrow * 2 + 1] = p1;
    }
}

// --- 5-scalar stats over pooled0 ---
__global__ __launch_bounds__(256) void k_p0stats(const float* __restrict__ pooled0,
                                                 float* __restrict__ out5) {
    __shared__ float red[4][5];
    int i = blockIdx.x * 256 + threadIdx.x;
    float p0 = pooled0[(size_t)i * 2], p1 = pooled0[(size_t)i * 2 + 1];
    float v[5] = {p0, p1, p0 * p0, p1 * p1, p0 * p1};
#pragma unroll
    for (int j = 0; j < 5; ++j)
#pragma unroll
        for (int off = 1; off < 64; off <<= 1) v[j] += __shfl_xor(v[j], off);
    int lane = threadIdx.x & 63, w = threadIdx.x >> 6;
    if (lane == 0)
#pragma unroll
        for (int j = 0; j < 5; ++j) red[w][j] = v[j];
    __syncthreads();
    if (threadIdx.x == 0)
#pragma unroll
        for (int j = 0; j < 5; ++j)
            atomicAdd(&out5[j], red[0][j] + red[1][j] + red[2][j] + red[3][j]);
}

// --- MFMA GEMM stage, COLUMN-SPLIT for occupancy:
//     grid = 2400 blocks; block bx covers rows (bx>>2)*64..+63, cols (bx&3)*32..+31.
//     9600 waves (was 2400) -> 37.5 waves/CU for latency hiding. Each wave:
//     16 rows x 32 cols = 2 MFMA tiles x 4 ks. A-unpack duplicated across the
//     4 col-blocks (VALU-cheap, L2-resident re-reads). ---
template<int MODE>
__global__ __launch_bounds__(256) void k_stage(const void* __restrict__ t_in_v,
                                               const float* __restrict__ pooled0,
                                               const float* __restrict__ W1,
                                               const unsigned short* __restrict__ wT,
                                               const float* __restrict__ stats_in,
                                               unsigned short* __restrict__ t_out,
                                               float* __restrict__ stats_out) {
    __shared__ float sm_mean[HH], sm_inv[HH];
    __shared__ float smS[4][32], smQ[4][32];
    int tid = threadIdx.x;
    if (MODE == 0 && tid < HH) {
        float S0 = stats_in[0], S1 = stats_in[1], Q0 = stats_in[2], Q1 = stats_in[3], P01 = stats_in[4];
        float w0 = W1[tid], w1 = W1[HH + tid];
        float m = (S0 * w0 + S1 * w1) * (1.f / NROWS);
        float eq = (Q0 * w0 * w0 + Q1 * w1 * w1 + 2.f * P01 * w0 * w1) * (1.f / NROWS);
        sm_mean[tid] = m;
        sm_inv[tid] = 1.f / sqrtf(eq - m * m + 1e-5f);
    }
    if (MODE == 1 && tid < HH) {
        float s = stats_in[tid], q = stats_in[HH + tid];
        float m = s * (1.f / NROWS);
        sm_mean[tid] = m;
        sm_inv[tid] = 1.f / sqrtf(q * (1.f / NROWS) - m * m + 1e-5f);
    }
    if (MODE != 2) __syncthreads();

    const unsigned short* tin = (const unsigned short*)t_in_v;
    int lane = tid & 63, wave = tid >> 6;
    int r16 = lane & 15, kg = lane >> 4;
    int rowbase = (blockIdx.x >> 2) * 64 + wave * 16;
    int colq = blockIdx.x & 3;

    f32x4 acc[2];
#pragma unroll
    for (int t = 0; t < 2; ++t)
#pragma unroll
        for (int i = 0; i < 4; ++i) acc[t][i] = 0.f;

    float p0 = 0.f, p1 = 0.f;
    if (MODE == 0) {
        p0 = pooled0[(size_t)(rowbase + r16) * 2];
        p1 = pooled0[(size_t)(rowbase + r16) * 2 + 1];
    }

#pragma unroll
    for (int ks = 0; ks < 4; ++ks) {
        int kb = ks * 32 + kg * 8;
        short8 afr;
        if (MODE == 2) {
            afr = *(const short8*)&tin[(size_t)(rowbase + r16) * HH + kb];
        } else {
            float av[8];
            if (MODE == 0) {
                float4 wa0 = *(const float4*)&W1[kb];
                float4 wa1 = *(const float4*)&W1[kb + 4];
                float4 wb0 = *(const float4*)&W1[HH + kb];
                float4 wb1 = *(const float4*)&W1[HH + kb + 4];
                av[0] = p0 * wa0.x + p1 * wb0.x; av[1] = p0 * wa0.y + p1 * wb0.y;
                av[2] = p0 * wa0.z + p1 * wb0.z; av[3] = p0 * wa0.w + p1 * wb0.w;
                av[4] = p0 * wa1.x + p1 * wb1.x; av[5] = p0 * wa1.y + p1 * wb1.y;
                av[6] = p0 * wa1.z + p1 * wb1.z; av[7] = p0 * wa1.w + p1 * wb1.w;
            } else {
                short8 raw = *(const short8*)&tin[(size_t)(rowbase + r16) * HH + kb];
#pragma unroll
                for (int j = 0; j < 8; ++j) av[j] = bf2f((unsigned short)raw[j]);
            }
            float4 m0 = *(const float4*)&sm_mean[kb];
            float4 m1 = *(const float4*)&sm_mean[kb + 4];
            float4 i0 = *(const float4*)&sm_inv[kb];
            float4 i1 = *(const float4*)&sm_inv[kb + 4];
            av[0] = fmaxf((av[0] - m0.x) * i0.x, 0.f);
            av[1] = fmaxf((av[1] - m0.y) * i0.y, 0.f);
            av[2] = fmaxf((av[2] - m0.z) * i0.z, 0.f);
            av[3] = fmaxf((av[3] - m0.w) * i0.w, 0.f);
            av[4] = fmaxf((av[4] - m1.x) * i1.x, 0.f);
            av[5] = fmaxf((av[5] - m1.y) * i1.y, 0.f);
            av[6] = fmaxf((av[6] - m1.z) * i1.z, 0.f);
            av[7] = fmaxf((av[7] - m1.w) * i1.w, 0.f);
#pragma unroll
            for (int j = 0; j < 8; ++j) afr[j] = bf16rne(av[j]);
        }
#pragma unroll
        for (int t = 0; t < 2; ++t) {
            short8 bfr = *(const short8*)&wT[(size_t)((colq * 2 + t) * 16 + r16) * HH + kb];
            acc[t] = __builtin_amdgcn_mfma_f32_16x16x32_bf16(afr, bfr, acc[t], 0, 0, 0);
        }
    }

#pragma unroll
    for (int t = 0; t < 2; ++t) {
        int lc = t * 16 + r16;               // 0..31 local col
        int col = colq * 32 + lc;
        float s = 0.f, q = 0.f;
#pragma unroll
        for (int i = 0; i < 4; ++i) {
            float v = acc[t][i];
            t_out[(size_t)(rowbase + kg * 4 + i) * HH + col] = (unsigned short)bf16rne(v);
            s += v; q += v * v;
        }
        s += __shfl_xor(s, 16); q += __shfl_xor(q, 16);
        s += __shfl_xor(s, 32); q += __shfl_xor(q, 32);
        if (kg == 0) { smS[wave][lc] = s; smQ[wave][lc] = q; }
    }
    __syncthreads();
    if (tid < 32) {
        int col = colq * 32 + tid;
        atomicAdd(&stats_out[col],      smS[0][tid] + smS[1][tid] + smS[2][tid] + smS[3][tid]);
        atomicAdd(&stats_out[HH + col], smQ[0][tid] + smQ[1][tid] + smQ[2][tid] + smQ[3][tid]);
    }
}

// --- pooled1(bf16) = sum_nbr relu(BN1(t1 bf16)); 2-way unrolled gather ---
__global__ __launch_bounds__(256) void k_pool1(const unsigned short* __restrict__ t1,
                                               const int* __restrict__ nbr_cnt,
                                               const int* __restrict__ nbr_idx,
                                               const float* __restrict__ stats1,
                                               unsigned short* __restrict__ pooled1) {
    __shared__ float sm_mean[HH], sm_inv[HH];
    int tid = threadIdx.x;
    if (tid < HH) {
        float s = stats1[tid], q = stats1[HH + tid];
        float m = s * (1.f / NROWS);
        sm_mean[tid] = m;
        sm_inv[tid] = 1.f / sqrtf(q * (1.f / NROWS) - m * m + 1e-5f);
    }
    __syncthreads();
    int c4 = tid & 31, rl = tid >> 5;
    int row = blockIdx.x * 8 + rl;
    int b = row / NN;
    float4 mm = *(const float4*)&sm_mean[c4 * 4];
    float4 iv = *(const float4*)&sm_inv[c4 * 4];
    int cnt = nbr_cnt[row];
    const int* ir = nbr_idx + (size_t)row * CAP;
    const unsigned short* tb = t1 + (size_t)b * NN * HH;
    float a0 = 0.f, a1 = 0.f, a2 = 0.f, a3 = 0.f;
    int i = 0;
    for (; i + 1 < cnt; i += 2) {
        int m0 = ir[i], m1 = ir[i + 1];
        uint2 w0 = *(const uint2*)&tb[(size_t)m0 * HH + c4 * 4];
        uint2 w1 = *(const uint2*)&tb[(size_t)m1 * HH + c4 * 4];
        a0 += fmaxf((bf2f(w0.x & 0xffffu) - mm.x) * iv.x, 0.f)
            + fmaxf((bf2f(w1.x & 0xffffu) - mm.x) * iv.x, 0.f);
        a1 += fmaxf((bf2f(w0.x >> 16)     - mm.y) * iv.y, 0.f)
            + fmaxf((bf2f(w1.x >> 16)     - mm.y) * iv.y, 0.f);
        a2 += fmaxf((bf2f(w0.y & 0xffffu) - mm.z) * iv.z, 0.f)
            + fmaxf((bf2f(w1.y & 0xffffu) - mm.z) * iv.z, 0.f);
        a3 += fmaxf((bf2f(w0.y >> 16)     - mm.w) * iv.w, 0.f)
            + fmaxf((bf2f(w1.y >> 16)     - mm.w) * iv.w, 0.f);
    }
    if (i < cnt) {
        int m0 = ir[i];
        uint2 w0 = *(const uint2*)&tb[(size_t)m0 * HH + c4 * 4];
        a0 += fmaxf((bf2f(w0.x & 0xffffu) - mm.x) * iv.x, 0.f);
        a1 += fmaxf((bf2f(w0.x >> 16)     - mm.y) * iv.y, 0.f);
        a2 += fmaxf((bf2f(w0.y & 0xffffu) - mm.z) * iv.z, 0.f);
        a3 += fmaxf((bf2f(w0.y >> 16)     - mm.w) * iv.w, 0.f);
    }
    uint2 o;
    o.x = packbf(a0, a1);
    o.y = packbf(a2, a3);
    *(uint2*)&pooled1[(size_t)row * HH + c4 * 4] = o;
}

// --- h_pooled = sum_n gp * relu(BN3(t3 bf16)); uint2 tiles, 8 rows in flight ---
__global__ __launch_bounds__(256) void k_hpool(const unsigned short* __restrict__ t3,
                                               const float* __restrict__ gp,
                                               const float* __restrict__ stats3,
                                               float* __restrict__ hpool) {
    __shared__ float sm_mean[HH], sm_inv[HH];
    __shared__ float red[8][HH];
    int tid = threadIdx.x;
    if (tid < HH) {
        float s = stats3[tid], q = stats3[HH + tid];
        float m = s * (1.f / NROWS);
        sm_mean[tid] = m;
        sm_inv[tid] = 1.f / sqrtf(q * (1.f / NROWS) - m * m + 1e-5f);
    }
    __syncthreads();
    int b = blockIdx.x >> 3, chunk = blockIdx.x & 7;
    int c4 = tid & 31, rl = tid >> 5;
    float4 mm = *(const float4*)&sm_mean[c4 * 4];
    float4 iv = *(const float4*)&sm_inv[c4 * 4];
    float a0 = 0.f, a1 = 0.f, a2 = 0.f, a3 = 0.f;
    int nend = chunk * 75 + 75;
    for (int n = chunk * 75 + rl; n < nend; n += 8) {
        float w = gp[b * NN + n];
        uint2 t = *(const uint2*)&t3[((size_t)b * NN + n) * HH + c4 * 4];
        a0 += w * fmaxf((bf2f(t.x & 0xffffu) - mm.x) * iv.x, 0.f);
        a1 += w * fmaxf((bf2f(t.x >> 16)     - mm.y) * iv.y, 0.f);
        a2 += w * fmaxf((bf2f(t.y & 0xffffu) - mm.z) * iv.z, 0.f);
        a3 += w * fmaxf((bf2f(t.y >> 16)     - mm.w) * iv.w, 0.f);
    }
    *(float4*)&red[rl][c4 * 4] = make_float4(a0, a1, a2, a3);
    __syncthreads();
    if (tid < HH) {
        float s = 0.f;
#pragma unroll
        for (int g = 0; g < 8; ++g) s += red[g][tid];
        atomicAdd(&hpool[b * HH + tid], s);
    }
}

// --- fused actor head: concat rows in LDS -> a1 -> a2 -> scores. 8 rows/block. ---
__global__ __launch_bounds__(256) void k_actor(const unsigned short* __restrict__ t3,
                                               const int* __restrict__ cand,
                                               const float* __restrict__ hpool,
                                               const float* __restrict__ mch,
                                               const float* __restrict__ stats3,
                                               const float* __restrict__ Wa1,
                                               const float* __restrict__ ba1,
                                               const float* __restrict__ Wa2,
                                               const float* __restrict__ ba2,
                                               const float* __restrict__ Wa3,
                                               const float* __restrict__ ba3,
                                               float* __restrict__ scores) {
    __shared__ float sh_c[8 * 384];
    __shared__ float sh_a1[8 * HH];
    __shared__ float sred[8][HH];
    int tid = threadIdx.x;
    int rbase = blockIdx.x * 8;
    int c = tid & 127, slot = tid >> 7;

    float mean_c, inv_c;
    {
        float s = stats3[c], q = stats3[HH + c];
        float m = s * (1.f / NROWS);
        mean_c = m;
        inv_c = 1.f / sqrtf(q * (1.f / NROWS) - m * m + 1e-5f);
    }
#pragma unroll
    for (int rr = 0; rr < 4; ++rr) {
        int r = slot * 4 + rr;
        int row = rbase + r;
        int b = row / NJ;
        int cd = cand[row];
        float v = bf2f(t3[((size_t)b * NN + cd) * HH + c]);
        sh_c[r * 384 + c]       = fmaxf((v - mean_c) * inv_c, 0.f);
        sh_c[r * 384 + 128 + c] = hpool[b * HH + c];
        sh_c[r * 384 + 256 + c] = mch[b * HH + c];
    }
    __syncthreads();

    float acc[4] = {0.f, 0.f, 0.f, 0.f};
    for (int k = 0; k < 384; ++k) {
        float w = Wa1[(size_t)k * HH + c];
#pragma unroll
        for (int rr = 0; rr < 4; ++rr)
            acc[rr] += sh_c[(slot * 4 + rr) * 384 + k] * w;
    }
    float bb = ba1[c];
#pragma unroll
    for (int rr = 0; rr < 4; ++rr)
        sh_a1[(slot * 4 + rr) * HH + c] = tanhf(acc[rr] + bb);
    __syncthreads();

    float acc2[4] = {0.f, 0.f, 0.f, 0.f};
    for (int k = 0; k < HH; ++k) {
        float w = Wa2[(size_t)k * HH + c];
#pragma unroll
        for (int rr = 0; rr < 4; ++rr)
            acc2[rr] += sh_a1[(slot * 4 + rr) * HH + k] * w;
    }
    float w3 = Wa3[c], bb2 = ba2[c];
#pragma unroll
    for (int rr = 0; rr < 4; ++rr)
        sred[slot * 4 + rr][c] = tanhf(acc2[rr] + bb2) * w3;
    __syncthreads();
    int r = tid >> 5, l32 = tid & 31;
    float v = sred[r][l32] + sred[r][l32 + 32] + sred[r][l32 + 64] + sred[r][l32 + 96];
    v += __shfl_xor(v, 1); v += __shfl_xor(v, 2); v += __shfl_xor(v, 4);
    v += __shfl_xor(v, 8); v += __shfl_xor(v, 16);
    if (l32 == 0) scores[rbase + r] = 10.f * (v + ba3[0]);
}

// --- per-b: critic, masked log_softmax/entropy/log_a, gathers ---
__global__ __launch_bounds__(128) void k_final(const unsigned short* __restrict__ t3,
                                               const float* __restrict__ stats3,
                                               const float* __restrict__ hpool,
                                               const float* __restrict__ scores,
                                               const void* __restrict__ mask_p,
                                               const void* __restrict__ maskmch_p,
                                               const int* __restrict__ flags,
                                               const float* __restrict__ dur,
                                               const int* __restrict__ a_index,
                                               const int* __restrict__ old_action,
                                               const float* __restrict__ Wc1,
                                               const float* __restrict__ bc1,
                                               const float* __restrict__ Wc2,
                                               const float* __restrict__ bc2,
                                               float* __restrict__ out) {
    __shared__ float sm_mean[HH], sm_inv[HH], sh_hp[HH], sh_red[HH];
    __shared__ float sh_s[32], sh_lp[32];
    __shared__ int sh_m[32];
    int b = blockIdx.x, t = threadIdx.x;
    {
        float s = stats3[t], q = stats3[HH + t];
        float m = s * (1.f / NROWS);
        sm_mean[t] = m;
        sm_inv[t] = 1.f / sqrtf(q * (1.f / NROWS) - m * m + 1e-5f);
    }
    sh_hp[t] = hpool[b * HH + t];
    __syncthreads();

    float acc = bc1[t];
    for (int k = 0; k < HH; ++k) acc += sh_hp[k] * Wc1[k * HH + t];
    sh_red[t] = tanhf(acc) * Wc2[t];
    __syncthreads();
    for (int st = 64; st > 0; st >>= 1) {
        if (t < st) sh_red[t] += sh_red[t + st];
        __syncthreads();
    }
    if (t == 0) out[OUT_V + b] = sh_red[0] + bc2[0];

    int fA = flags[0], fB = flags[1];
    int layA = (fA & 1) ? 2 : ((fA & 2) ? 1 : 0);
    int layB = (fB & 1) ? 2 : ((fB & 2) ? 1 : 0);
    if (t < NJ) {
        sh_s[t] = scores[b * NJ + t];
        sh_m[t] = mask_at(mask_p, layA, (long)b * NJ + t) ? 1 : 0;
    }
    __syncthreads();
    if (t == 0) {
        float mx = -1e30f;
        for (int j = 0; j < NJ; ++j)
            if (!sh_m[j] && sh_s[j] > mx) mx = sh_s[j];
        float sum = 0.f;
        for (int j = 0; j < NJ; ++j)
            if (!sh_m[j]) sum += expf(sh_s[j] - mx);
        float lse = mx + logf(sum);
        float ent = 0.f;
        for (int j = 0; j < NJ; ++j) {
            if (!sh_m[j]) {
                float lp = sh_s[j] - lse;
                sh_lp[j] = lp;
                float pi = expf(lp);
                if (pi > 0.f) ent -= pi * lp;
            }
        }
        out[OUT_ENT + b] = ent;
        out[OUT_LOGA + b] = sh_lp[a_index[b]];
    }

    int old = old_action[b];
    if (t < NM) {
        out[OUT_ANODE + b * NM + t] = dur[((size_t)b * NN + old) * NM + t];
        out[OUT_MMCH + b * NM + t] =
            mask_at(maskmch_p, layB, ((size_t)b * NN + old) * NM + t) ? 1.f : 0.f;
    }
    {
        float v = bf2f(t3[((size_t)b * NN + old) * HH + t]);
        out[OUT_AFEAT + b * HH + t] = fmaxf((v - sm_mean[t]) * sm_inv[t], 0.f);
        out[OUT_HPOOL + b * HH + t] = sh_hp[t];
    }
}

extern "C" void kernel_launch(void* const* d_in, const int* in_sizes, int n_in,
                              void* d_out, int out_size, void* d_ws, size_t ws_size,
                              hipStream_t stream) {
    (void)in_sizes; (void)n_in; (void)out_size; (void)ws_size;
    const float* x         = (const float*)d_in[0];
    const float* gp        = (const float*)d_in[1];
    const float* adj       = (const float*)d_in[3];
    const int*   cand      = (const int*)d_in[4];
    const void*  mask_p    = d_in[5];
    const void*  maskmch_p = d_in[6];
    const float* dur       = (const float*)d_in[7];
    const int*   a_index   = (const int*)d_in[8];
    const int*   old_act   = (const int*)d_in[9];
    const float* mch_pool  = (const float*)d_in[10];
    const float* W1_0 = (const float*)d_in[11];
    const float* W2_0 = (const float*)d_in[13];
    const float* W1_1 = (const float*)d_in[15];
    const float* W2_1 = (const float*)d_in[17];
    const float* Wa1  = (const float*)d_in[19];
    const float* ba1  = (const float*)d_in[20];
    const float* Wa2  = (const float*)d_in[21];
    const float* ba2  = (const float*)d_in[22];
    const float* Wa3  = (const float*)d_in[23];
    const float* ba3  = (const float*)d_in[24];
    const float* Wc1  = (const float*)d_in[25];
    const float* bc1  = (const float*)d_in[26];
    const float* Wc2  = (const float*)d_in[27];
    const float* bc2  = (const float*)d_in[28];

    char* ws = (char*)d_ws;
    float* stats   = (float*)(ws + STATS_B);
    float* hpool   = (float*)(ws + HPOOL_B);
    int*   flags   = (int*)(ws + FLAGS_B);
    unsigned short* wtb = (unsigned short*)(ws + WTB_B);
    float* scores  = (float*)(ws + SCORES_B);
    int*   nbr_cnt = (int*)(ws + NBRCNT_B);
    int*   nbr_idx = (int*)(ws + NBRIDX_B);
    float* pooled0 = (float*)(ws + POOLED0_B);
    unsigned short* t1_16 = (unsigned short*)(ws + T1_B);  // t1, then t2 (bf16)
    unsigned short* p1_16 = (unsigned short*)(ws + P1_B);  // pooled1, then t3 (bf16)
    float* out     = (float*)d_out;

    hipMemsetAsync(ws, 0, ZERO_B, stream);
    k_pre<<<289, 256, 0, stream>>>(mask_p, maskmch_p, flags, W2_0, W1_1, W2_1, wtb);
    k_sparse<<<NROWS / 4, 256, 0, stream>>>(adj, x, nbr_cnt, nbr_idx, pooled0);
    k_p0stats<<<NROWS / 256, 256, 0, stream>>>(pooled0, stats);
    // t1(bf16) = relu(BN0(pooled0 @ W1_0)) @ W2_0   [+ stats1]
    k_stage<0><<<2400, 256, 0, stream>>>(nullptr, pooled0, W1_0, wtb, stats, t1_16, stats + 256);
    // pooled1(bf16) = sum_nbr relu(BN1(t1))
    k_pool1<<<NROWS / 8, 256, 0, stream>>>(t1_16, nbr_cnt, nbr_idx, stats + 256, p1_16);
    // t2(bf16) = pooled1 @ W1_1   [+ stats2]  (t2 aliases t1 buffer)
    k_stage<2><<<2400, 256, 0, stream>>>(p1_16, nullptr, nullptr, wtb + 16384, stats, t1_16, stats + 512);
    // t3(bf16) = relu(BN2(t2)) @ W2_1   [+ stats3]  (t3 aliases pooled1 buffer)
    k_stage<1><<<2400, 256, 0, stream>>>(t1_16, nullptr, nullptr, wtb + 32768, stats + 512, p1_16, stats + 768);
    k_hpool<<<BB * 8, 256, 0, stream>>>(p1_16, gp, stats + 768, hpool);
    k_actor<<<240, 256, 0, stream>>>(p1_16, cand, hpool, mch_pool, stats + 768,
                                     Wa1, ba1, Wa2, ba2, Wa3, ba3, scores);
    k_final<<<BB, 128, 0, stream>>>(p1_16, stats + 768, hpool, scores, mask_p, maskmch_p, flags,
                                    dur, a_index, old_act, Wc1, bc1, Wc2, bc2, out);
}